// Round 14
// baseline (3323.981 us; speedup 1.0000x reference)
//
#include <hip/hip_runtime.h>
#include <math.h>

#define NBATCH 256
#define NNODE 256
#define FCLAMP 60000.0f   // tripwire; post-bn6 values are ~1e3 max

typedef float f32x4 __attribute__((ext_vector_type(4)));
typedef _Float16 half_t;
typedef half_t f16x8 __attribute__((ext_vector_type(8)));
typedef half_t f16x4 __attribute__((ext_vector_type(4)));

// f16 2-term split: v = h + l + O(2^-22 * v); range-safe for |v| < 60000.
__device__ __forceinline__ void split2(float v, half_t& h, half_t& l)
{
    v = fminf(fmaxf(v, -FCLAMP), FCLAMP);
    half_t hh = (half_t)v;
    h = hh;
    l = (half_t)(v - (float)hh);
}

// ===========================================================================
// f16 2-term split GEMM: A LDS-staged (split2 once per element), B DIRECT
// GLOBAL (pre-split weight panel, L2-resident) — splits operand traffic
// across the LDS and VMEM pipes, which co-schedule (m114). Round-13's
// both-in-LDS version was LDS-pipe-bound (144KB/kstep vs 233 MFMA-cyc,
// cap 21%); this layout: LDS 48KB (565cyc) || VMEM 32KB (~500cyc) vs 233
// MFMA-cyc -> cap ~41%.
// Block 128x128, 4 waves (2x2), wave 64x64 = 4x4 frags of 16x16x32, BK=32.
// 3 MFMA per product {ah*bh, ah*bl, al*bh}; fp32 accum. Arithmetic order
// identical to rounds 10/12/13 -> bit-identical output.
// Frag family (m89/m91/m97-verified): a: lane=(row l&15, k=(l>>4)*8+j);
// b: lane=(col l&15, same k); d: row=(l>>4)*4+r, col=l&15.
// B global addressing identical to round-10's verified kernel.
// ===========================================================================
template<bool RELU, bool ACC>
__global__ __launch_bounds__(256)
void gemm_wk2(int M, int N, int K,
              const float* __restrict__ A, int lda,
              const half_t* __restrict__ Bh, const half_t* __restrict__ Bl, int ldb,
              float* __restrict__ C, int ldc,
              const float* __restrict__ bias)
{
    __shared__ half_t Ash[128][40], Asl[128][40];

    const int tid  = threadIdx.x;
    const int tn0  = blockIdx.x * 128;
    const int tm0  = blockIdx.y * 128;
    const int lane = tid & 63;
    const int w    = tid >> 6;
    const int wr   = (w >> 1) * 64, wc = (w & 1) * 64;
    const int lr   = lane & 15, ko = lane >> 4;

    const int srow = tid >> 1;          // staging row 0..127
    const int skh  = (tid & 1) * 16;    // staging k-half 0/16

    f32x4 acc[4][4];
#pragma unroll
    for (int i = 0; i < 4; ++i)
#pragma unroll
        for (int j = 0; j < 4; ++j) acc[i][j] = (f32x4){0.f, 0.f, 0.f, 0.f};

    const float* aP = A + (size_t)(tm0 + srow) * lda + skh;
    size_t boff[4];
#pragma unroll
    for (int nf = 0; nf < 4; ++nf)
        boff[nf] = (size_t)(tn0 + wc + nf * 16 + lr) * ldb + ko * 8;

    for (int kb = 0; kb < K; kb += 32) {
        // ---- stage A: 16 fp32 per thread, split2 once ----
        {
            const float4* ap = (const float4*)(aP + kb);
            float4 u0 = ap[0], u1 = ap[1], u2 = ap[2], u3 = ap[3];
            float vv[16] = {u0.x, u0.y, u0.z, u0.w, u1.x, u1.y, u1.z, u1.w,
                            u2.x, u2.y, u2.z, u2.w, u3.x, u3.y, u3.z, u3.w};
            half_t th[16], tl[16];
#pragma unroll
            for (int j = 0; j < 16; ++j)
                split2(vv[j], th[j], tl[j]);
            *(f16x8*)&Ash[srow][skh]     = *(f16x8*)&th[0];
            *(f16x8*)&Ash[srow][skh + 8] = *(f16x8*)&th[8];
            *(f16x8*)&Asl[srow][skh]     = *(f16x8*)&tl[0];
            *(f16x8*)&Asl[srow][skh + 8] = *(f16x8*)&tl[8];
        }
        __syncthreads();

        // ---- B frags direct from global (L2-resident weight panel) ----
        f16x8 bh[4], bl[4];
#pragma unroll
        for (int nf = 0; nf < 4; ++nf) {
            bh[nf] = *(const f16x8*)(Bh + boff[nf] + kb);
            bl[nf] = *(const f16x8*)(Bl + boff[nf] + kb);
        }
        // ---- A frags from LDS ----
        f16x8 ah[4], al[4];
#pragma unroll
        for (int mf = 0; mf < 4; ++mf) {
            int r = wr + mf * 16 + lr;
            ah[mf] = *(const f16x8*)&Ash[r][ko * 8];
            al[mf] = *(const f16x8*)&Asl[r][ko * 8];
        }
        // ---- MFMA: 3 per product (same order as rounds 12/13) ----
#pragma unroll
        for (int nf = 0; nf < 4; ++nf) {
#pragma unroll
            for (int mf = 0; mf < 4; ++mf) {
                acc[mf][nf] = __builtin_amdgcn_mfma_f32_16x16x32_f16(ah[mf], bh[nf], acc[mf][nf], 0, 0, 0);
                acc[mf][nf] = __builtin_amdgcn_mfma_f32_16x16x32_f16(ah[mf], bl[nf], acc[mf][nf], 0, 0, 0);
                acc[mf][nf] = __builtin_amdgcn_mfma_f32_16x16x32_f16(al[mf], bh[nf], acc[mf][nf], 0, 0, 0);
            }
        }
        __syncthreads();
    }

#pragma unroll
    for (int mf = 0; mf < 4; ++mf) {
        int r0 = tm0 + wr + mf * 16 + ko * 4;
#pragma unroll
        for (int nf = 0; nf < 4; ++nf) {
            int c = tn0 + wc + nf * 16 + lr;
            float bsv = bias ? bias[c] : 0.f;
#pragma unroll
            for (int r = 0; r < 4; ++r) {
                float* cp = C + (size_t)(r0 + r) * ldc + c;
                float t = acc[mf][nf][r] + bsv;
                if (ACC) t += *cp;
                if (RELU) t = fmaxf(t, 0.f);
                *cp = t;
            }
        }
    }
}

// ===========================================================================
// f16 2-term adj-GEMM: adj (pre-split, shared across all z -> L2-hot)
// LDS-staged; XT frags direct global. Same pipe-split rationale as wk2.
// Out[z] = adj @ X[z]; XT[C][RSc] (col-major over global row m=z*256+k).
// ===========================================================================
__global__ __launch_bounds__(256)
void gemm_ak2(int K, int ldxt,
              const half_t* __restrict__ Ah, const half_t* __restrict__ Al,
              const half_t* __restrict__ XTh, const half_t* __restrict__ XTl,
              float* __restrict__ C, int ldc, long long sC)
{
    __shared__ half_t Ash[128][40], Asl[128][40];

    const int z = blockIdx.z;
    C += sC * z;
    const int zoff = z * NNODE;
    const int tid  = threadIdx.x;
    const int tn0  = blockIdx.x * 128;
    const int tm0  = blockIdx.y * 128;
    const int lane = tid & 63;
    const int w    = tid >> 6;
    const int wr   = (w >> 1) * 64, wc = (w & 1) * 64;
    const int lr   = lane & 15, ko = lane >> 4;

    const int srow = tid >> 1;
    const int skh  = (tid & 1) * 16;

    f32x4 acc[4][4];
#pragma unroll
    for (int i = 0; i < 4; ++i)
#pragma unroll
        for (int j = 0; j < 4; ++j) acc[i][j] = (f32x4){0.f, 0.f, 0.f, 0.f};

    const half_t* ahP = Ah + (size_t)(tm0 + srow) * NNODE + skh;
    const half_t* alP = Al + (size_t)(tm0 + srow) * NNODE + skh;
    size_t boff[4];
#pragma unroll
    for (int nf = 0; nf < 4; ++nf)
        boff[nf] = (size_t)(tn0 + wc + nf * 16 + lr) * ldxt + zoff + ko * 8;

    for (int kb = 0; kb < K; kb += 32) {
        // ---- stage adj (already split, no VALU) ----
        *(f16x8*)&Ash[srow][skh]     = *(const f16x8*)(ahP + kb);
        *(f16x8*)&Ash[srow][skh + 8] = *(const f16x8*)(ahP + kb + 8);
        *(f16x8*)&Asl[srow][skh]     = *(const f16x8*)(alP + kb);
        *(f16x8*)&Asl[srow][skh + 8] = *(const f16x8*)(alP + kb + 8);
        __syncthreads();

        // ---- XT frags direct from global ----
        f16x8 bh[4], bl[4];
#pragma unroll
        for (int nf = 0; nf < 4; ++nf) {
            bh[nf] = *(const f16x8*)(XTh + boff[nf] + kb);
            bl[nf] = *(const f16x8*)(XTl + boff[nf] + kb);
        }
        // ---- adj frags from LDS ----
        f16x8 ah[4], al[4];
#pragma unroll
        for (int mf = 0; mf < 4; ++mf) {
            int r = wr + mf * 16 + lr;
            ah[mf] = *(const f16x8*)&Ash[r][ko * 8];
            al[mf] = *(const f16x8*)&Asl[r][ko * 8];
        }
#pragma unroll
        for (int nf = 0; nf < 4; ++nf) {
#pragma unroll
            for (int mf = 0; mf < 4; ++mf) {
                acc[mf][nf] = __builtin_amdgcn_mfma_f32_16x16x32_f16(ah[mf], bh[nf], acc[mf][nf], 0, 0, 0);
                acc[mf][nf] = __builtin_amdgcn_mfma_f32_16x16x32_f16(ah[mf], bl[nf], acc[mf][nf], 0, 0, 0);
                acc[mf][nf] = __builtin_amdgcn_mfma_f32_16x16x32_f16(al[mf], bh[nf], acc[mf][nf], 0, 0, 0);
            }
        }
        __syncthreads();
    }

#pragma unroll
    for (int mf = 0; mf < 4; ++mf) {
        int r0 = tm0 + wr + mf * 16 + ko * 4;
#pragma unroll
        for (int nf = 0; nf < 4; ++nf) {
            int c = tn0 + wc + nf * 16 + lr;
#pragma unroll
            for (int r = 0; r < 4; ++r)
                C[(size_t)(r0 + r) * ldc + c] = acc[mf][nf][r];
        }
    }
}

// Transpose + f16-2 split: X (Mtot x C, ld) -> T[C][Mtot] x 2 terms.
__global__ __launch_bounds__(256)
void xpose2_k(const float* __restrict__ X, int ld, int Mtot,
              half_t* __restrict__ Th, half_t* __restrict__ Tl)
{
    __shared__ float tile[32][33];
    const int m0 = blockIdx.x * 32, c0 = blockIdx.y * 32;
    const int t = threadIdx.x;
    {
        int r = t >> 3, cc = (t & 7) * 4;
        float4 v = *(const float4*)(X + (size_t)(m0 + r) * ld + c0 + cc);
        tile[r][cc + 0] = v.x; tile[r][cc + 1] = v.y;
        tile[r][cc + 2] = v.z; tile[r][cc + 3] = v.w;
    }
    __syncthreads();
    {
        int cr = t >> 3, mc = (t & 7) * 4;
        f16x4 h, l;
#pragma unroll
        for (int j = 0; j < 4; ++j) {
            half_t hh, ll;
            split2(tile[mc + j][cr], hh, ll);
            h[j] = hh; l[j] = ll;
        }
        size_t o = (size_t)(c0 + cr) * Mtot + m0 + mc;
        *(f16x4*)(Th + o) = h;
        *(f16x4*)(Tl + o) = l;
    }
}

// W [K][N] fp32 -> WT [N][K] f16 2-term
__global__ __launch_bounds__(256)
void wsplit2_k(const float* __restrict__ W, int K, int N,
               half_t* __restrict__ Th, half_t* __restrict__ Tl)
{
    __shared__ float tile[32][33];
    const int k0 = blockIdx.x * 32, n0 = blockIdx.y * 32;
    const int t = threadIdx.x;
    {
        int kr = t >> 3, nc = (t & 7) * 4;
        float4 v = *(const float4*)(W + (size_t)(k0 + kr) * N + n0 + nc);
        tile[kr][nc + 0] = v.x; tile[kr][nc + 1] = v.y;
        tile[kr][nc + 2] = v.z; tile[kr][nc + 3] = v.w;
    }
    __syncthreads();
    {
        int nr = t >> 3, kc = (t & 7) * 4;
        f16x4 h, l;
#pragma unroll
        for (int j = 0; j < 4; ++j) {
            half_t hh, ll;
            split2(tile[kc + j][nr], hh, ll);
            h[j] = hh; l[j] = ll;
        }
        size_t o = (size_t)(n0 + nr) * K + k0 + kc;
        *(f16x4*)(Th + o) = h;
        *(f16x4*)(Tl + o) = l;
    }
}

__global__ void asplit2_k(const float* __restrict__ A,
                          half_t* __restrict__ Ah, half_t* __restrict__ Al, int n)
{
    int i = blockIdx.x * blockDim.x + threadIdx.x;
    if (i < n) {
        half_t h, l;
        split2(A[i], h, l);
        Ah[i] = h; Al[i] = l;
    }
}

// ===========================================================================
// fp32 tiled GEMM (BM=128, BN=64, BK=16) — the round-5-validated arithmetic.
// Used for the ENTIRE pre-bn6 chain (error-amplifying region) + C=64 stages.
// ===========================================================================
template<bool RELU, bool ACC>
__global__ __launch_bounds__(256)
void gemm_k(int M, int N, int K,
            const float* __restrict__ A, int lda, long long sA,
            const float* __restrict__ B, int ldb, long long sB,
            float* __restrict__ C, int ldc, long long sC)
{
    constexpr int BM = 128, BN_ = 64, BK = 16, TM = 8, TN = 4;
    constexpr int TX = BN_ / TN;
    __shared__ float As[BK][BM + 4];
    __shared__ float Bs[BK][BN_ + 4];
    const int bz = blockIdx.z;
    A += sA * bz; B += sB * bz; C += sC * bz;
    const int tn0 = blockIdx.x * BN_, tm0 = blockIdx.y * BM;
    const int tid = threadIdx.x;
    const int tx = tid % TX, ty = tid / TX;
    float acc[TM][TN];
#pragma unroll
    for (int i = 0; i < TM; ++i)
#pragma unroll
        for (int j = 0; j < TN; ++j) acc[i][j] = 0.f;
    const int arow = tid >> 2, akq = tid & 3;
    const int bcq = tid % 16, bkr = tid / 16;
    for (int k0 = 0; k0 < K; k0 += BK) {
#pragma unroll
        for (int i = 0; i < 2; ++i) {
            int row = arow + i * 64;
            float4 a = *(const float4*)(A + (size_t)(tm0 + row) * lda + k0 + akq * 4);
            As[akq * 4 + 0][row] = a.x; As[akq * 4 + 1][row] = a.y;
            As[akq * 4 + 2][row] = a.z; As[akq * 4 + 3][row] = a.w;
        }
        {
            float4 b4 = *(const float4*)(B + (size_t)(k0 + bkr) * ldb + tn0 + bcq * 4);
            *(float4*)&Bs[bkr][bcq * 4] = b4;
        }
        __syncthreads();
#pragma unroll
        for (int k = 0; k < BK; ++k) {
            float av[TM], bv[TN];
#pragma unroll
            for (int i = 0; i < TM; ++i) av[i] = As[k][ty * TM + i];
#pragma unroll
            for (int j = 0; j < TN; ++j) bv[j] = Bs[k][tx * TN + j];
#pragma unroll
            for (int i = 0; i < TM; ++i)
#pragma unroll
                for (int j = 0; j < TN; ++j)
                    acc[i][j] = fmaf(av[i], bv[j], acc[i][j]);
        }
        __syncthreads();
    }
#pragma unroll
    for (int i = 0; i < TM; ++i) {
        size_t r = (size_t)tm0 + ty * TM + i;
        int c = tn0 + tx * TN;
        float t0 = acc[i][0], t1 = acc[i][1], t2 = acc[i][2], t3 = acc[i][3];
        float* cp = C + r * ldc + c;
        if (ACC) {
            float4 p = *(const float4*)cp;
            t0 += p.x; t1 += p.y; t2 += p.z; t3 += p.w;
        }
        if (RELU) {
            t0 = fmaxf(t0, 0.f); t1 = fmaxf(t1, 0.f);
            t2 = fmaxf(t2, 0.f); t3 = fmaxf(t3, 0.f);
        }
        float4 v; v.x = t0; v.y = t1; v.z = t2; v.w = t3;
        *(float4*)cp = v;
    }
}

// skip_1 = x (x) W_fst, into SS cols 512..575 (ld 576)
__global__ void s1_k(const float* __restrict__ x, const float* __restrict__ Wfst,
                     float* __restrict__ dst)
{
    int idx = blockIdx.x * blockDim.x + threadIdx.x;
    int r = idx >> 4, c4 = idx & 15;
    float xv = x[r];
    float4 wv = *(const float4*)(Wfst + c4 * 4);
    float4 o; o.x = xv * wv.x; o.y = xv * wv.y; o.z = xv * wv.z; o.w = xv * wv.w;
    *(float4*)(dst + (size_t)r * 576 + c4 * 4) = o;
}

// Per-sample BN over nodes (256 ch), fp64 stats. grid=(nb,4), blk=256.
__global__ __launch_bounds__(256)
void bn_k(const float* __restrict__ src, int lds_, float* __restrict__ dst, int ldd,
          const float* __restrict__ g, const float* __restrict__ bt)
{
    const int b = blockIdx.x, c0 = blockIdx.y * 64;
    const int cl = threadIdx.x & 63, ph = threadIdx.x >> 6;
    const int c = c0 + cl;
    const float* Sb = src + (size_t)b * NNODE * lds_;
    float* Db = dst + (size_t)b * NNODE * ldd;
    double sum = 0.0, sq = 0.0;
    for (int n = ph; n < NNODE; n += 4) {
        double v = (double)Sb[(size_t)n * lds_ + c];
        sum += v; sq += v * v;
    }
    __shared__ double ssum[4][64], ssq[4][64];
    __shared__ float sscale[64], sshift[64];
    ssum[ph][cl] = sum; ssq[ph][cl] = sq;
    __syncthreads();
    if (ph == 0) {
        double s = ssum[0][cl] + ssum[1][cl] + ssum[2][cl] + ssum[3][cl];
        double q = ssq[0][cl] + ssq[1][cl] + ssq[2][cl] + ssq[3][cl];
        double m = s * (1.0 / NNODE);
        double var = q * (1.0 / NNODE) - m * m;
        double sc = (double)g[c] / sqrt(var + 1e-5);
        sscale[cl] = (float)sc;
        sshift[cl] = (float)((double)bt[c] - m * sc);
    }
    __syncthreads();
    float sc = sscale[cl], sh = sshift[cl];
    for (int n = ph; n < NNODE; n += 4)
        Db[(size_t)n * ldd + c] = fmaf(Sb[(size_t)n * lds_ + c], sc, sh);
}

__global__ __launch_bounds__(256)
void head_k(const float* __restrict__ H, const float* __restrict__ Wff2,
            const float* __restrict__ bff2, const float* __restrict__ Wfin,
            float* __restrict__ out)
{
    __shared__ float wsm[128];
    __shared__ float red[256];
    const int b = blockIdx.x, n = threadIdx.x;
    if (n < 128) wsm[n] = Wff2[n];
    __syncthreads();
    const float* h = H + ((size_t)b * NNODE + n) * 128;
    float dot = 0.f;
#pragma unroll
    for (int k = 0; k < 128; k += 4) {
        float4 hv = *(const float4*)(h + k);
        dot = fmaf(hv.x, wsm[k + 0], dot); dot = fmaf(hv.y, wsm[k + 1], dot);
        dot = fmaf(hv.z, wsm[k + 2], dot); dot = fmaf(hv.w, wsm[k + 3], dot);
    }
    float logit = (dot + bff2[0]) * Wfin[0];
    red[n] = logit; __syncthreads();
    for (int s = 128; s > 0; s >>= 1) {
        if (n < s) red[n] = fmaxf(red[n], red[n + s]);
        __syncthreads();
    }
    float mx = red[0]; __syncthreads();
    float e = expf(logit - mx);
    red[n] = e; __syncthreads();
    for (int s = 128; s > 0; s >>= 1) {
        if (n < s) red[n] += red[n + s];
        __syncthreads();
    }
    out[(size_t)b * NNODE + n] = e / red[0];
}

__global__ void zero_k(float* p, int n)
{
    int i = blockIdx.x * blockDim.x + threadIdx.x;
    if (i < n) p[i] = 0.f;
}

// ---------------------------------------------------------------------------
static inline void g(bool relu, bool acc, int M, int N, int K,
    const float* A, int lda, long long sA,
    const float* B, int ldb, long long sB,
    float* C, int ldc, long long sC, int nb, hipStream_t s)
{
    dim3 grid(N / 64, M / 128, nb), blk(256);
    if ( relu &&  acc) gemm_k<true,  true ><<<grid, blk, 0, s>>>(M,N,K,A,lda,sA,B,ldb,sB,C,ldc,sC);
    if ( relu && !acc) gemm_k<true,  false><<<grid, blk, 0, s>>>(M,N,K,A,lda,sA,B,ldb,sB,C,ldc,sC);
    if (!relu &&  acc) gemm_k<false, true ><<<grid, blk, 0, s>>>(M,N,K,A,lda,sA,B,ldb,sB,C,ldc,sC);
    if (!relu && !acc) gemm_k<false, false><<<grid, blk, 0, s>>>(M,N,K,A,lda,sA,B,ldb,sB,C,ldc,sC);
}

static inline void wk2(bool relu, bool acc, int M, int N, int K,
                       const float* A, int lda,
                       const half_t* Bh, const half_t* Bl, int ldb,
                       float* C, int ldc, const float* bias, hipStream_t s)
{
    dim3 grid(N / 128, M / 128, 1), blk(256);
    if (relu  &&  acc) gemm_wk2<true,  true ><<<grid, blk, 0, s>>>(M, N, K, A, lda, Bh, Bl, ldb, C, ldc, bias);
    if (relu  && !acc) gemm_wk2<true,  false><<<grid, blk, 0, s>>>(M, N, K, A, lda, Bh, Bl, ldb, C, ldc, bias);
    if (!relu &&  acc) gemm_wk2<false, true ><<<grid, blk, 0, s>>>(M, N, K, A, lda, Bh, Bl, ldb, C, ldc, bias);
    if (!relu && !acc) gemm_wk2<false, false><<<grid, blk, 0, s>>>(M, N, K, A, lda, Bh, Bl, ldb, C, ldc, bias);
}

struct Ctx {
    const half_t *ajh, *ajl;       // f16-2 adj
    half_t *XT;                    // XT slot (capacity 512*CH halves = 256 ch)
    int RSc, nb;
    hipStream_t s;
};

static inline void ak2(const Ctx& cx, int Cch, const float* X, int ldx,
                       float* Cout, int ldc, long long sC)
{
    half_t* X0 = cx.XT;
    half_t* X1 = X0 + (size_t)Cch * cx.RSc;
    xpose2_k<<<dim3(cx.RSc / 32, Cch / 32), 256, 0, cx.s>>>(X, ldx, cx.RSc, X0, X1);
    gemm_ak2<<<dim3(Cch / 128, 2, cx.nb), 256, 0, cx.s>>>(NNODE, cx.RSc,
        cx.ajh, cx.ajl, X0, X1, Cout, ldc, sC);
}

struct Weights {
    const float *adj, *W_fst, *W_snd, *W_thrd, *W_thrdb, *W_frth, *W_ffth;
    const float *bn6_g, *bn6_b, *W_svth, *bn8_g, *bn8_b, *W_nnth, *W_tnth;
    const float *W_lvnth, *bn12_g, *bn12_b, *W_ff1, *b_ff1, *W_ff2, *b_ff2, *W_final;
};
struct WT2 { half_t *h, *l; };

static void run_chunk(const float* x, float* out, float* ws, int nb,
                      const Weights& W, const WT2* V, const Ctx& cx0,
                      hipStream_t stream)
{
    const int RSc = nb * NNODE;
    const size_t CH = (size_t)RSc;
    float* SS = ws;                  // [S3|S2|S1] ld 576
    float* S3 = SS;
    float* S2 = SS + 256;
    float* S1 = SS + 512;
    float* U  = ws + 576 * CH;       // 1024-wide; packed Q slots early
    float* Q0 = U;
    float* Q1 = U + 256 * CH;
    float* Q2 = U + 512 * CH;
    float* Q3 = U + 768 * CH;
    float* R  = ws + 1600 * CH;      // 256-wide scratch (A5/B2), within R512
    float* R512 = ws + 1600 * CH;    // 512-wide scratch (T6, Gt halves)
    half_t* XTb = (half_t*)(ws + 2112 * CH);  // 512*CH halves

    Ctx cx = cx0; cx.XT = XTb; cx.RSc = RSc; cx.nb = nb; cx.s = stream;
    const float* adj = W.adj;
    const long long SN = (long long)NNODE;
    const long long S576 = SN * 576, S256 = SN * 256, S1024 = SN * 1024,
                    S128 = SN * 128, S64 = SN * 64;

    // ======== pre-bn6: fp32 VALU (round-5-validated arithmetic) ========
    s1_k<<<RSc / 16, 256, 0, stream>>>(x, W.W_fst, S1);
    g(0,0, NNODE,64,NNODE, adj,NNODE,0, S1,576,S576, Q0,256,S256, nb, stream);
    g(1,0, RSc,64,64, Q0,256,0, W.W_snd,64,0, Q1,64,0, 1, stream);
    g(0,0, NNODE,64,NNODE, adj,NNODE,0, Q1,64,S64, Q0+64,256,S256, nb, stream);
    g(1,0, RSc,128,128, Q0,256,0, W.W_thrd,128,0, Q2,128,0, 1, stream);
    g(0,0, NNODE,128,NNODE, adj,NNODE,0, Q2,128,S128, Q0+128,256,S256, nb, stream);
    g(1,0, RSc,256,256, Q0,256,0, W.W_thrdb,256,0, Q1,256,0, 1, stream);
    g(0,0, NNODE,256,NNODE, adj,NNODE,0, Q1,256,S256, Q2,256,S256, nb, stream);
    g(1,0, RSc,256,256, Q2,256,0, W.W_frth,256,0, Q3,256,0, 1, stream);
    g(0,0, RSc,256,64,  S1,576,0, W.W_ffth,          256,0, S2,576,0, 1, stream);
    g(0,1, RSc,256,256, Q3,256,0, W.W_ffth + 64*256, 256,0, S2,576,0, 1, stream);
    bn_k<<<dim3(nb, 4), 256, 0, stream>>>(S2, 576, S2, 576, W.bn6_g, W.bn6_b);

    // ======== post-bn6: f16-2 MFMA (bounded values) ========
    // 11. A5 = adj@S2 -> R
    ak2(cx, 256, S2, 576, R, 256, S256);
    // 12. T5 = relu(A5 @ W_svth) -> U+512 (ld 1024)
    wk2(1, 0, RSc, 256, 256, R, 256, V[0].h, V[0].l, 256, U + 512, 1024, 0, stream);
    // 13. bn8: B2 -> R ; B5 in place
    bn_k<<<dim3(nb, 4), 256, 0, stream>>>(S2, 576, R, 256, W.bn8_g, W.bn8_b);
    bn_k<<<dim3(nb, 4), 256, 0, stream>>>(U + 512, 1024, U + 512, 1024,
                                          W.bn8_g + 256, W.bn8_b + 256);
    // 14. A6a = adj@B2 -> U ; A6b = adj@B5 -> U+256
    ak2(cx, 256, R, 256, U, 1024, S1024);
    ak2(cx, 256, U + 512, 1024, U + 256, 1024, S1024);
    // 15. T6 = relu([A6a|A6b] @ W_nnth), ONE N=512 GEMM -> R512 (ld 512)
    wk2(1, 0, RSc, 512, 512, U, 1024, V[1].h, V[1].l, 512, R512, 512, 0, stream);
    // 16. A7ta = adj@T6a -> U+512 ; A7tb = adj@T6b -> U+768
    ak2(cx, 256, R512,       512, U + 512, 1024, S1024);
    ak2(cx, 256, R512 + 256, 512, U + 768, 1024, S1024);
    // 17. two N=512 halves: Gt_h = relu(U @ Wtnth[:,h*512..]) -> R512 ;
    //     S3 (+)= Gt_h @ W_lvnth[h*512 : h*512+512]
    for (int h = 0; h < 2; ++h) {
        wk2(1, 0, RSc, 512, 1024, U, 1024,
            V[2].h + (size_t)h * 512 * 1024, V[2].l + (size_t)h * 512 * 1024, 1024,
            R512, 512, 0, stream);
        wk2(0, h > 0, RSc, 256, 512, R512, 512,
            V[3].h + (size_t)h * 512, V[3].l + (size_t)h * 512, 1280,
            S3, 576, 0, stream);
    }
    // 18. S3 += S2 @ W_lvnth[1024:1280] ; bn12
    wk2(0, 1, RSc, 256, 256, S2, 576,
        V[3].h + 1024, V[3].l + 1024, 1280, S3, 576, 0, stream);
    bn_k<<<dim3(nb, 4), 256, 0, stream>>>(S3, 576, S3, 576, W.bn12_g, W.bn12_b);
    // 19. H = relu(SS @ W_ff1 + b_ff1) -> U (ld 128)
    wk2(1, 0, RSc, 128, 576, SS, 576, V[4].h, V[4].l, 576, U, 128, W.b_ff1, stream);
    // 20. head + softmax
    head_k<<<nb, 256, 0, stream>>>(U, W.W_ff2, W.b_ff2, W.W_final, out);
}

extern "C" void kernel_launch(void* const* d_in, const int* in_sizes, int n_in,
                              void* d_out, int out_size, void* d_ws, size_t ws_size,
                              hipStream_t stream)
{
    const float* x = (const float*)d_in[0];
    Weights W;
    W.adj = (const float*)d_in[1];   W.W_fst  = (const float*)d_in[2];
    W.W_snd = (const float*)d_in[3]; W.W_thrd = (const float*)d_in[4];
    W.W_thrdb = (const float*)d_in[5]; W.W_frth = (const float*)d_in[6];
    W.W_ffth = (const float*)d_in[7]; W.bn6_g = (const float*)d_in[8];
    W.bn6_b = (const float*)d_in[9];  W.W_svth = (const float*)d_in[10];
    W.bn8_g = (const float*)d_in[11]; W.bn8_b = (const float*)d_in[12];
    W.W_nnth = (const float*)d_in[13]; W.W_tnth = (const float*)d_in[14];
    W.W_lvnth = (const float*)d_in[15]; W.bn12_g = (const float*)d_in[16];
    W.bn12_b = (const float*)d_in[17]; W.W_ff1 = (const float*)d_in[18];
    W.b_ff1 = (const float*)d_in[19]; W.W_ff2 = (const float*)d_in[20];
    W.b_ff2 = (const float*)d_in[21]; W.W_final = (const float*)d_in[22];
    float* out = (float*)d_out;

    // f16-2 split weights (post-bn6): W_svth, W_nnth, W_tnth, W_lvnth, W_ff1
    const size_t szs[5] = {65536, 262144, 1048576, 327680, 73728};
    const size_t ADJSZ = 65536;
    size_t tot_halves = 2 * ADJSZ;
    for (int i = 0; i < 5; ++i) tot_halves += 2 * szs[i];
    const size_t split_bytes = tot_halves * 2;

    // arena = 2368 fp32 channels (576 SS + 1024 U + 512 R512 + 256 XT slot)
    int nb = NBATCH;
    while (nb > 0 && (size_t)2368 * nb * NNODE * 4 + split_bytes > ws_size) nb -= 32;
    if (nb <= 0) {
        zero_k<<<(out_size + 255) / 256, 256, 0, stream>>>(out, out_size);
        return;
    }

    float* ws = (float*)d_ws;
    half_t* hb = (half_t*)(ws + (size_t)2368 * nb * NNODE);
    WT2 V[5];
    size_t off = 0;
    for (int i = 0; i < 5; ++i) {
        V[i].h = hb + off; off += szs[i];
        V[i].l = hb + off; off += szs[i];
    }
    half_t* ajh = hb + off; off += ADJSZ;
    half_t* ajl = hb + off; off += ADJSZ;

    // one-time weight transpose+split (f16 2-term), post-bn6 weights only
    const float* wp[5] = {W.W_svth, W.W_nnth, W.W_tnth, W.W_lvnth, W.W_ff1};
    const int wkk[5] = {256, 512, 1024, 1280, 576};
    const int wnn[5] = {256, 512, 1024, 256, 128};
    for (int i = 0; i < 5; ++i)
        wsplit2_k<<<dim3(wkk[i] / 32, wnn[i] / 32), 256, 0, stream>>>(
            wp[i], wkk[i], wnn[i], V[i].h, V[i].l);
    asplit2_k<<<256, 256, 0, stream>>>(W.adj, ajh, ajl, 65536);

    Ctx cx0; cx0.ajh = ajh; cx0.ajl = ajl;
    cx0.XT = nullptr; cx0.RSc = 0; cx0.nb = 0; cx0.s = stream;

    for (int b0 = 0; b0 < NBATCH; b0 += nb) {
        int nbc = (NBATCH - b0 < nb) ? (NBATCH - b0) : nb;
        run_chunk(x + (size_t)b0 * NNODE, out + (size_t)b0 * NNODE,
                  ws, nbc, W, V, cx0, stream);
    }
}

// Round 15
// 2887.171 us; speedup vs baseline: 1.1513x; 1.1513x over previous
//
#include <hip/hip_runtime.h>
#include <math.h>

#define NBATCH 256
#define NNODE 256
#define FCLAMP 60000.0f   // tripwire; post-bn6 values are ~1e3 max

typedef float f32x4 __attribute__((ext_vector_type(4)));
typedef _Float16 half_t;
typedef half_t f16x8 __attribute__((ext_vector_type(8)));
typedef half_t f16x4 __attribute__((ext_vector_type(4)));

// f16 2-term split: v = h + l + O(2^-22 * v); range-safe for |v| < 60000.
__device__ __forceinline__ void split2(float v, half_t& h, half_t& l)
{
    v = fminf(fmaxf(v, -FCLAMP), FCLAMP);
    half_t hh = (half_t)v;
    h = hh;
    l = (half_t)(v - (float)hh);
}

// ===========================================================================
// f16 2-term split GEMM, LDS-staged both operands (round-13 proven layout)
// + T14 async-STAGE split: next-tile global loads issued right after
// barrier #1 so their latency retires under the MFMA phase (m249: +3% on
// reg-staged 2-phase GEMM). Split2 VALU runs in the write phase of the NEXT
// iteration, by which time the loads have landed.
// Block 128x128, 4 waves (2x2), wave 64x64 = 4x4 frags of 16x16x32, BK=32.
// [128][40] half LDS: frag b128 reads 2-way bank-aliased (free, m136).
// 3 MFMA per product {ah*bh, ah*bl, al*bh}; fp32 accum. MFMA order per
// accumulator identical to rounds 12/13 -> bit-identical output.
// Frag family (m89/m91/m97-verified): a: lane=(row l&15, k=(l>>4)*8+j);
// b: lane=(col l&15, same k); d: row=(l>>4)*4+r, col=l&15.
// ===========================================================================
template<bool RELU, bool ACC>
__global__ __launch_bounds__(256)
void gemm_wk2(int M, int N, int K,
              const float* __restrict__ A, int lda,
              const half_t* __restrict__ Bh, const half_t* __restrict__ Bl, int ldb,
              float* __restrict__ C, int ldc,
              const float* __restrict__ bias)
{
    __shared__ half_t Ash[128][40], Asl[128][40];
    __shared__ half_t Bsh[128][40], Bsl[128][40];

    const int tid  = threadIdx.x;
    const int tn0  = blockIdx.x * 128;
    const int tm0  = blockIdx.y * 128;
    const int lane = tid & 63;
    const int w    = tid >> 6;
    const int wr   = (w >> 1) * 64, wc = (w & 1) * 64;
    const int lr   = lane & 15, ko = lane >> 4;

    const int srow = tid >> 1;          // staging row 0..127
    const int skh  = (tid & 1) * 16;    // staging k-half 0/16

    f32x4 acc[4][4];
#pragma unroll
    for (int i = 0; i < 4; ++i)
#pragma unroll
        for (int j = 0; j < 4; ++j) acc[i][j] = (f32x4){0.f, 0.f, 0.f, 0.f};

    const float*  aP  = A  + (size_t)(tm0 + srow) * lda + skh;
    const half_t* bhP = Bh + (size_t)(tn0 + srow) * ldb + skh;
    const half_t* blP = Bl + (size_t)(tn0 + srow) * ldb + skh;

    // staged-tile registers (tile kb), preloaded before the loop
    float4 ra0, ra1, ra2, ra3;
    f16x8  rbh0, rbh1, rbl0, rbl1;
    {
        const float4* ap = (const float4*)aP;
        ra0 = ap[0]; ra1 = ap[1]; ra2 = ap[2]; ra3 = ap[3];
        const f16x8* ph = (const f16x8*)bhP;
        const f16x8* pl = (const f16x8*)blP;
        rbh0 = ph[0]; rbh1 = ph[1]; rbl0 = pl[0]; rbl1 = pl[1];
    }

    for (int kb = 0; kb < K; kb += 32) {
        // ---- write phase: split2 staged A regs, write A+B tiles to LDS ----
        {
            float vv[16] = {ra0.x, ra0.y, ra0.z, ra0.w, ra1.x, ra1.y, ra1.z, ra1.w,
                            ra2.x, ra2.y, ra2.z, ra2.w, ra3.x, ra3.y, ra3.z, ra3.w};
            half_t th[16], tl[16];
#pragma unroll
            for (int j = 0; j < 16; ++j)
                split2(vv[j], th[j], tl[j]);
            *(f16x8*)&Ash[srow][skh]     = *(f16x8*)&th[0];
            *(f16x8*)&Ash[srow][skh + 8] = *(f16x8*)&th[8];
            *(f16x8*)&Asl[srow][skh]     = *(f16x8*)&tl[0];
            *(f16x8*)&Asl[srow][skh + 8] = *(f16x8*)&tl[8];
            *(f16x8*)&Bsh[srow][skh]     = rbh0;
            *(f16x8*)&Bsh[srow][skh + 8] = rbh1;
            *(f16x8*)&Bsl[srow][skh]     = rbl0;
            *(f16x8*)&Bsl[srow][skh + 8] = rbl1;
        }
        __syncthreads();                        // barrier #1: tiles visible

        // ---- issue NEXT-tile global loads: retire under the MFMA phase ----
        if (kb + 32 < K) {
            const float4* ap = (const float4*)(aP + kb + 32);
            ra0 = ap[0]; ra1 = ap[1]; ra2 = ap[2]; ra3 = ap[3];
            const f16x8* ph = (const f16x8*)(bhP + kb + 32);
            const f16x8* pl = (const f16x8*)(blP + kb + 32);
            rbh0 = ph[0]; rbh1 = ph[1]; rbl0 = pl[0]; rbl1 = pl[1];
        }

        // ---- fragment reads ----
        f16x8 ah[4], al[4], bh[4], bl[4];
#pragma unroll
        for (int mf = 0; mf < 4; ++mf) {
            int r = wr + mf * 16 + lr;
            ah[mf] = *(const f16x8*)&Ash[r][ko * 8];
            al[mf] = *(const f16x8*)&Asl[r][ko * 8];
        }
#pragma unroll
        for (int nf = 0; nf < 4; ++nf) {
            int c = wc + nf * 16 + lr;
            bh[nf] = *(const f16x8*)&Bsh[c][ko * 8];
            bl[nf] = *(const f16x8*)&Bsl[c][ko * 8];
        }
        // ---- MFMA: 3 per product (same order as rounds 12/13) ----
#pragma unroll
        for (int nf = 0; nf < 4; ++nf) {
#pragma unroll
            for (int mf = 0; mf < 4; ++mf) {
                acc[mf][nf] = __builtin_amdgcn_mfma_f32_16x16x32_f16(ah[mf], bh[nf], acc[mf][nf], 0, 0, 0);
                acc[mf][nf] = __builtin_amdgcn_mfma_f32_16x16x32_f16(ah[mf], bl[nf], acc[mf][nf], 0, 0, 0);
                acc[mf][nf] = __builtin_amdgcn_mfma_f32_16x16x32_f16(al[mf], bh[nf], acc[mf][nf], 0, 0, 0);
            }
        }
        __syncthreads();                        // barrier #2: reads done
    }

#pragma unroll
    for (int mf = 0; mf < 4; ++mf) {
        int r0 = tm0 + wr + mf * 16 + ko * 4;
#pragma unroll
        for (int nf = 0; nf < 4; ++nf) {
            int c = tn0 + wc + nf * 16 + lr;
            float bsv = bias ? bias[c] : 0.f;
#pragma unroll
            for (int r = 0; r < 4; ++r) {
                float* cp = C + (size_t)(r0 + r) * ldc + c;
                float t = acc[mf][nf][r] + bsv;
                if (ACC) t += *cp;
                if (RELU) t = fmaxf(t, 0.f);
                *cp = t;
            }
        }
    }
}

// ===========================================================================
// f16 2-term adj-GEMM (round-13 direct-global form): Out[z] = adj @ X[z].
// adj pre-split [256][256]; X pre-transposed+split XT[C][RSc].
// ===========================================================================
__global__ __launch_bounds__(256)
void gemm_ak2(int K, int ldxt,
              const half_t* __restrict__ Ah, const half_t* __restrict__ Al,
              const half_t* __restrict__ XTh, const half_t* __restrict__ XTl,
              float* __restrict__ C, int ldc, long long sC)
{
    const int z = blockIdx.z;
    C += sC * z;
    const int zoff = z * NNODE;
    const int tid  = threadIdx.x;
    const int tn0  = blockIdx.x * 128;
    const int tm0  = blockIdx.y * 128;
    const int lane = tid & 63;
    const int w    = tid >> 6;
    const int wr   = (w >> 1) * 64, wc = (w & 1) * 64;
    const int lr   = lane & 15, ko = lane >> 4;

    f32x4 acc[4][4];
#pragma unroll
    for (int i = 0; i < 4; ++i)
#pragma unroll
        for (int j = 0; j < 4; ++j) acc[i][j] = (f32x4){0.f, 0.f, 0.f, 0.f};

    size_t aoff[4], boff[4];
#pragma unroll
    for (int mf = 0; mf < 4; ++mf)
        aoff[mf] = (size_t)(tm0 + wr + mf * 16 + lr) * NNODE + ko * 8;
#pragma unroll
    for (int nf = 0; nf < 4; ++nf)
        boff[nf] = (size_t)(tn0 + wc + nf * 16 + lr) * ldxt + zoff + ko * 8;

    for (int kb = 0; kb < K; kb += 32) {
        f16x8 ah[4], al[4];
#pragma unroll
        for (int mf = 0; mf < 4; ++mf) {
            ah[mf] = *(const f16x8*)(Ah + aoff[mf] + kb);
            al[mf] = *(const f16x8*)(Al + aoff[mf] + kb);
        }
#pragma unroll
        for (int nf = 0; nf < 4; ++nf) {
            f16x8 bh = *(const f16x8*)(XTh + boff[nf] + kb);
            f16x8 bl = *(const f16x8*)(XTl + boff[nf] + kb);
#pragma unroll
            for (int mf = 0; mf < 4; ++mf) {
                acc[mf][nf] = __builtin_amdgcn_mfma_f32_16x16x32_f16(ah[mf], bh, acc[mf][nf], 0, 0, 0);
                acc[mf][nf] = __builtin_amdgcn_mfma_f32_16x16x32_f16(ah[mf], bl, acc[mf][nf], 0, 0, 0);
                acc[mf][nf] = __builtin_amdgcn_mfma_f32_16x16x32_f16(al[mf], bh, acc[mf][nf], 0, 0, 0);
            }
        }
    }

#pragma unroll
    for (int mf = 0; mf < 4; ++mf) {
        int r0 = tm0 + wr + mf * 16 + ko * 4;
#pragma unroll
        for (int nf = 0; nf < 4; ++nf) {
            int c = tn0 + wc + nf * 16 + lr;
#pragma unroll
            for (int r = 0; r < 4; ++r)
                C[(size_t)(r0 + r) * ldc + c] = acc[mf][nf][r];
        }
    }
}

// Transpose + f16-2 split: X (Mtot x C, ld) -> T[C][Mtot] x 2 terms.
__global__ __launch_bounds__(256)
void xpose2_k(const float* __restrict__ X, int ld, int Mtot,
              half_t* __restrict__ Th, half_t* __restrict__ Tl)
{
    __shared__ float tile[32][33];
    const int m0 = blockIdx.x * 32, c0 = blockIdx.y * 32;
    const int t = threadIdx.x;
    {
        int r = t >> 3, cc = (t & 7) * 4;
        float4 v = *(const float4*)(X + (size_t)(m0 + r) * ld + c0 + cc);
        tile[r][cc + 0] = v.x; tile[r][cc + 1] = v.y;
        tile[r][cc + 2] = v.z; tile[r][cc + 3] = v.w;
    }
    __syncthreads();
    {
        int cr = t >> 3, mc = (t & 7) * 4;
        f16x4 h, l;
#pragma unroll
        for (int j = 0; j < 4; ++j) {
            half_t hh, ll;
            split2(tile[mc + j][cr], hh, ll);
            h[j] = hh; l[j] = ll;
        }
        size_t o = (size_t)(c0 + cr) * Mtot + m0 + mc;
        *(f16x4*)(Th + o) = h;
        *(f16x4*)(Tl + o) = l;
    }
}

// W [K][N] fp32 -> WT [N][K] f16 2-term
__global__ __launch_bounds__(256)
void wsplit2_k(const float* __restrict__ W, int K, int N,
               half_t* __restrict__ Th, half_t* __restrict__ Tl)
{
    __shared__ float tile[32][33];
    const int k0 = blockIdx.x * 32, n0 = blockIdx.y * 32;
    const int t = threadIdx.x;
    {
        int kr = t >> 3, nc = (t & 7) * 4;
        float4 v = *(const float4*)(W + (size_t)(k0 + kr) * N + n0 + nc);
        tile[kr][nc + 0] = v.x; tile[kr][nc + 1] = v.y;
        tile[kr][nc + 2] = v.z; tile[kr][nc + 3] = v.w;
    }
    __syncthreads();
    {
        int nr = t >> 3, kc = (t & 7) * 4;
        f16x4 h, l;
#pragma unroll
        for (int j = 0; j < 4; ++j) {
            half_t hh, ll;
            split2(tile[kc + j][nr], hh, ll);
            h[j] = hh; l[j] = ll;
        }
        size_t o = (size_t)(n0 + nr) * K + k0 + kc;
        *(f16x4*)(Th + o) = h;
        *(f16x4*)(Tl + o) = l;
    }
}

__global__ void asplit2_k(const float* __restrict__ A,
                          half_t* __restrict__ Ah, half_t* __restrict__ Al, int n)
{
    int i = blockIdx.x * blockDim.x + threadIdx.x;
    if (i < n) {
        half_t h, l;
        split2(A[i], h, l);
        Ah[i] = h; Al[i] = l;
    }
}

// ===========================================================================
// fp32 tiled GEMM (BM=128, BN=64, BK=16) — the round-5-validated arithmetic.
// Used for the ENTIRE pre-bn6 chain (error-amplifying region) + C=64 stages.
// ===========================================================================
template<bool RELU, bool ACC>
__global__ __launch_bounds__(256)
void gemm_k(int M, int N, int K,
            const float* __restrict__ A, int lda, long long sA,
            const float* __restrict__ B, int ldb, long long sB,
            float* __restrict__ C, int ldc, long long sC)
{
    constexpr int BM = 128, BN_ = 64, BK = 16, TM = 8, TN = 4;
    constexpr int TX = BN_ / TN;
    __shared__ float As[BK][BM + 4];
    __shared__ float Bs[BK][BN_ + 4];
    const int bz = blockIdx.z;
    A += sA * bz; B += sB * bz; C += sC * bz;
    const int tn0 = blockIdx.x * BN_, tm0 = blockIdx.y * BM;
    const int tid = threadIdx.x;
    const int tx = tid % TX, ty = tid / TX;
    float acc[TM][TN];
#pragma unroll
    for (int i = 0; i < TM; ++i)
#pragma unroll
        for (int j = 0; j < TN; ++j) acc[i][j] = 0.f;
    const int arow = tid >> 2, akq = tid & 3;
    const int bcq = tid % 16, bkr = tid / 16;
    for (int k0 = 0; k0 < K; k0 += BK) {
#pragma unroll
        for (int i = 0; i < 2; ++i) {
            int row = arow + i * 64;
            float4 a = *(const float4*)(A + (size_t)(tm0 + row) * lda + k0 + akq * 4);
            As[akq * 4 + 0][row] = a.x; As[akq * 4 + 1][row] = a.y;
            As[akq * 4 + 2][row] = a.z; As[akq * 4 + 3][row] = a.w;
        }
        {
            float4 b4 = *(const float4*)(B + (size_t)(k0 + bkr) * ldb + tn0 + bcq * 4);
            *(float4*)&Bs[bkr][bcq * 4] = b4;
        }
        __syncthreads();
#pragma unroll
        for (int k = 0; k < BK; ++k) {
            float av[TM], bv[TN];
#pragma unroll
            for (int i = 0; i < TM; ++i) av[i] = As[k][ty * TM + i];
#pragma unroll
            for (int j = 0; j < TN; ++j) bv[j] = Bs[k][tx * TN + j];
#pragma unroll
            for (int i = 0; i < TM; ++i)
#pragma unroll
                for (int j = 0; j < TN; ++j)
                    acc[i][j] = fmaf(av[i], bv[j], acc[i][j]);
        }
        __syncthreads();
    }
#pragma unroll
    for (int i = 0; i < TM; ++i) {
        size_t r = (size_t)tm0 + ty * TM + i;
        int c = tn0 + tx * TN;
        float t0 = acc[i][0], t1 = acc[i][1], t2 = acc[i][2], t3 = acc[i][3];
        float* cp = C + r * ldc + c;
        if (ACC) {
            float4 p = *(const float4*)cp;
            t0 += p.x; t1 += p.y; t2 += p.z; t3 += p.w;
        }
        if (RELU) {
            t0 = fmaxf(t0, 0.f); t1 = fmaxf(t1, 0.f);
            t2 = fmaxf(t2, 0.f); t3 = fmaxf(t3, 0.f);
        }
        float4 v; v.x = t0; v.y = t1; v.z = t2; v.w = t3;
        *(float4*)cp = v;
    }
}

// skip_1 = x (x) W_fst, into SS cols 512..575 (ld 576)
__global__ void s1_k(const float* __restrict__ x, const float* __restrict__ Wfst,
                     float* __restrict__ dst)
{
    int idx = blockIdx.x * blockDim.x + threadIdx.x;
    int r = idx >> 4, c4 = idx & 15;
    float xv = x[r];
    float4 wv = *(const float4*)(Wfst + c4 * 4);
    float4 o; o.x = xv * wv.x; o.y = xv * wv.y; o.z = xv * wv.z; o.w = xv * wv.w;
    *(float4*)(dst + (size_t)r * 576 + c4 * 4) = o;
}

// Per-sample BN over nodes (256 ch), fp64 stats. grid=(nb,4), blk=256.
__global__ __launch_bounds__(256)
void bn_k(const float* __restrict__ src, int lds_, float* __restrict__ dst, int ldd,
          const float* __restrict__ g, const float* __restrict__ bt)
{
    const int b = blockIdx.x, c0 = blockIdx.y * 64;
    const int cl = threadIdx.x & 63, ph = threadIdx.x >> 6;
    const int c = c0 + cl;
    const float* Sb = src + (size_t)b * NNODE * lds_;
    float* Db = dst + (size_t)b * NNODE * ldd;
    double sum = 0.0, sq = 0.0;
    for (int n = ph; n < NNODE; n += 4) {
        double v = (double)Sb[(size_t)n * lds_ + c];
        sum += v; sq += v * v;
    }
    __shared__ double ssum[4][64], ssq[4][64];
    __shared__ float sscale[64], sshift[64];
    ssum[ph][cl] = sum; ssq[ph][cl] = sq;
    __syncthreads();
    if (ph == 0) {
        double s = ssum[0][cl] + ssum[1][cl] + ssum[2][cl] + ssum[3][cl];
        double q = ssq[0][cl] + ssq[1][cl] + ssq[2][cl] + ssq[3][cl];
        double m = s * (1.0 / NNODE);
        double var = q * (1.0 / NNODE) - m * m;
        double sc = (double)g[c] / sqrt(var + 1e-5);
        sscale[cl] = (float)sc;
        sshift[cl] = (float)((double)bt[c] - m * sc);
    }
    __syncthreads();
    float sc = sscale[cl], sh = sshift[cl];
    for (int n = ph; n < NNODE; n += 4)
        Db[(size_t)n * ldd + c] = fmaf(Sb[(size_t)n * lds_ + c], sc, sh);
}

__global__ __launch_bounds__(256)
void head_k(const float* __restrict__ H, const float* __restrict__ Wff2,
            const float* __restrict__ bff2, const float* __restrict__ Wfin,
            float* __restrict__ out)
{
    __shared__ float wsm[128];
    __shared__ float red[256];
    const int b = blockIdx.x, n = threadIdx.x;
    if (n < 128) wsm[n] = Wff2[n];
    __syncthreads();
    const float* h = H + ((size_t)b * NNODE + n) * 128;
    float dot = 0.f;
#pragma unroll
    for (int k = 0; k < 128; k += 4) {
        float4 hv = *(const float4*)(h + k);
        dot = fmaf(hv.x, wsm[k + 0], dot); dot = fmaf(hv.y, wsm[k + 1], dot);
        dot = fmaf(hv.z, wsm[k + 2], dot); dot = fmaf(hv.w, wsm[k + 3], dot);
    }
    float logit = (dot + bff2[0]) * Wfin[0];
    red[n] = logit; __syncthreads();
    for (int s = 128; s > 0; s >>= 1) {
        if (n < s) red[n] = fmaxf(red[n], red[n + s]);
        __syncthreads();
    }
    float mx = red[0]; __syncthreads();
    float e = expf(logit - mx);
    red[n] = e; __syncthreads();
    for (int s = 128; s > 0; s >>= 1) {
        if (n < s) red[n] += red[n + s];
        __syncthreads();
    }
    out[(size_t)b * NNODE + n] = e / red[0];
}

__global__ void zero_k(float* p, int n)
{
    int i = blockIdx.x * blockDim.x + threadIdx.x;
    if (i < n) p[i] = 0.f;
}

// ---------------------------------------------------------------------------
static inline void g(bool relu, bool acc, int M, int N, int K,
    const float* A, int lda, long long sA,
    const float* B, int ldb, long long sB,
    float* C, int ldc, long long sC, int nb, hipStream_t s)
{
    dim3 grid(N / 64, M / 128, nb), blk(256);
    if ( relu &&  acc) gemm_k<true,  true ><<<grid, blk, 0, s>>>(M,N,K,A,lda,sA,B,ldb,sB,C,ldc,sC);
    if ( relu && !acc) gemm_k<true,  false><<<grid, blk, 0, s>>>(M,N,K,A,lda,sA,B,ldb,sB,C,ldc,sC);
    if (!relu &&  acc) gemm_k<false, true ><<<grid, blk, 0, s>>>(M,N,K,A,lda,sA,B,ldb,sB,C,ldc,sC);
    if (!relu && !acc) gemm_k<false, false><<<grid, blk, 0, s>>>(M,N,K,A,lda,sA,B,ldb,sB,C,ldc,sC);
}

static inline void wk2(bool relu, bool acc, int M, int N, int K,
                       const float* A, int lda,
                       const half_t* Bh, const half_t* Bl, int ldb,
                       float* C, int ldc, const float* bias, hipStream_t s)
{
    dim3 grid(N / 128, M / 128, 1), blk(256);
    if (relu  &&  acc) gemm_wk2<true,  true ><<<grid, blk, 0, s>>>(M, N, K, A, lda, Bh, Bl, ldb, C, ldc, bias);
    if (relu  && !acc) gemm_wk2<true,  false><<<grid, blk, 0, s>>>(M, N, K, A, lda, Bh, Bl, ldb, C, ldc, bias);
    if (!relu &&  acc) gemm_wk2<false, true ><<<grid, blk, 0, s>>>(M, N, K, A, lda, Bh, Bl, ldb, C, ldc, bias);
    if (!relu && !acc) gemm_wk2<false, false><<<grid, blk, 0, s>>>(M, N, K, A, lda, Bh, Bl, ldb, C, ldc, bias);
}

struct Ctx {
    const half_t *ajh, *ajl;       // f16-2 adj
    half_t *XT;                    // XT slot (capacity 512*CH halves = 256 ch)
    int RSc, nb;
    hipStream_t s;
};

static inline void ak2(const Ctx& cx, int Cch, const float* X, int ldx,
                       float* Cout, int ldc, long long sC)
{
    half_t* X0 = cx.XT;
    half_t* X1 = X0 + (size_t)Cch * cx.RSc;
    xpose2_k<<<dim3(cx.RSc / 32, Cch / 32), 256, 0, cx.s>>>(X, ldx, cx.RSc, X0, X1);
    gemm_ak2<<<dim3(Cch / 128, 2, cx.nb), 256, 0, cx.s>>>(NNODE, cx.RSc,
        cx.ajh, cx.ajl, X0, X1, Cout, ldc, sC);
}

struct Weights {
    const float *adj, *W_fst, *W_snd, *W_thrd, *W_thrdb, *W_frth, *W_ffth;
    const float *bn6_g, *bn6_b, *W_svth, *bn8_g, *bn8_b, *W_nnth, *W_tnth;
    const float *W_lvnth, *bn12_g, *bn12_b, *W_ff1, *b_ff1, *W_ff2, *b_ff2, *W_final;
};
struct WT2 { half_t *h, *l; };

static void run_chunk(const float* x, float* out, float* ws, int nb,
                      const Weights& W, const WT2* V, const Ctx& cx0,
                      hipStream_t stream)
{
    const int RSc = nb * NNODE;
    const size_t CH = (size_t)RSc;
    float* SS = ws;                  // [S3|S2|S1] ld 576
    float* S3 = SS;
    float* S2 = SS + 256;
    float* S1 = SS + 512;
    float* U  = ws + 576 * CH;       // 1024-wide; packed Q slots early
    float* Q0 = U;
    float* Q1 = U + 256 * CH;
    float* Q2 = U + 512 * CH;
    float* Q3 = U + 768 * CH;
    float* R  = ws + 1600 * CH;      // 256-wide scratch (A5/B2), within R512
    float* R512 = ws + 1600 * CH;    // 512-wide scratch (T6, Gt halves)
    half_t* XTb = (half_t*)(ws + 2112 * CH);  // 512*CH halves

    Ctx cx = cx0; cx.XT = XTb; cx.RSc = RSc; cx.nb = nb; cx.s = stream;
    const float* adj = W.adj;
    const long long SN = (long long)NNODE;
    const long long S576 = SN * 576, S256 = SN * 256, S1024 = SN * 1024,
                    S128 = SN * 128, S64 = SN * 64;

    // ======== pre-bn6: fp32 VALU (round-5-validated arithmetic) ========
    s1_k<<<RSc / 16, 256, 0, stream>>>(x, W.W_fst, S1);
    g(0,0, NNODE,64,NNODE, adj,NNODE,0, S1,576,S576, Q0,256,S256, nb, stream);
    g(1,0, RSc,64,64, Q0,256,0, W.W_snd,64,0, Q1,64,0, 1, stream);
    g(0,0, NNODE,64,NNODE, adj,NNODE,0, Q1,64,S64, Q0+64,256,S256, nb, stream);
    g(1,0, RSc,128,128, Q0,256,0, W.W_thrd,128,0, Q2,128,0, 1, stream);
    g(0,0, NNODE,128,NNODE, adj,NNODE,0, Q2,128,S128, Q0+128,256,S256, nb, stream);
    g(1,0, RSc,256,256, Q0,256,0, W.W_thrdb,256,0, Q1,256,0, 1, stream);
    g(0,0, NNODE,256,NNODE, adj,NNODE,0, Q1,256,S256, Q2,256,S256, nb, stream);
    g(1,0, RSc,256,256, Q2,256,0, W.W_frth,256,0, Q3,256,0, 1, stream);
    g(0,0, RSc,256,64,  S1,576,0, W.W_ffth,          256,0, S2,576,0, 1, stream);
    g(0,1, RSc,256,256, Q3,256,0, W.W_ffth + 64*256, 256,0, S2,576,0, 1, stream);
    bn_k<<<dim3(nb, 4), 256, 0, stream>>>(S2, 576, S2, 576, W.bn6_g, W.bn6_b);

    // ======== post-bn6: f16-2 MFMA (bounded values) ========
    // 11. A5 = adj@S2 -> R
    ak2(cx, 256, S2, 576, R, 256, S256);
    // 12. T5 = relu(A5 @ W_svth) -> U+512 (ld 1024)
    wk2(1, 0, RSc, 256, 256, R, 256, V[0].h, V[0].l, 256, U + 512, 1024, 0, stream);
    // 13. bn8: B2 -> R ; B5 in place
    bn_k<<<dim3(nb, 4), 256, 0, stream>>>(S2, 576, R, 256, W.bn8_g, W.bn8_b);
    bn_k<<<dim3(nb, 4), 256, 0, stream>>>(U + 512, 1024, U + 512, 1024,
                                          W.bn8_g + 256, W.bn8_b + 256);
    // 14. A6a = adj@B2 -> U ; A6b = adj@B5 -> U+256
    ak2(cx, 256, R, 256, U, 1024, S1024);
    ak2(cx, 256, U + 512, 1024, U + 256, 1024, S1024);
    // 15. T6 = relu([A6a|A6b] @ W_nnth), ONE N=512 GEMM -> R512 (ld 512)
    wk2(1, 0, RSc, 512, 512, U, 1024, V[1].h, V[1].l, 512, R512, 512, 0, stream);
    // 16. A7ta = adj@T6a -> U+512 ; A7tb = adj@T6b -> U+768
    ak2(cx, 256, R512,       512, U + 512, 1024, S1024);
    ak2(cx, 256, R512 + 256, 512, U + 768, 1024, S1024);
    // 17. two N=512 halves: Gt_h = relu(U @ Wtnth[:,h*512..]) -> R512 ;
    //     S3 (+)= Gt_h @ W_lvnth[h*512 : h*512+512]
    for (int h = 0; h < 2; ++h) {
        wk2(1, 0, RSc, 512, 1024, U, 1024,
            V[2].h + (size_t)h * 512 * 1024, V[2].l + (size_t)h * 512 * 1024, 1024,
            R512, 512, 0, stream);
        wk2(0, h > 0, RSc, 256, 512, R512, 512,
            V[3].h + (size_t)h * 512, V[3].l + (size_t)h * 512, 1280,
            S3, 576, 0, stream);
    }
    // 18. S3 += S2 @ W_lvnth[1024:1280] ; bn12
    wk2(0, 1, RSc, 256, 256, S2, 576,
        V[3].h + 1024, V[3].l + 1024, 1280, S3, 576, 0, stream);
    bn_k<<<dim3(nb, 4), 256, 0, stream>>>(S3, 576, S3, 576, W.bn12_g, W.bn12_b);
    // 19. H = relu(SS @ W_ff1 + b_ff1) -> U (ld 128)
    wk2(1, 0, RSc, 128, 576, SS, 576, V[4].h, V[4].l, 576, U, 128, W.b_ff1, stream);
    // 20. head + softmax
    head_k<<<nb, 256, 0, stream>>>(U, W.W_ff2, W.b_ff2, W.W_final, out);
}

extern "C" void kernel_launch(void* const* d_in, const int* in_sizes, int n_in,
                              void* d_out, int out_size, void* d_ws, size_t ws_size,
                              hipStream_t stream)
{
    const float* x = (const float*)d_in[0];
    Weights W;
    W.adj = (const float*)d_in[1];   W.W_fst  = (const float*)d_in[2];
    W.W_snd = (const float*)d_in[3]; W.W_thrd = (const float*)d_in[4];
    W.W_thrdb = (const float*)d_in[5]; W.W_frth = (const float*)d_in[6];
    W.W_ffth = (const float*)d_in[7]; W.bn6_g = (const float*)d_in[8];
    W.bn6_b = (const float*)d_in[9];  W.W_svth = (const float*)d_in[10];
    W.bn8_g = (const float*)d_in[11]; W.bn8_b = (const float*)d_in[12];
    W.W_nnth = (const float*)d_in[13]; W.W_tnth = (const float*)d_in[14];
    W.W_lvnth = (const float*)d_in[15]; W.bn12_g = (const float*)d_in[16];
    W.bn12_b = (const float*)d_in[17]; W.W_ff1 = (const float*)d_in[18];
    W.b_ff1 = (const float*)d_in[19]; W.W_ff2 = (const float*)d_in[20];
    W.b_ff2 = (const float*)d_in[21]; W.W_final = (const float*)d_in[22];
    float* out = (float*)d_out;

    // f16-2 split weights (post-bn6): W_svth, W_nnth, W_tnth, W_lvnth, W_ff1
    const size_t szs[5] = {65536, 262144, 1048576, 327680, 73728};
    const size_t ADJSZ = 65536;
    size_t tot_halves = 2 * ADJSZ;
    for (int i = 0; i < 5; ++i) tot_halves += 2 * szs[i];
    const size_t split_bytes = tot_halves * 2;

    // arena = 2368 fp32 channels (576 SS + 1024 U + 512 R512 + 256 XT slot)
    int nb = NBATCH;
    while (nb > 0 && (size_t)2368 * nb * NNODE * 4 + split_bytes > ws_size) nb -= 32;
    if (nb <= 0) {
        zero_k<<<(out_size + 255) / 256, 256, 0, stream>>>(out, out_size);
        return;
    }

    float* ws = (float*)d_ws;
    half_t* hb = (half_t*)(ws + (size_t)2368 * nb * NNODE);
    WT2 V[5];
    size_t off = 0;
    for (int i = 0; i < 5; ++i) {
        V[i].h = hb + off; off += szs[i];
        V[i].l = hb + off; off += szs[i];
    }
    half_t* ajh = hb + off; off += ADJSZ;
    half_t* ajl = hb + off; off += ADJSZ;

    // one-time weight transpose+split (f16 2-term), post-bn6 weights only
    const float* wp[5] = {W.W_svth, W.W_nnth, W.W_tnth, W.W_lvnth, W.W_ff1};
    const int wkk[5] = {256, 512, 1024, 1280, 576};
    const int wnn[5] = {256, 512, 1024, 256, 128};
    for (int i = 0; i < 5; ++i)
        wsplit2_k<<<dim3(wkk[i] / 32, wnn[i] / 32), 256, 0, stream>>>(
            wp[i], wkk[i], wnn[i], V[i].h, V[i].l);
    asplit2_k<<<256, 256, 0, stream>>>(W.adj, ajh, ajl, 65536);

    Ctx cx0; cx0.ajh = ajh; cx0.ajl = ajl;
    cx0.XT = nullptr; cx0.RSc = 0; cx0.nb = 0; cx0.s = stream;

    for (int b0 = 0; b0 < NBATCH; b0 += nb) {
        int nbc = (NBATCH - b0 < nb) ? (NBATCH - b0) : nb;
        run_chunk(x + (size_t)b0 * NNODE, out + (size_t)b0 * NNODE,
                  ws, nbc, W, V, cx0, stream);
    }
}

// Round 16
// 2862.620 us; speedup vs baseline: 1.1612x; 1.0086x over previous
//
#include <hip/hip_runtime.h>
#include <math.h>

#define NBATCH 256
#define NNODE 256
#define FCLAMP 60000.0f   // tripwire; post-bn6 values are ~1e3 max

typedef float f32x4 __attribute__((ext_vector_type(4)));
typedef _Float16 half_t;
typedef half_t f16x8 __attribute__((ext_vector_type(8)));
typedef half_t f16x4 __attribute__((ext_vector_type(4)));

// f16 2-term split: v = h + l + O(2^-22 * v); range-safe for |v| < 60000.
__device__ __forceinline__ void split2(float v, half_t& h, half_t& l)
{
    v = fminf(fmaxf(v, -FCLAMP), FCLAMP);
    half_t hh = (half_t)v;
    h = hh;
    l = (half_t)(v - (float)hh);
}

// ===========================================================================
// f16 2-term split GEMM, LDS-staged + T14 async-STAGE (round-15, proven)
// + T1 XCD-aware bijective block swizzle (m204): consecutive same-XCD blocks
// cover contiguous row-panels incl. all N-column blocks -> the 0.5MB A
// row-panel is re-read from the XCD's private L2 instead of HBM (round-15
// FETCH showed A costing 2x its size in HBM traffic; 34.5% HBM util).
// Block 128x128, 4 waves (2x2), wave 64x64 = 4x4 frags of 16x16x32, BK=32.
// 3 MFMA per product {ah*bh, ah*bl, al*bh}; fp32 accum. MFMA order per
// accumulator identical to rounds 12/13/15 -> bit-identical output.
// Frag family (m89/m91/m97-verified): a: lane=(row l&15, k=(l>>4)*8+j);
// b: lane=(col l&15, same k); d: row=(l>>4)*4+r, col=l&15.
// ===========================================================================
template<bool RELU, bool ACC>
__global__ __launch_bounds__(256)
void gemm_wk2(int M, int N, int K,
              const float* __restrict__ A, int lda,
              const half_t* __restrict__ Bh, const half_t* __restrict__ Bl, int ldb,
              float* __restrict__ C, int ldc,
              const float* __restrict__ bias)
{
    __shared__ half_t Ash[128][40], Asl[128][40];
    __shared__ half_t Bsh[128][40], Bsl[128][40];

    // ---- T1: bijective XCD swizzle (m204) ----
    const int nwg  = gridDim.x * gridDim.y;
    const int orig = blockIdx.y * gridDim.x + blockIdx.x;
    const int q = nwg >> 3, r8 = nwg & 7;
    const int xcd = orig & 7, pos = orig >> 3;
    const int wgid = (xcd < r8 ? xcd * (q + 1) : r8 * (q + 1) + (xcd - r8) * q) + pos;
    const int bx = wgid % gridDim.x;
    const int by = wgid / gridDim.x;

    const int tid  = threadIdx.x;
    const int tn0  = bx * 128;
    const int tm0  = by * 128;
    const int lane = tid & 63;
    const int w    = tid >> 6;
    const int wr   = (w >> 1) * 64, wc = (w & 1) * 64;
    const int lr   = lane & 15, ko = lane >> 4;

    const int srow = tid >> 1;          // staging row 0..127
    const int skh  = (tid & 1) * 16;    // staging k-half 0/16

    f32x4 acc[4][4];
#pragma unroll
    for (int i = 0; i < 4; ++i)
#pragma unroll
        for (int j = 0; j < 4; ++j) acc[i][j] = (f32x4){0.f, 0.f, 0.f, 0.f};

    const float*  aP  = A  + (size_t)(tm0 + srow) * lda + skh;
    const half_t* bhP = Bh + (size_t)(tn0 + srow) * ldb + skh;
    const half_t* blP = Bl + (size_t)(tn0 + srow) * ldb + skh;

    // staged-tile registers (tile kb), preloaded before the loop
    float4 ra0, ra1, ra2, ra3;
    f16x8  rbh0, rbh1, rbl0, rbl1;
    {
        const float4* ap = (const float4*)aP;
        ra0 = ap[0]; ra1 = ap[1]; ra2 = ap[2]; ra3 = ap[3];
        const f16x8* ph = (const f16x8*)bhP;
        const f16x8* pl = (const f16x8*)blP;
        rbh0 = ph[0]; rbh1 = ph[1]; rbl0 = pl[0]; rbl1 = pl[1];
    }

    for (int kb = 0; kb < K; kb += 32) {
        // ---- write phase: split2 staged A regs, write A+B tiles to LDS ----
        {
            float vv[16] = {ra0.x, ra0.y, ra0.z, ra0.w, ra1.x, ra1.y, ra1.z, ra1.w,
                            ra2.x, ra2.y, ra2.z, ra2.w, ra3.x, ra3.y, ra3.z, ra3.w};
            half_t th[16], tl[16];
#pragma unroll
            for (int j = 0; j < 16; ++j)
                split2(vv[j], th[j], tl[j]);
            *(f16x8*)&Ash[srow][skh]     = *(f16x8*)&th[0];
            *(f16x8*)&Ash[srow][skh + 8] = *(f16x8*)&th[8];
            *(f16x8*)&Asl[srow][skh]     = *(f16x8*)&tl[0];
            *(f16x8*)&Asl[srow][skh + 8] = *(f16x8*)&tl[8];
            *(f16x8*)&Bsh[srow][skh]     = rbh0;
            *(f16x8*)&Bsh[srow][skh + 8] = rbh1;
            *(f16x8*)&Bsl[srow][skh]     = rbl0;
            *(f16x8*)&Bsl[srow][skh + 8] = rbl1;
        }
        __syncthreads();                        // barrier #1: tiles visible

        // ---- issue NEXT-tile global loads: retire under the MFMA phase ----
        if (kb + 32 < K) {
            const float4* ap = (const float4*)(aP + kb + 32);
            ra0 = ap[0]; ra1 = ap[1]; ra2 = ap[2]; ra3 = ap[3];
            const f16x8* ph = (const f16x8*)(bhP + kb + 32);
            const f16x8* pl = (const f16x8*)(blP + kb + 32);
            rbh0 = ph[0]; rbh1 = ph[1]; rbl0 = pl[0]; rbl1 = pl[1];
        }

        // ---- fragment reads ----
        f16x8 ah[4], al[4], bh[4], bl[4];
#pragma unroll
        for (int mf = 0; mf < 4; ++mf) {
            int r = wr + mf * 16 + lr;
            ah[mf] = *(const f16x8*)&Ash[r][ko * 8];
            al[mf] = *(const f16x8*)&Asl[r][ko * 8];
        }
#pragma unroll
        for (int nf = 0; nf < 4; ++nf) {
            int c = wc + nf * 16 + lr;
            bh[nf] = *(const f16x8*)&Bsh[c][ko * 8];
            bl[nf] = *(const f16x8*)&Bsl[c][ko * 8];
        }
        // ---- MFMA: 3 per product (same order as rounds 12/13/15) ----
#pragma unroll
        for (int nf = 0; nf < 4; ++nf) {
#pragma unroll
            for (int mf = 0; mf < 4; ++mf) {
                acc[mf][nf] = __builtin_amdgcn_mfma_f32_16x16x32_f16(ah[mf], bh[nf], acc[mf][nf], 0, 0, 0);
                acc[mf][nf] = __builtin_amdgcn_mfma_f32_16x16x32_f16(ah[mf], bl[nf], acc[mf][nf], 0, 0, 0);
                acc[mf][nf] = __builtin_amdgcn_mfma_f32_16x16x32_f16(al[mf], bh[nf], acc[mf][nf], 0, 0, 0);
            }
        }
        __syncthreads();                        // barrier #2: reads done
    }

#pragma unroll
    for (int mf = 0; mf < 4; ++mf) {
        int r0 = tm0 + wr + mf * 16 + ko * 4;
#pragma unroll
        for (int nf = 0; nf < 4; ++nf) {
            int c = tn0 + wc + nf * 16 + lr;
            float bsv = bias ? bias[c] : 0.f;
#pragma unroll
            for (int r = 0; r < 4; ++r) {
                float* cp = C + (size_t)(r0 + r) * ldc + c;
                float t = acc[mf][nf][r] + bsv;
                if (ACC) t += *cp;
                if (RELU) t = fmaxf(t, 0.f);
                *cp = t;
            }
        }
    }
}

// ===========================================================================
// f16 2-term adj-GEMM (round-13/15 direct-global form): Out[z] = adj @ X[z].
// adj pre-split [256][256] (L2-resident, shared); XT[C][RSc] pre-split.
// ===========================================================================
__global__ __launch_bounds__(256)
void gemm_ak2(int K, int ldxt,
              const half_t* __restrict__ Ah, const half_t* __restrict__ Al,
              const half_t* __restrict__ XTh, const half_t* __restrict__ XTl,
              float* __restrict__ C, int ldc, long long sC)
{
    const int z = blockIdx.z;
    C += sC * z;
    const int zoff = z * NNODE;
    const int tid  = threadIdx.x;
    const int tn0  = blockIdx.x * 128;
    const int tm0  = blockIdx.y * 128;
    const int lane = tid & 63;
    const int w    = tid >> 6;
    const int wr   = (w >> 1) * 64, wc = (w & 1) * 64;
    const int lr   = lane & 15, ko = lane >> 4;

    f32x4 acc[4][4];
#pragma unroll
    for (int i = 0; i < 4; ++i)
#pragma unroll
        for (int j = 0; j < 4; ++j) acc[i][j] = (f32x4){0.f, 0.f, 0.f, 0.f};

    size_t aoff[4], boff[4];
#pragma unroll
    for (int mf = 0; mf < 4; ++mf)
        aoff[mf] = (size_t)(tm0 + wr + mf * 16 + lr) * NNODE + ko * 8;
#pragma unroll
    for (int nf = 0; nf < 4; ++nf)
        boff[nf] = (size_t)(tn0 + wc + nf * 16 + lr) * ldxt + zoff + ko * 8;

    for (int kb = 0; kb < K; kb += 32) {
        f16x8 ah[4], al[4];
#pragma unroll
        for (int mf = 0; mf < 4; ++mf) {
            ah[mf] = *(const f16x8*)(Ah + aoff[mf] + kb);
            al[mf] = *(const f16x8*)(Al + aoff[mf] + kb);
        }
#pragma unroll
        for (int nf = 0; nf < 4; ++nf) {
            f16x8 bh = *(const f16x8*)(XTh + boff[nf] + kb);
            f16x8 bl = *(const f16x8*)(XTl + boff[nf] + kb);
#pragma unroll
            for (int mf = 0; mf < 4; ++mf) {
                acc[mf][nf] = __builtin_amdgcn_mfma_f32_16x16x32_f16(ah[mf], bh, acc[mf][nf], 0, 0, 0);
                acc[mf][nf] = __builtin_amdgcn_mfma_f32_16x16x32_f16(ah[mf], bl, acc[mf][nf], 0, 0, 0);
                acc[mf][nf] = __builtin_amdgcn_mfma_f32_16x16x32_f16(al[mf], bh, acc[mf][nf], 0, 0, 0);
            }
        }
    }

#pragma unroll
    for (int mf = 0; mf < 4; ++mf) {
        int r0 = tm0 + wr + mf * 16 + ko * 4;
#pragma unroll
        for (int nf = 0; nf < 4; ++nf) {
            int c = tn0 + wc + nf * 16 + lr;
#pragma unroll
            for (int r = 0; r < 4; ++r)
                C[(size_t)(r0 + r) * ldc + c] = acc[mf][nf][r];
        }
    }
}

// Transpose + f16-2 split: X (Mtot x C, ld) -> T[C][Mtot] x 2 terms.
__global__ __launch_bounds__(256)
void xpose2_k(const float* __restrict__ X, int ld, int Mtot,
              half_t* __restrict__ Th, half_t* __restrict__ Tl)
{
    __shared__ float tile[32][33];
    const int m0 = blockIdx.x * 32, c0 = blockIdx.y * 32;
    const int t = threadIdx.x;
    {
        int r = t >> 3, cc = (t & 7) * 4;
        float4 v = *(const float4*)(X + (size_t)(m0 + r) * ld + c0 + cc);
        tile[r][cc + 0] = v.x; tile[r][cc + 1] = v.y;
        tile[r][cc + 2] = v.z; tile[r][cc + 3] = v.w;
    }
    __syncthreads();
    {
        int cr = t >> 3, mc = (t & 7) * 4;
        f16x4 h, l;
#pragma unroll
        for (int j = 0; j < 4; ++j) {
            half_t hh, ll;
            split2(tile[mc + j][cr], hh, ll);
            h[j] = hh; l[j] = ll;
        }
        size_t o = (size_t)(c0 + cr) * Mtot + m0 + mc;
        *(f16x4*)(Th + o) = h;
        *(f16x4*)(Tl + o) = l;
    }
}

// W [K][N] fp32 -> WT [N][K] f16 2-term
__global__ __launch_bounds__(256)
void wsplit2_k(const float* __restrict__ W, int K, int N,
               half_t* __restrict__ Th, half_t* __restrict__ Tl)
{
    __shared__ float tile[32][33];
    const int k0 = blockIdx.x * 32, n0 = blockIdx.y * 32;
    const int t = threadIdx.x;
    {
        int kr = t >> 3, nc = (t & 7) * 4;
        float4 v = *(const float4*)(W + (size_t)(k0 + kr) * N + n0 + nc);
        tile[kr][nc + 0] = v.x; tile[kr][nc + 1] = v.y;
        tile[kr][nc + 2] = v.z; tile[kr][nc + 3] = v.w;
    }
    __syncthreads();
    {
        int nr = t >> 3, kc = (t & 7) * 4;
        f16x4 h, l;
#pragma unroll
        for (int j = 0; j < 4; ++j) {
            half_t hh, ll;
            split2(tile[kc + j][nr], hh, ll);
            h[j] = hh; l[j] = ll;
        }
        size_t o = (size_t)(n0 + nr) * K + k0 + kc;
        *(f16x4*)(Th + o) = h;
        *(f16x4*)(Tl + o) = l;
    }
}

__global__ void asplit2_k(const float* __restrict__ A,
                          half_t* __restrict__ Ah, half_t* __restrict__ Al, int n)
{
    int i = blockIdx.x * blockDim.x + threadIdx.x;
    if (i < n) {
        half_t h, l;
        split2(A[i], h, l);
        Ah[i] = h; Al[i] = l;
    }
}

// ===========================================================================
// fp32 tiled GEMM (BM=128, BN=64, BK=16) — the round-5-validated arithmetic.
// Used for the ENTIRE pre-bn6 chain (error-amplifying region) + C=64 stages.
// ===========================================================================
template<bool RELU, bool ACC>
__global__ __launch_bounds__(256)
void gemm_k(int M, int N, int K,
            const float* __restrict__ A, int lda, long long sA,
            const float* __restrict__ B, int ldb, long long sB,
            float* __restrict__ C, int ldc, long long sC)
{
    constexpr int BM = 128, BN_ = 64, BK = 16, TM = 8, TN = 4;
    constexpr int TX = BN_ / TN;
    __shared__ float As[BK][BM + 4];
    __shared__ float Bs[BK][BN_ + 4];
    const int bz = blockIdx.z;
    A += sA * bz; B += sB * bz; C += sC * bz;
    const int tn0 = blockIdx.x * BN_, tm0 = blockIdx.y * BM;
    const int tid = threadIdx.x;
    const int tx = tid % TX, ty = tid / TX;
    float acc[TM][TN];
#pragma unroll
    for (int i = 0; i < TM; ++i)
#pragma unroll
        for (int j = 0; j < TN; ++j) acc[i][j] = 0.f;
    const int arow = tid >> 2, akq = tid & 3;
    const int bcq = tid % 16, bkr = tid / 16;
    for (int k0 = 0; k0 < K; k0 += BK) {
#pragma unroll
        for (int i = 0; i < 2; ++i) {
            int row = arow + i * 64;
            float4 a = *(const float4*)(A + (size_t)(tm0 + row) * lda + k0 + akq * 4);
            As[akq * 4 + 0][row] = a.x; As[akq * 4 + 1][row] = a.y;
            As[akq * 4 + 2][row] = a.z; As[akq * 4 + 3][row] = a.w;
        }
        {
            float4 b4 = *(const float4*)(B + (size_t)(k0 + bkr) * ldb + tn0 + bcq * 4);
            *(float4*)&Bs[bkr][bcq * 4] = b4;
        }
        __syncthreads();
#pragma unroll
        for (int k = 0; k < BK; ++k) {
            float av[TM], bv[TN];
#pragma unroll
            for (int i = 0; i < TM; ++i) av[i] = As[k][ty * TM + i];
#pragma unroll
            for (int j = 0; j < TN; ++j) bv[j] = Bs[k][tx * TN + j];
#pragma unroll
            for (int i = 0; i < TM; ++i)
#pragma unroll
                for (int j = 0; j < TN; ++j)
                    acc[i][j] = fmaf(av[i], bv[j], acc[i][j]);
        }
        __syncthreads();
    }
#pragma unroll
    for (int i = 0; i < TM; ++i) {
        size_t r = (size_t)tm0 + ty * TM + i;
        int c = tn0 + tx * TN;
        float t0 = acc[i][0], t1 = acc[i][1], t2 = acc[i][2], t3 = acc[i][3];
        float* cp = C + r * ldc + c;
        if (ACC) {
            float4 p = *(const float4*)cp;
            t0 += p.x; t1 += p.y; t2 += p.z; t3 += p.w;
        }
        if (RELU) {
            t0 = fmaxf(t0, 0.f); t1 = fmaxf(t1, 0.f);
            t2 = fmaxf(t2, 0.f); t3 = fmaxf(t3, 0.f);
        }
        float4 v; v.x = t0; v.y = t1; v.z = t2; v.w = t3;
        *(float4*)cp = v;
    }
}

// skip_1 = x (x) W_fst, into SS cols 512..575 (ld 576)
__global__ void s1_k(const float* __restrict__ x, const float* __restrict__ Wfst,
                     float* __restrict__ dst)
{
    int idx = blockIdx.x * blockDim.x + threadIdx.x;
    int r = idx >> 4, c4 = idx & 15;
    float xv = x[r];
    float4 wv = *(const float4*)(Wfst + c4 * 4);
    float4 o; o.x = xv * wv.x; o.y = xv * wv.y; o.z = xv * wv.z; o.w = xv * wv.w;
    *(float4*)(dst + (size_t)r * 576 + c4 * 4) = o;
}

// Per-sample BN over nodes (256 ch), fp64 stats. grid=(nb,4), blk=256.
__global__ __launch_bounds__(256)
void bn_k(const float* __restrict__ src, int lds_, float* __restrict__ dst, int ldd,
          const float* __restrict__ g, const float* __restrict__ bt)
{
    const int b = blockIdx.x, c0 = blockIdx.y * 64;
    const int cl = threadIdx.x & 63, ph = threadIdx.x >> 6;
    const int c = c0 + cl;
    const float* Sb = src + (size_t)b * NNODE * lds_;
    float* Db = dst + (size_t)b * NNODE * ldd;
    double sum = 0.0, sq = 0.0;
    for (int n = ph; n < NNODE; n += 4) {
        double v = (double)Sb[(size_t)n * lds_ + c];
        sum += v; sq += v * v;
    }
    __shared__ double ssum[4][64], ssq[4][64];
    __shared__ float sscale[64], sshift[64];
    ssum[ph][cl] = sum; ssq[ph][cl] = sq;
    __syncthreads();
    if (ph == 0) {
        double s = ssum[0][cl] + ssum[1][cl] + ssum[2][cl] + ssum[3][cl];
        double q = ssq[0][cl] + ssq[1][cl] + ssq[2][cl] + ssq[3][cl];
        double m = s * (1.0 / NNODE);
        double var = q * (1.0 / NNODE) - m * m;
        double sc = (double)g[c] / sqrt(var + 1e-5);
        sscale[cl] = (float)sc;
        sshift[cl] = (float)((double)bt[c] - m * sc);
    }
    __syncthreads();
    float sc = sscale[cl], sh = sshift[cl];
    for (int n = ph; n < NNODE; n += 4)
        Db[(size_t)n * ldd + c] = fmaf(Sb[(size_t)n * lds_ + c], sc, sh);
}

__global__ __launch_bounds__(256)
void head_k(const float* __restrict__ H, const float* __restrict__ Wff2,
            const float* __restrict__ bff2, const float* __restrict__ Wfin,
            float* __restrict__ out)
{
    __shared__ float wsm[128];
    __shared__ float red[256];
    const int b = blockIdx.x, n = threadIdx.x;
    if (n < 128) wsm[n] = Wff2[n];
    __syncthreads();
    const float* h = H + ((size_t)b * NNODE + n) * 128;
    float dot = 0.f;
#pragma unroll
    for (int k = 0; k < 128; k += 4) {
        float4 hv = *(const float4*)(h + k);
        dot = fmaf(hv.x, wsm[k + 0], dot); dot = fmaf(hv.y, wsm[k + 1], dot);
        dot = fmaf(hv.z, wsm[k + 2], dot); dot = fmaf(hv.w, wsm[k + 3], dot);
    }
    float logit = (dot + bff2[0]) * Wfin[0];
    red[n] = logit; __syncthreads();
    for (int s = 128; s > 0; s >>= 1) {
        if (n < s) red[n] = fmaxf(red[n], red[n + s]);
        __syncthreads();
    }
    float mx = red[0]; __syncthreads();
    float e = expf(logit - mx);
    red[n] = e; __syncthreads();
    for (int s = 128; s > 0; s >>= 1) {
        if (n < s) red[n] += red[n + s];
        __syncthreads();
    }
    out[(size_t)b * NNODE + n] = e / red[0];
}

__global__ void zero_k(float* p, int n)
{
    int i = blockIdx.x * blockDim.x + threadIdx.x;
    if (i < n) p[i] = 0.f;
}

// ---------------------------------------------------------------------------
static inline void g(bool relu, bool acc, int M, int N, int K,
    const float* A, int lda, long long sA,
    const float* B, int ldb, long long sB,
    float* C, int ldc, long long sC, int nb, hipStream_t s)
{
    dim3 grid(N / 64, M / 128, nb), blk(256);
    if ( relu &&  acc) gemm_k<true,  true ><<<grid, blk, 0, s>>>(M,N,K,A,lda,sA,B,ldb,sB,C,ldc,sC);
    if ( relu && !acc) gemm_k<true,  false><<<grid, blk, 0, s>>>(M,N,K,A,lda,sA,B,ldb,sB,C,ldc,sC);
    if (!relu &&  acc) gemm_k<false, true ><<<grid, blk, 0, s>>>(M,N,K,A,lda,sA,B,ldb,sB,C,ldc,sC);
    if (!relu && !acc) gemm_k<false, false><<<grid, blk, 0, s>>>(M,N,K,A,lda,sA,B,ldb,sB,C,ldc,sC);
}

static inline void wk2(bool relu, bool acc, int M, int N, int K,
                       const float* A, int lda,
                       const half_t* Bh, const half_t* Bl, int ldb,
                       float* C, int ldc, const float* bias, hipStream_t s)
{
    dim3 grid(N / 128, M / 128, 1), blk(256);
    if (relu  &&  acc) gemm_wk2<true,  true ><<<grid, blk, 0, s>>>(M, N, K, A, lda, Bh, Bl, ldb, C, ldc, bias);
    if (relu  && !acc) gemm_wk2<true,  false><<<grid, blk, 0, s>>>(M, N, K, A, lda, Bh, Bl, ldb, C, ldc, bias);
    if (!relu &&  acc) gemm_wk2<false, true ><<<grid, blk, 0, s>>>(M, N, K, A, lda, Bh, Bl, ldb, C, ldc, bias);
    if (!relu && !acc) gemm_wk2<false, false><<<grid, blk, 0, s>>>(M, N, K, A, lda, Bh, Bl, ldb, C, ldc, bias);
}

struct Ctx {
    const half_t *ajh, *ajl;       // f16-2 adj
    half_t *XT;                    // XT slot (capacity 512*CH halves = 256 ch)
    int RSc, nb;
    hipStream_t s;
};

static inline void ak2(const Ctx& cx, int Cch, const float* X, int ldx,
                       float* Cout, int ldc, long long sC)
{
    half_t* X0 = cx.XT;
    half_t* X1 = X0 + (size_t)Cch * cx.RSc;
    xpose2_k<<<dim3(cx.RSc / 32, Cch / 32), 256, 0, cx.s>>>(X, ldx, cx.RSc, X0, X1);
    gemm_ak2<<<dim3(Cch / 128, 2, cx.nb), 256, 0, cx.s>>>(NNODE, cx.RSc,
        cx.ajh, cx.ajl, X0, X1, Cout, ldc, sC);
}

struct Weights {
    const float *adj, *W_fst, *W_snd, *W_thrd, *W_thrdb, *W_frth, *W_ffth;
    const float *bn6_g, *bn6_b, *W_svth, *bn8_g, *bn8_b, *W_nnth, *W_tnth;
    const float *W_lvnth, *bn12_g, *bn12_b, *W_ff1, *b_ff1, *W_ff2, *b_ff2, *W_final;
};
struct WT2 { half_t *h, *l; };

static void run_chunk(const float* x, float* out, float* ws, int nb,
                      const Weights& W, const WT2* V, const Ctx& cx0,
                      hipStream_t stream)
{
    const int RSc = nb * NNODE;
    const size_t CH = (size_t)RSc;
    float* SS = ws;                  // [S3|S2|S1] ld 576
    float* S3 = SS;
    float* S2 = SS + 256;
    float* S1 = SS + 512;
    float* U  = ws + 576 * CH;       // 1024-wide; packed Q slots early
    float* Q0 = U;
    float* Q1 = U + 256 * CH;
    float* Q2 = U + 512 * CH;
    float* Q3 = U + 768 * CH;
    float* R  = ws + 1600 * CH;      // 256-wide scratch (A5/B2), within R512
    float* R512 = ws + 1600 * CH;    // 512-wide scratch (T6, Gt halves)
    half_t* XTb = (half_t*)(ws + 2112 * CH);  // 512*CH halves

    Ctx cx = cx0; cx.XT = XTb; cx.RSc = RSc; cx.nb = nb; cx.s = stream;
    const float* adj = W.adj;
    const long long SN = (long long)NNODE;
    const long long S576 = SN * 576, S256 = SN * 256, S1024 = SN * 1024,
                    S128 = SN * 128, S64 = SN * 64;

    // ======== pre-bn6: fp32 VALU (round-5-validated arithmetic) ========
    s1_k<<<RSc / 16, 256, 0, stream>>>(x, W.W_fst, S1);
    g(0,0, NNODE,64,NNODE, adj,NNODE,0, S1,576,S576, Q0,256,S256, nb, stream);
    g(1,0, RSc,64,64, Q0,256,0, W.W_snd,64,0, Q1,64,0, 1, stream);
    g(0,0, NNODE,64,NNODE, adj,NNODE,0, Q1,64,S64, Q0+64,256,S256, nb, stream);
    g(1,0, RSc,128,128, Q0,256,0, W.W_thrd,128,0, Q2,128,0, 1, stream);
    g(0,0, NNODE,128,NNODE, adj,NNODE,0, Q2,128,S128, Q0+128,256,S256, nb, stream);
    g(1,0, RSc,256,256, Q0,256,0, W.W_thrdb,256,0, Q1,256,0, 1, stream);
    g(0,0, NNODE,256,NNODE, adj,NNODE,0, Q1,256,S256, Q2,256,S256, nb, stream);
    g(1,0, RSc,256,256, Q2,256,0, W.W_frth,256,0, Q3,256,0, 1, stream);
    g(0,0, RSc,256,64,  S1,576,0, W.W_ffth,          256,0, S2,576,0, 1, stream);
    g(0,1, RSc,256,256, Q3,256,0, W.W_ffth + 64*256, 256,0, S2,576,0, 1, stream);
    bn_k<<<dim3(nb, 4), 256, 0, stream>>>(S2, 576, S2, 576, W.bn6_g, W.bn6_b);

    // ======== post-bn6: f16-2 MFMA (bounded values) ========
    // 11. A5 = adj@S2 -> R
    ak2(cx, 256, S2, 576, R, 256, S256);
    // 12. T5 = relu(A5 @ W_svth) -> U+512 (ld 1024)
    wk2(1, 0, RSc, 256, 256, R, 256, V[0].h, V[0].l, 256, U + 512, 1024, 0, stream);
    // 13. bn8: B2 -> R ; B5 in place
    bn_k<<<dim3(nb, 4), 256, 0, stream>>>(S2, 576, R, 256, W.bn8_g, W.bn8_b);
    bn_k<<<dim3(nb, 4), 256, 0, stream>>>(U + 512, 1024, U + 512, 1024,
                                          W.bn8_g + 256, W.bn8_b + 256);
    // 14. A6a = adj@B2 -> U ; A6b = adj@B5 -> U+256
    ak2(cx, 256, R, 256, U, 1024, S1024);
    ak2(cx, 256, U + 512, 1024, U + 256, 1024, S1024);
    // 15. T6 = relu([A6a|A6b] @ W_nnth), ONE N=512 GEMM -> R512 (ld 512)
    wk2(1, 0, RSc, 512, 512, U, 1024, V[1].h, V[1].l, 512, R512, 512, 0, stream);
    // 16. A7ta = adj@T6a -> U+512 ; A7tb = adj@T6b -> U+768
    ak2(cx, 256, R512,       512, U + 512, 1024, S1024);
    ak2(cx, 256, R512 + 256, 512, U + 768, 1024, S1024);
    // 17. two N=512 halves: Gt_h = relu(U @ Wtnth[:,h*512..]) -> R512 ;
    //     S3 (+)= Gt_h @ W_lvnth[h*512 : h*512+512]
    for (int h = 0; h < 2; ++h) {
        wk2(1, 0, RSc, 512, 1024, U, 1024,
            V[2].h + (size_t)h * 512 * 1024, V[2].l + (size_t)h * 512 * 1024, 1024,
            R512, 512, 0, stream);
        wk2(0, h > 0, RSc, 256, 512, R512, 512,
            V[3].h + (size_t)h * 512, V[3].l + (size_t)h * 512, 1280,
            S3, 576, 0, stream);
    }
    // 18. S3 += S2 @ W_lvnth[1024:1280] ; bn12
    wk2(0, 1, RSc, 256, 256, S2, 576,
        V[3].h + 1024, V[3].l + 1024, 1280, S3, 576, 0, stream);
    bn_k<<<dim3(nb, 4), 256, 0, stream>>>(S3, 576, S3, 576, W.bn12_g, W.bn12_b);
    // 19. H = relu(SS @ W_ff1 + b_ff1) -> U (ld 128)
    wk2(1, 0, RSc, 128, 576, SS, 576, V[4].h, V[4].l, 576, U, 128, W.b_ff1, stream);
    // 20. head + softmax
    head_k<<<nb, 256, 0, stream>>>(U, W.W_ff2, W.b_ff2, W.W_final, out);
}

extern "C" void kernel_launch(void* const* d_in, const int* in_sizes, int n_in,
                              void* d_out, int out_size, void* d_ws, size_t ws_size,
                              hipStream_t stream)
{
    const float* x = (const float*)d_in[0];
    Weights W;
    W.adj = (const float*)d_in[1];   W.W_fst  = (const float*)d_in[2];
    W.W_snd = (const float*)d_in[3]; W.W_thrd = (const float*)d_in[4];
    W.W_thrdb = (const float*)d_in[5]; W.W_frth = (const float*)d_in[6];
    W.W_ffth = (const float*)d_in[7]; W.bn6_g = (const float*)d_in[8];
    W.bn6_b = (const float*)d_in[9];  W.W_svth = (const float*)d_in[10];
    W.bn8_g = (const float*)d_in[11]; W.bn8_b = (const float*)d_in[12];
    W.W_nnth = (const float*)d_in[13]; W.W_tnth = (const float*)d_in[14];
    W.W_lvnth = (const float*)d_in[15]; W.bn12_g = (const float*)d_in[16];
    W.bn12_b = (const float*)d_in[17]; W.W_ff1 = (const float*)d_in[18];
    W.b_ff1 = (const float*)d_in[19]; W.W_ff2 = (const float*)d_in[20];
    W.b_ff2 = (const float*)d_in[21]; W.W_final = (const float*)d_in[22];
    float* out = (float*)d_out;

    // f16-2 split weights (post-bn6): W_svth, W_nnth, W_tnth, W_lvnth, W_ff1
    const size_t szs[5] = {65536, 262144, 1048576, 327680, 73728};
    const size_t ADJSZ = 65536;
    size_t tot_halves = 2 * ADJSZ;
    for (int i = 0; i < 5; ++i) tot_halves += 2 * szs[i];
    const size_t split_bytes = tot_halves * 2;

    // arena = 2368 fp32 channels (576 SS + 1024 U + 512 R512 + 256 XT slot)
    int nb = NBATCH;
    while (nb > 0 && (size_t)2368 * nb * NNODE * 4 + split_bytes > ws_size) nb -= 32;
    if (nb <= 0) {
        zero_k<<<(out_size + 255) / 256, 256, 0, stream>>>(out, out_size);
        return;
    }

    float* ws = (float*)d_ws;
    half_t* hb = (half_t*)(ws + (size_t)2368 * nb * NNODE);
    WT2 V[5];
    size_t off = 0;
    for (int i = 0; i < 5; ++i) {
        V[i].h = hb + off; off += szs[i];
        V[i].l = hb + off; off += szs[i];
    }
    half_t* ajh = hb + off; off += ADJSZ;
    half_t* ajl = hb + off; off += ADJSZ;

    // one-time weight transpose+split (f16 2-term), post-bn6 weights only
    const float* wp[5] = {W.W_svth, W.W_nnth, W.W_tnth, W.W_lvnth, W.W_ff1};
    const int wkk[5] = {256, 512, 1024, 1280, 576};
    const int wnn[5] = {256, 512, 1024, 256, 128};
    for (int i = 0; i < 5; ++i)
        wsplit2_k<<<dim3(wkk[i] / 32, wnn[i] / 32), 256, 0, stream>>>(
            wp[i], wkk[i], wnn[i], V[i].h, V[i].l);
    asplit2_k<<<256, 256, 0, stream>>>(W.adj, ajh, ajl, 65536);

    Ctx cx0; cx0.ajh = ajh; cx0.ajl = ajl;
    cx0.XT = nullptr; cx0.RSc = 0; cx0.nb = 0; cx0.s = stream;

    for (int b0 = 0; b0 < NBATCH; b0 += nb) {
        int nbc = (NBATCH - b0 < nb) ? (NBATCH - b0) : nb;
        run_chunk(x + (size_t)b0 * NNODE, out + (size_t)b0 * NNODE,
                  ws, nbc, W, V, cx0, stream);
    }
}

// Round 17
// 2640.179 us; speedup vs baseline: 1.2590x; 1.0843x over previous
//
#include <hip/hip_runtime.h>
#include <math.h>

#define NBATCH 256
#define NNODE 256
#define FCLAMP 60000.0f   // tripwire; post-bn6 values are ~1e3 max

typedef float f32x4 __attribute__((ext_vector_type(4)));
typedef _Float16 half_t;
typedef half_t f16x8 __attribute__((ext_vector_type(8)));
typedef half_t f16x4 __attribute__((ext_vector_type(4)));

// f16 2-term split: v = h + l + O(2^-22 * v); range-safe for |v| < 60000.
__device__ __forceinline__ void split2(float v, half_t& h, half_t& l)
{
    v = fminf(fmaxf(v, -FCLAMP), FCLAMP);
    half_t hh = (half_t)v;
    h = hh;
    l = (half_t)(v - (float)hh);
}

// ===========================================================================
// f16 2-term split GEMM, LDS-staged + T14 async-STAGE + T1 XCD swizzle
// (round-16 form, unchanged — hot kernel at ~36.5% MfmaUtil, ~90% of the
// 2-barrier structure cap).
// Block 128x128, 4 waves (2x2), wave 64x64 = 4x4 frags of 16x16x32, BK=32.
// 3 MFMA per product {ah*bh, ah*bl, al*bh}; fp32 accum -> bit-identical
// output vs rounds 12-16.
// ===========================================================================
template<bool RELU, bool ACC>
__global__ __launch_bounds__(256)
void gemm_wk2(int M, int N, int K,
              const float* __restrict__ A, int lda,
              const half_t* __restrict__ Bh, const half_t* __restrict__ Bl, int ldb,
              float* __restrict__ C, int ldc,
              const float* __restrict__ bias)
{
    __shared__ half_t Ash[128][40], Asl[128][40];
    __shared__ half_t Bsh[128][40], Bsl[128][40];

    // ---- T1: bijective XCD swizzle (m204) ----
    const int nwg  = gridDim.x * gridDim.y;
    const int orig = blockIdx.y * gridDim.x + blockIdx.x;
    const int q = nwg >> 3, r8 = nwg & 7;
    const int xcd = orig & 7, pos = orig >> 3;
    const int wgid = (xcd < r8 ? xcd * (q + 1) : r8 * (q + 1) + (xcd - r8) * q) + pos;
    const int bx = wgid % gridDim.x;
    const int by = wgid / gridDim.x;

    const int tid  = threadIdx.x;
    const int tn0  = bx * 128;
    const int tm0  = by * 128;
    const int lane = tid & 63;
    const int w    = tid >> 6;
    const int wr   = (w >> 1) * 64, wc = (w & 1) * 64;
    const int lr   = lane & 15, ko = lane >> 4;

    const int srow = tid >> 1;          // staging row 0..127
    const int skh  = (tid & 1) * 16;    // staging k-half 0/16

    f32x4 acc[4][4];
#pragma unroll
    for (int i = 0; i < 4; ++i)
#pragma unroll
        for (int j = 0; j < 4; ++j) acc[i][j] = (f32x4){0.f, 0.f, 0.f, 0.f};

    const float*  aP  = A  + (size_t)(tm0 + srow) * lda + skh;
    const half_t* bhP = Bh + (size_t)(tn0 + srow) * ldb + skh;
    const half_t* blP = Bl + (size_t)(tn0 + srow) * ldb + skh;

    // staged-tile registers (tile kb), preloaded before the loop
    float4 ra0, ra1, ra2, ra3;
    f16x8  rbh0, rbh1, rbl0, rbl1;
    {
        const float4* ap = (const float4*)aP;
        ra0 = ap[0]; ra1 = ap[1]; ra2 = ap[2]; ra3 = ap[3];
        const f16x8* ph = (const f16x8*)bhP;
        const f16x8* pl = (const f16x8*)blP;
        rbh0 = ph[0]; rbh1 = ph[1]; rbl0 = pl[0]; rbl1 = pl[1];
    }

    for (int kb = 0; kb < K; kb += 32) {
        // ---- write phase: split2 staged A regs, write A+B tiles to LDS ----
        {
            float vv[16] = {ra0.x, ra0.y, ra0.z, ra0.w, ra1.x, ra1.y, ra1.z, ra1.w,
                            ra2.x, ra2.y, ra2.z, ra2.w, ra3.x, ra3.y, ra3.z, ra3.w};
            half_t th[16], tl[16];
#pragma unroll
            for (int j = 0; j < 16; ++j)
                split2(vv[j], th[j], tl[j]);
            *(f16x8*)&Ash[srow][skh]     = *(f16x8*)&th[0];
            *(f16x8*)&Ash[srow][skh + 8] = *(f16x8*)&th[8];
            *(f16x8*)&Asl[srow][skh]     = *(f16x8*)&tl[0];
            *(f16x8*)&Asl[srow][skh + 8] = *(f16x8*)&tl[8];
            *(f16x8*)&Bsh[srow][skh]     = rbh0;
            *(f16x8*)&Bsh[srow][skh + 8] = rbh1;
            *(f16x8*)&Bsl[srow][skh]     = rbl0;
            *(f16x8*)&Bsl[srow][skh + 8] = rbl1;
        }
        __syncthreads();                        // barrier #1: tiles visible

        // ---- issue NEXT-tile global loads: retire under the MFMA phase ----
        if (kb + 32 < K) {
            const float4* ap = (const float4*)(aP + kb + 32);
            ra0 = ap[0]; ra1 = ap[1]; ra2 = ap[2]; ra3 = ap[3];
            const f16x8* ph = (const f16x8*)(bhP + kb + 32);
            const f16x8* pl = (const f16x8*)(blP + kb + 32);
            rbh0 = ph[0]; rbh1 = ph[1]; rbl0 = pl[0]; rbl1 = pl[1];
        }

        // ---- fragment reads ----
        f16x8 ah[4], al[4], bh[4], bl[4];
#pragma unroll
        for (int mf = 0; mf < 4; ++mf) {
            int r = wr + mf * 16 + lr;
            ah[mf] = *(const f16x8*)&Ash[r][ko * 8];
            al[mf] = *(const f16x8*)&Asl[r][ko * 8];
        }
#pragma unroll
        for (int nf = 0; nf < 4; ++nf) {
            int c = wc + nf * 16 + lr;
            bh[nf] = *(const f16x8*)&Bsh[c][ko * 8];
            bl[nf] = *(const f16x8*)&Bsl[c][ko * 8];
        }
        // ---- MFMA: 3 per product (same order as rounds 12-16) ----
#pragma unroll
        for (int nf = 0; nf < 4; ++nf) {
#pragma unroll
            for (int mf = 0; mf < 4; ++mf) {
                acc[mf][nf] = __builtin_amdgcn_mfma_f32_16x16x32_f16(ah[mf], bh[nf], acc[mf][nf], 0, 0, 0);
                acc[mf][nf] = __builtin_amdgcn_mfma_f32_16x16x32_f16(ah[mf], bl[nf], acc[mf][nf], 0, 0, 0);
                acc[mf][nf] = __builtin_amdgcn_mfma_f32_16x16x32_f16(al[mf], bh[nf], acc[mf][nf], 0, 0, 0);
            }
        }
        __syncthreads();                        // barrier #2: reads done
    }

#pragma unroll
    for (int mf = 0; mf < 4; ++mf) {
        int r0 = tm0 + wr + mf * 16 + ko * 4;
#pragma unroll
        for (int nf = 0; nf < 4; ++nf) {
            int c = tn0 + wc + nf * 16 + lr;
            float bsv = bias ? bias[c] : 0.f;
#pragma unroll
            for (int r = 0; r < 4; ++r) {
                float* cp = C + (size_t)(r0 + r) * ldc + c;
                float t = acc[mf][nf][r] + bsv;
                if (ACC) t += *cp;
                if (RELU) t = fmaxf(t, 0.f);
                *cp = t;
            }
        }
    }
}

// ===========================================================================
// FUSED f16-2 adj-GEMM: Out[z] = adj @ X[z] with X read DIRECTLY as fp32
// row-major and transposed+split2 in-kernel via LDS — replaces the separate
// xpose2_k pass + XT global buffer (was ~50MB traffic + 1 launch per call).
// B staging: thread = (col sc=tid&127, k-half skh=(tid>>7)*16); per k, the
// 128 lanes of a half-wave-group read consecutive cols of one X row
// (wave-coalesced 256B); split2 in-flight; contiguous f16x8 writes into the
// proven [128][40] layout. adj frags direct-global (256KB, L2-hot).
// split2 of identical fp32 values -> MFMA inputs bit-identical to the old
// xpose2+ak2 path.
// ===========================================================================
__global__ __launch_bounds__(256)
void gemm_ak2f(int K, const half_t* __restrict__ Ah, const half_t* __restrict__ Al,
               const float* __restrict__ X, int ldx,
               float* __restrict__ C, int ldc, long long sC)
{
    __shared__ half_t Bsh[128][40], Bsl[128][40];

    const int z = blockIdx.z;
    C += sC * z;
    const long long zoff = (long long)z * NNODE;
    const int tid  = threadIdx.x;
    const int tn0  = blockIdx.x * 128;
    const int tm0  = blockIdx.y * 128;
    const int lane = tid & 63;
    const int w    = tid >> 6;
    const int wr   = (w >> 1) * 64, wc = (w & 1) * 64;
    const int lr   = lane & 15, ko = lane >> 4;

    const int sc  = tid & 127;          // staging col 0..127
    const int skh = (tid >> 7) * 16;    // staging k-half 0/16

    f32x4 acc[4][4];
#pragma unroll
    for (int i = 0; i < 4; ++i)
#pragma unroll
        for (int j = 0; j < 4; ++j) acc[i][j] = (f32x4){0.f, 0.f, 0.f, 0.f};

    size_t aoff[4];
#pragma unroll
    for (int mf = 0; mf < 4; ++mf)
        aoff[mf] = (size_t)(tm0 + wr + mf * 16 + lr) * NNODE + ko * 8;

    const float* xP = X + (size_t)(zoff + skh) * ldx + tn0 + sc;

    for (int kb = 0; kb < K; kb += 32) {
        // ---- stage B: 16 k-values of one col, split2, contiguous writes ----
        {
            float v[16];
#pragma unroll
            for (int i = 0; i < 16; ++i)
                v[i] = xP[(size_t)(kb + i) * ldx];
            half_t th[16], tl[16];
#pragma unroll
            for (int i = 0; i < 16; ++i)
                split2(v[i], th[i], tl[i]);
            *(f16x8*)&Bsh[sc][skh]     = *(f16x8*)&th[0];
            *(f16x8*)&Bsh[sc][skh + 8] = *(f16x8*)&th[8];
            *(f16x8*)&Bsl[sc][skh]     = *(f16x8*)&tl[0];
            *(f16x8*)&Bsl[sc][skh + 8] = *(f16x8*)&tl[8];
        }
        __syncthreads();

        // ---- adj frags direct from global (L2-hot) ----
        f16x8 ah[4], al[4];
#pragma unroll
        for (int mf = 0; mf < 4; ++mf) {
            ah[mf] = *(const f16x8*)(Ah + aoff[mf] + kb);
            al[mf] = *(const f16x8*)(Al + aoff[mf] + kb);
        }
        // ---- B frags from LDS ----
        f16x8 bh[4], bl[4];
#pragma unroll
        for (int nf = 0; nf < 4; ++nf) {
            int c = wc + nf * 16 + lr;
            bh[nf] = *(const f16x8*)&Bsh[c][ko * 8];
            bl[nf] = *(const f16x8*)&Bsl[c][ko * 8];
        }
        // ---- MFMA: 3 per product (same per-acc order as old ak2) ----
#pragma unroll
        for (int nf = 0; nf < 4; ++nf) {
#pragma unroll
            for (int mf = 0; mf < 4; ++mf) {
                acc[mf][nf] = __builtin_amdgcn_mfma_f32_16x16x32_f16(ah[mf], bh[nf], acc[mf][nf], 0, 0, 0);
                acc[mf][nf] = __builtin_amdgcn_mfma_f32_16x16x32_f16(ah[mf], bl[nf], acc[mf][nf], 0, 0, 0);
                acc[mf][nf] = __builtin_amdgcn_mfma_f32_16x16x32_f16(al[mf], bh[nf], acc[mf][nf], 0, 0, 0);
            }
        }
        __syncthreads();
    }

#pragma unroll
    for (int mf = 0; mf < 4; ++mf) {
        int r0 = tm0 + wr + mf * 16 + ko * 4;
#pragma unroll
        for (int nf = 0; nf < 4; ++nf) {
            int c = tn0 + wc + nf * 16 + lr;
#pragma unroll
            for (int r = 0; r < 4; ++r)
                C[(size_t)(r0 + r) * ldc + c] = acc[mf][nf][r];
        }
    }
}

// W [K][N] fp32 -> WT [N][K] f16 2-term
__global__ __launch_bounds__(256)
void wsplit2_k(const float* __restrict__ W, int K, int N,
               half_t* __restrict__ Th, half_t* __restrict__ Tl)
{
    __shared__ float tile[32][33];
    const int k0 = blockIdx.x * 32, n0 = blockIdx.y * 32;
    const int t = threadIdx.x;
    {
        int kr = t >> 3, nc = (t & 7) * 4;
        float4 v = *(const float4*)(W + (size_t)(k0 + kr) * N + n0 + nc);
        tile[kr][nc + 0] = v.x; tile[kr][nc + 1] = v.y;
        tile[kr][nc + 2] = v.z; tile[kr][nc + 3] = v.w;
    }
    __syncthreads();
    {
        int nr = t >> 3, kc = (t & 7) * 4;
        f16x4 h, l;
#pragma unroll
        for (int j = 0; j < 4; ++j) {
            half_t hh, ll;
            split2(tile[kc + j][nr], hh, ll);
            h[j] = hh; l[j] = ll;
        }
        size_t o = (size_t)(n0 + nr) * K + k0 + kc;
        *(f16x4*)(Th + o) = h;
        *(f16x4*)(Tl + o) = l;
    }
}

__global__ void asplit2_k(const float* __restrict__ A,
                          half_t* __restrict__ Ah, half_t* __restrict__ Al, int n)
{
    int i = blockIdx.x * blockDim.x + threadIdx.x;
    if (i < n) {
        half_t h, l;
        split2(A[i], h, l);
        Ah[i] = h; Al[i] = l;
    }
}

// ===========================================================================
// fp32 tiled GEMM (BM=128, BN=64, BK=16) — the round-5-validated arithmetic.
// Used for the ENTIRE pre-bn6 chain (error-amplifying region) + C=64 stages.
// ===========================================================================
template<bool RELU, bool ACC>
__global__ __launch_bounds__(256)
void gemm_k(int M, int N, int K,
            const float* __restrict__ A, int lda, long long sA,
            const float* __restrict__ B, int ldb, long long sB,
            float* __restrict__ C, int ldc, long long sC)
{
    constexpr int BM = 128, BN_ = 64, BK = 16, TM = 8, TN = 4;
    constexpr int TX = BN_ / TN;
    __shared__ float As[BK][BM + 4];
    __shared__ float Bs[BK][BN_ + 4];
    const int bz = blockIdx.z;
    A += sA * bz; B += sB * bz; C += sC * bz;
    const int tn0 = blockIdx.x * BN_, tm0 = blockIdx.y * BM;
    const int tid = threadIdx.x;
    const int tx = tid % TX, ty = tid / TX;
    float acc[TM][TN];
#pragma unroll
    for (int i = 0; i < TM; ++i)
#pragma unroll
        for (int j = 0; j < TN; ++j) acc[i][j] = 0.f;
    const int arow = tid >> 2, akq = tid & 3;
    const int bcq = tid % 16, bkr = tid / 16;
    for (int k0 = 0; k0 < K; k0 += BK) {
#pragma unroll
        for (int i = 0; i < 2; ++i) {
            int row = arow + i * 64;
            float4 a = *(const float4*)(A + (size_t)(tm0 + row) * lda + k0 + akq * 4);
            As[akq * 4 + 0][row] = a.x; As[akq * 4 + 1][row] = a.y;
            As[akq * 4 + 2][row] = a.z; As[akq * 4 + 3][row] = a.w;
        }
        {
            float4 b4 = *(const float4*)(B + (size_t)(k0 + bkr) * ldb + tn0 + bcq * 4);
            *(float4*)&Bs[bkr][bcq * 4] = b4;
        }
        __syncthreads();
#pragma unroll
        for (int k = 0; k < BK; ++k) {
            float av[TM], bv[TN];
#pragma unroll
            for (int i = 0; i < TM; ++i) av[i] = As[k][ty * TM + i];
#pragma unroll
            for (int j = 0; j < TN; ++j) bv[j] = Bs[k][tx * TN + j];
#pragma unroll
            for (int i = 0; i < TM; ++i)
#pragma unroll
                for (int j = 0; j < TN; ++j)
                    acc[i][j] = fmaf(av[i], bv[j], acc[i][j]);
        }
        __syncthreads();
    }
#pragma unroll
    for (int i = 0; i < TM; ++i) {
        size_t r = (size_t)tm0 + ty * TM + i;
        int c = tn0 + tx * TN;
        float t0 = acc[i][0], t1 = acc[i][1], t2 = acc[i][2], t3 = acc[i][3];
        float* cp = C + r * ldc + c;
        if (ACC) {
            float4 p = *(const float4*)cp;
            t0 += p.x; t1 += p.y; t2 += p.z; t3 += p.w;
        }
        if (RELU) {
            t0 = fmaxf(t0, 0.f); t1 = fmaxf(t1, 0.f);
            t2 = fmaxf(t2, 0.f); t3 = fmaxf(t3, 0.f);
        }
        float4 v; v.x = t0; v.y = t1; v.z = t2; v.w = t3;
        *(float4*)cp = v;
    }
}

// skip_1 = x (x) W_fst, into SS cols 512..575 (ld 576)
__global__ void s1_k(const float* __restrict__ x, const float* __restrict__ Wfst,
                     float* __restrict__ dst)
{
    int idx = blockIdx.x * blockDim.x + threadIdx.x;
    int r = idx >> 4, c4 = idx & 15;
    float xv = x[r];
    float4 wv = *(const float4*)(Wfst + c4 * 4);
    float4 o; o.x = xv * wv.x; o.y = xv * wv.y; o.z = xv * wv.z; o.w = xv * wv.w;
    *(float4*)(dst + (size_t)r * 576 + c4 * 4) = o;
}

// Per-sample BN over nodes (256 ch), fp64 stats. grid=(nb,4), blk=256.
__global__ __launch_bounds__(256)
void bn_k(const float* __restrict__ src, int lds_, float* __restrict__ dst, int ldd,
          const float* __restrict__ g, const float* __restrict__ bt)
{
    const int b = blockIdx.x, c0 = blockIdx.y * 64;
    const int cl = threadIdx.x & 63, ph = threadIdx.x >> 6;
    const int c = c0 + cl;
    const float* Sb = src + (size_t)b * NNODE * lds_;
    float* Db = dst + (size_t)b * NNODE * ldd;
    double sum = 0.0, sq = 0.0;
    for (int n = ph; n < NNODE; n += 4) {
        double v = (double)Sb[(size_t)n * lds_ + c];
        sum += v; sq += v * v;
    }
    __shared__ double ssum[4][64], ssq[4][64];
    __shared__ float sscale[64], sshift[64];
    ssum[ph][cl] = sum; ssq[ph][cl] = sq;
    __syncthreads();
    if (ph == 0) {
        double s = ssum[0][cl] + ssum[1][cl] + ssum[2][cl] + ssum[3][cl];
        double q = ssq[0][cl] + ssq[1][cl] + ssq[2][cl] + ssq[3][cl];
        double m = s * (1.0 / NNODE);
        double var = q * (1.0 / NNODE) - m * m;
        double sc = (double)g[c] / sqrt(var + 1e-5);
        sscale[cl] = (float)sc;
        sshift[cl] = (float)((double)bt[c] - m * sc);
    }
    __syncthreads();
    float sc = sscale[cl], sh = sshift[cl];
    for (int n = ph; n < NNODE; n += 4)
        Db[(size_t)n * ldd + c] = fmaf(Sb[(size_t)n * lds_ + c], sc, sh);
}

__global__ __launch_bounds__(256)
void head_k(const float* __restrict__ H, const float* __restrict__ Wff2,
            const float* __restrict__ bff2, const float* __restrict__ Wfin,
            float* __restrict__ out)
{
    __shared__ float wsm[128];
    __shared__ float red[256];
    const int b = blockIdx.x, n = threadIdx.x;
    if (n < 128) wsm[n] = Wff2[n];
    __syncthreads();
    const float* h = H + ((size_t)b * NNODE + n) * 128;
    float dot = 0.f;
#pragma unroll
    for (int k = 0; k < 128; k += 4) {
        float4 hv = *(const float4*)(h + k);
        dot = fmaf(hv.x, wsm[k + 0], dot); dot = fmaf(hv.y, wsm[k + 1], dot);
        dot = fmaf(hv.z, wsm[k + 2], dot); dot = fmaf(hv.w, wsm[k + 3], dot);
    }
    float logit = (dot + bff2[0]) * Wfin[0];
    red[n] = logit; __syncthreads();
    for (int s = 128; s > 0; s >>= 1) {
        if (n < s) red[n] = fmaxf(red[n], red[n + s]);
        __syncthreads();
    }
    float mx = red[0]; __syncthreads();
    float e = expf(logit - mx);
    red[n] = e; __syncthreads();
    for (int s = 128; s > 0; s >>= 1) {
        if (n < s) red[n] += red[n + s];
        __syncthreads();
    }
    out[(size_t)b * NNODE + n] = e / red[0];
}

__global__ void zero_k(float* p, int n)
{
    int i = blockIdx.x * blockDim.x + threadIdx.x;
    if (i < n) p[i] = 0.f;
}

// ---------------------------------------------------------------------------
static inline void g(bool relu, bool acc, int M, int N, int K,
    const float* A, int lda, long long sA,
    const float* B, int ldb, long long sB,
    float* C, int ldc, long long sC, int nb, hipStream_t s)
{
    dim3 grid(N / 64, M / 128, nb), blk(256);
    if ( relu &&  acc) gemm_k<true,  true ><<<grid, blk, 0, s>>>(M,N,K,A,lda,sA,B,ldb,sB,C,ldc,sC);
    if ( relu && !acc) gemm_k<true,  false><<<grid, blk, 0, s>>>(M,N,K,A,lda,sA,B,ldb,sB,C,ldc,sC);
    if (!relu &&  acc) gemm_k<false, true ><<<grid, blk, 0, s>>>(M,N,K,A,lda,sA,B,ldb,sB,C,ldc,sC);
    if (!relu && !acc) gemm_k<false, false><<<grid, blk, 0, s>>>(M,N,K,A,lda,sA,B,ldb,sB,C,ldc,sC);
}

static inline void wk2(bool relu, bool acc, int M, int N, int K,
                       const float* A, int lda,
                       const half_t* Bh, const half_t* Bl, int ldb,
                       float* C, int ldc, const float* bias, hipStream_t s)
{
    dim3 grid(N / 128, M / 128, 1), blk(256);
    if (relu  &&  acc) gemm_wk2<true,  true ><<<grid, blk, 0, s>>>(M, N, K, A, lda, Bh, Bl, ldb, C, ldc, bias);
    if (relu  && !acc) gemm_wk2<true,  false><<<grid, blk, 0, s>>>(M, N, K, A, lda, Bh, Bl, ldb, C, ldc, bias);
    if (!relu &&  acc) gemm_wk2<false, true ><<<grid, blk, 0, s>>>(M, N, K, A, lda, Bh, Bl, ldb, C, ldc, bias);
    if (!relu && !acc) gemm_wk2<false, false><<<grid, blk, 0, s>>>(M, N, K, A, lda, Bh, Bl, ldb, C, ldc, bias);
}

struct Ctx {
    const half_t *ajh, *ajl;       // f16-2 adj
    int nb;
    hipStream_t s;
};

// fused adj-GEMM: Out[z] = adj @ X[z], X fp32 row-major (ld = ldx)
static inline void ak2(const Ctx& cx, int Cch, const float* X, int ldx,
                       float* Cout, int ldc, long long sC)
{
    gemm_ak2f<<<dim3(Cch / 128, NNODE / 128, cx.nb), 256, 0, cx.s>>>(
        NNODE, cx.ajh, cx.ajl, X, ldx, Cout, ldc, sC);
}

struct Weights {
    const float *adj, *W_fst, *W_snd, *W_thrd, *W_thrdb, *W_frth, *W_ffth;
    const float *bn6_g, *bn6_b, *W_svth, *bn8_g, *bn8_b, *W_nnth, *W_tnth;
    const float *W_lvnth, *bn12_g, *bn12_b, *W_ff1, *b_ff1, *W_ff2, *b_ff2, *W_final;
};
struct WT2 { half_t *h, *l; };

static void run_chunk(const float* x, float* out, float* ws, int nb,
                      const Weights& W, const WT2* V, const Ctx& cx0,
                      hipStream_t stream)
{
    const int RSc = nb * NNODE;
    const size_t CH = (size_t)RSc;
    float* SS = ws;                  // [S3|S2|S1] ld 576
    float* S3 = SS;
    float* S2 = SS + 256;
    float* S1 = SS + 512;
    float* U  = ws + 576 * CH;       // 1024-wide; packed Q slots early
    float* Q0 = U;
    float* Q1 = U + 256 * CH;
    float* Q2 = U + 512 * CH;
    float* Q3 = U + 768 * CH;
    float* R  = ws + 1600 * CH;      // 256-wide scratch (A5/B2), within R512
    float* R512 = ws + 1600 * CH;    // 512-wide scratch (T6, Gt halves)

    Ctx cx = cx0; cx.nb = nb; cx.s = stream;
    const float* adj = W.adj;
    const long long SN = (long long)NNODE;
    const long long S576 = SN * 576, S256 = SN * 256, S1024 = SN * 1024,
                    S128 = SN * 128, S64 = SN * 64;

    // ======== pre-bn6: fp32 VALU (round-5-validated arithmetic) ========
    s1_k<<<RSc / 16, 256, 0, stream>>>(x, W.W_fst, S1);
    g(0,0, NNODE,64,NNODE, adj,NNODE,0, S1,576,S576, Q0,256,S256, nb, stream);
    g(1,0, RSc,64,64, Q0,256,0, W.W_snd,64,0, Q1,64,0, 1, stream);
    g(0,0, NNODE,64,NNODE, adj,NNODE,0, Q1,64,S64, Q0+64,256,S256, nb, stream);
    g(1,0, RSc,128,128, Q0,256,0, W.W_thrd,128,0, Q2,128,0, 1, stream);
    g(0,0, NNODE,128,NNODE, adj,NNODE,0, Q2,128,S128, Q0+128,256,S256, nb, stream);
    g(1,0, RSc,256,256, Q0,256,0, W.W_thrdb,256,0, Q1,256,0, 1, stream);
    g(0,0, NNODE,256,NNODE, adj,NNODE,0, Q1,256,S256, Q2,256,S256, nb, stream);
    g(1,0, RSc,256,256, Q2,256,0, W.W_frth,256,0, Q3,256,0, 1, stream);
    g(0,0, RSc,256,64,  S1,576,0, W.W_ffth,          256,0, S2,576,0, 1, stream);
    g(0,1, RSc,256,256, Q3,256,0, W.W_ffth + 64*256, 256,0, S2,576,0, 1, stream);
    bn_k<<<dim3(nb, 4), 256, 0, stream>>>(S2, 576, S2, 576, W.bn6_g, W.bn6_b);

    // ======== post-bn6: f16-2 MFMA (bounded values) ========
    // 11. A5 = adj@S2 -> R
    ak2(cx, 256, S2, 576, R, 256, S256);
    // 12. T5 = relu(A5 @ W_svth) -> U+512 (ld 1024)
    wk2(1, 0, RSc, 256, 256, R, 256, V[0].h, V[0].l, 256, U + 512, 1024, 0, stream);
    // 13. bn8: B2 -> R ; B5 in place
    bn_k<<<dim3(nb, 4), 256, 0, stream>>>(S2, 576, R, 256, W.bn8_g, W.bn8_b);
    bn_k<<<dim3(nb, 4), 256, 0, stream>>>(U + 512, 1024, U + 512, 1024,
                                          W.bn8_g + 256, W.bn8_b + 256);
    // 14. A6a = adj@B2 -> U ; A6b = adj@B5 -> U+256
    ak2(cx, 256, R, 256, U, 1024, S1024);
    ak2(cx, 256, U + 512, 1024, U + 256, 1024, S1024);
    // 15. T6 = relu([A6a|A6b] @ W_nnth), ONE N=512 GEMM -> R512 (ld 512)
    wk2(1, 0, RSc, 512, 512, U, 1024, V[1].h, V[1].l, 512, R512, 512, 0, stream);
    // 16. A7ta = adj@T6a -> U+512 ; A7tb = adj@T6b -> U+768
    ak2(cx, 256, R512,       512, U + 512, 1024, S1024);
    ak2(cx, 256, R512 + 256, 512, U + 768, 1024, S1024);
    // 17. two N=512 halves: Gt_h = relu(U @ Wtnth[:,h*512..]) -> R512 ;
    //     S3 (+)= Gt_h @ W_lvnth[h*512 : h*512+512]
    for (int h = 0; h < 2; ++h) {
        wk2(1, 0, RSc, 512, 1024, U, 1024,
            V[2].h + (size_t)h * 512 * 1024, V[2].l + (size_t)h * 512 * 1024, 1024,
            R512, 512, 0, stream);
        wk2(0, h > 0, RSc, 256, 512, R512, 512,
            V[3].h + (size_t)h * 512, V[3].l + (size_t)h * 512, 1280,
            S3, 576, 0, stream);
    }
    // 18. S3 += S2 @ W_lvnth[1024:1280] ; bn12
    wk2(0, 1, RSc, 256, 256, S2, 576,
        V[3].h + 1024, V[3].l + 1024, 1280, S3, 576, 0, stream);
    bn_k<<<dim3(nb, 4), 256, 0, stream>>>(S3, 576, S3, 576, W.bn12_g, W.bn12_b);
    // 19. H = relu(SS @ W_ff1 + b_ff1) -> U (ld 128)
    wk2(1, 0, RSc, 128, 576, SS, 576, V[4].h, V[4].l, 576, U, 128, W.b_ff1, stream);
    // 20. head + softmax
    head_k<<<nb, 256, 0, stream>>>(U, W.W_ff2, W.b_ff2, W.W_final, out);
}

extern "C" void kernel_launch(void* const* d_in, const int* in_sizes, int n_in,
                              void* d_out, int out_size, void* d_ws, size_t ws_size,
                              hipStream_t stream)
{
    const float* x = (const float*)d_in[0];
    Weights W;
    W.adj = (const float*)d_in[1];   W.W_fst  = (const float*)d_in[2];
    W.W_snd = (const float*)d_in[3]; W.W_thrd = (const float*)d_in[4];
    W.W_thrdb = (const float*)d_in[5]; W.W_frth = (const float*)d_in[6];
    W.W_ffth = (const float*)d_in[7]; W.bn6_g = (const float*)d_in[8];
    W.bn6_b = (const float*)d_in[9];  W.W_svth = (const float*)d_in[10];
    W.bn8_g = (const float*)d_in[11]; W.bn8_b = (const float*)d_in[12];
    W.W_nnth = (const float*)d_in[13]; W.W_tnth = (const float*)d_in[14];
    W.W_lvnth = (const float*)d_in[15]; W.bn12_g = (const float*)d_in[16];
    W.bn12_b = (const float*)d_in[17]; W.W_ff1 = (const float*)d_in[18];
    W.b_ff1 = (const float*)d_in[19]; W.W_ff2 = (const float*)d_in[20];
    W.b_ff2 = (const float*)d_in[21]; W.W_final = (const float*)d_in[22];
    float* out = (float*)d_out;

    // f16-2 split weights (post-bn6): W_svth, W_nnth, W_tnth, W_lvnth, W_ff1
    const size_t szs[5] = {65536, 262144, 1048576, 327680, 73728};
    const size_t ADJSZ = 65536;
    size_t tot_halves = 2 * ADJSZ;
    for (int i = 0; i < 5; ++i) tot_halves += 2 * szs[i];
    const size_t split_bytes = tot_halves * 2;

    // arena = 2112 fp32 channels (576 SS + 1024 U + 512 R512); XT eliminated
    int nb = NBATCH;
    while (nb > 0 && (size_t)2112 * nb * NNODE * 4 + split_bytes > ws_size) nb -= 32;
    if (nb <= 0) {
        zero_k<<<(out_size + 255) / 256, 256, 0, stream>>>(out, out_size);
        return;
    }

    float* ws = (float*)d_ws;
    half_t* hb = (half_t*)(ws + (size_t)2112 * nb * NNODE);
    WT2 V[5];
    size_t off = 0;
    for (int i = 0; i < 5; ++i) {
        V[i].h = hb + off; off += szs[i];
        V[i].l = hb + off; off += szs[i];
    }
    half_t* ajh = hb + off; off += ADJSZ;
    half_t* ajl = hb + off; off += ADJSZ;

    // one-time weight transpose+split (f16 2-term), post-bn6 weights only
    const float* wp[5] = {W.W_svth, W.W_nnth, W.W_tnth, W.W_lvnth, W.W_ff1};
    const int wkk[5] = {256, 512, 1024, 1280, 576};
    const int wnn[5] = {256, 512, 1024, 256, 128};
    for (int i = 0; i < 5; ++i)
        wsplit2_k<<<dim3(wkk[i] / 32, wnn[i] / 32), 256, 0, stream>>>(
            wp[i], wkk[i], wnn[i], V[i].h, V[i].l);
    asplit2_k<<<256, 256, 0, stream>>>(W.adj, ajh, ajl, 65536);

    Ctx cx0; cx0.ajh = ajh; cx0.ajl = ajl; cx0.nb = 0; cx0.s = stream;

    for (int b0 = 0; b0 < NBATCH; b0 += nb) {
        int nbc = (NBATCH - b0 < nb) ? (NBATCH - b0) : nb;
        run_chunk(x + (size_t)b0 * NNODE, out + (size_t)b0 * NNODE,
                  ws, nbc, W, V, cx0, stream);
    }
}

// Round 18
// 2392.699 us; speedup vs baseline: 1.3892x; 1.1034x over previous
//
#include <hip/hip_runtime.h>
#include <math.h>

#define NBATCH 256
#define NNODE 256
#define FCLAMP 60000.0f   // tripwire; post-bn6 values are ~1e3 max

typedef float f32x4 __attribute__((ext_vector_type(4)));
typedef _Float16 half_t;
typedef half_t f16x8 __attribute__((ext_vector_type(8)));
typedef half_t f16x4 __attribute__((ext_vector_type(4)));

// f16 2-term split: v = h + l + O(2^-22 * v); range-safe for |v| < 60000.
__device__ __forceinline__ void split2(float v, half_t& h, half_t& l)
{
    v = fminf(fmaxf(v, -FCLAMP), FCLAMP);
    half_t hh = (half_t)v;
    h = hh;
    l = (half_t)(v - (float)hh);
}

// ===========================================================================
// f16 2-term split GEMM, LDS-staged + T14 async-STAGE + T1 XCD swizzle
// (round-16/17 form, unchanged — ~36.5% MfmaUtil, ~90% of the 2-barrier
// structure cap). Block 128x128, 4 waves (2x2), wave 64x64, BK=32.
// 3 MFMA per product {ah*bh, ah*bl, al*bh}; fp32 accum -> bit-identical
// output vs rounds 12-17.
// ===========================================================================
template<bool RELU, bool ACC>
__global__ __launch_bounds__(256)
void gemm_wk2(int M, int N, int K,
              const float* __restrict__ A, int lda,
              const half_t* __restrict__ Bh, const half_t* __restrict__ Bl, int ldb,
              float* __restrict__ C, int ldc,
              const float* __restrict__ bias)
{
    __shared__ half_t Ash[128][40], Asl[128][40];
    __shared__ half_t Bsh[128][40], Bsl[128][40];

    // ---- T1: bijective XCD swizzle (m204) ----
    const int nwg  = gridDim.x * gridDim.y;
    const int orig = blockIdx.y * gridDim.x + blockIdx.x;
    const int q = nwg >> 3, r8 = nwg & 7;
    const int xcd = orig & 7, pos = orig >> 3;
    const int wgid = (xcd < r8 ? xcd * (q + 1) : r8 * (q + 1) + (xcd - r8) * q) + pos;
    const int bx = wgid % gridDim.x;
    const int by = wgid / gridDim.x;

    const int tid  = threadIdx.x;
    const int tn0  = bx * 128;
    const int tm0  = by * 128;
    const int lane = tid & 63;
    const int w    = tid >> 6;
    const int wr   = (w >> 1) * 64, wc = (w & 1) * 64;
    const int lr   = lane & 15, ko = lane >> 4;

    const int srow = tid >> 1;          // staging row 0..127
    const int skh  = (tid & 1) * 16;    // staging k-half 0/16

    f32x4 acc[4][4];
#pragma unroll
    for (int i = 0; i < 4; ++i)
#pragma unroll
        for (int j = 0; j < 4; ++j) acc[i][j] = (f32x4){0.f, 0.f, 0.f, 0.f};

    const float*  aP  = A  + (size_t)(tm0 + srow) * lda + skh;
    const half_t* bhP = Bh + (size_t)(tn0 + srow) * ldb + skh;
    const half_t* blP = Bl + (size_t)(tn0 + srow) * ldb + skh;

    // staged-tile registers (tile kb), preloaded before the loop
    float4 ra0, ra1, ra2, ra3;
    f16x8  rbh0, rbh1, rbl0, rbl1;
    {
        const float4* ap = (const float4*)aP;
        ra0 = ap[0]; ra1 = ap[1]; ra2 = ap[2]; ra3 = ap[3];
        const f16x8* ph = (const f16x8*)bhP;
        const f16x8* pl = (const f16x8*)blP;
        rbh0 = ph[0]; rbh1 = ph[1]; rbl0 = pl[0]; rbl1 = pl[1];
    }

    for (int kb = 0; kb < K; kb += 32) {
        // ---- write phase: split2 staged A regs, write A+B tiles to LDS ----
        {
            float vv[16] = {ra0.x, ra0.y, ra0.z, ra0.w, ra1.x, ra1.y, ra1.z, ra1.w,
                            ra2.x, ra2.y, ra2.z, ra2.w, ra3.x, ra3.y, ra3.z, ra3.w};
            half_t th[16], tl[16];
#pragma unroll
            for (int j = 0; j < 16; ++j)
                split2(vv[j], th[j], tl[j]);
            *(f16x8*)&Ash[srow][skh]     = *(f16x8*)&th[0];
            *(f16x8*)&Ash[srow][skh + 8] = *(f16x8*)&th[8];
            *(f16x8*)&Asl[srow][skh]     = *(f16x8*)&tl[0];
            *(f16x8*)&Asl[srow][skh + 8] = *(f16x8*)&tl[8];
            *(f16x8*)&Bsh[srow][skh]     = rbh0;
            *(f16x8*)&Bsh[srow][skh + 8] = rbh1;
            *(f16x8*)&Bsl[srow][skh]     = rbl0;
            *(f16x8*)&Bsl[srow][skh + 8] = rbl1;
        }
        __syncthreads();                        // barrier #1: tiles visible

        // ---- issue NEXT-tile global loads: retire under the MFMA phase ----
        if (kb + 32 < K) {
            const float4* ap = (const float4*)(aP + kb + 32);
            ra0 = ap[0]; ra1 = ap[1]; ra2 = ap[2]; ra3 = ap[3];
            const f16x8* ph = (const f16x8*)(bhP + kb + 32);
            const f16x8* pl = (const f16x8*)(blP + kb + 32);
            rbh0 = ph[0]; rbh1 = ph[1]; rbl0 = pl[0]; rbl1 = pl[1];
        }

        // ---- fragment reads ----
        f16x8 ah[4], al[4], bh[4], bl[4];
#pragma unroll
        for (int mf = 0; mf < 4; ++mf) {
            int r = wr + mf * 16 + lr;
            ah[mf] = *(const f16x8*)&Ash[r][ko * 8];
            al[mf] = *(const f16x8*)&Asl[r][ko * 8];
        }
#pragma unroll
        for (int nf = 0; nf < 4; ++nf) {
            int c = wc + nf * 16 + lr;
            bh[nf] = *(const f16x8*)&Bsh[c][ko * 8];
            bl[nf] = *(const f16x8*)&Bsl[c][ko * 8];
        }
        // ---- MFMA: 3 per product (same order as rounds 12-17) ----
#pragma unroll
        for (int nf = 0; nf < 4; ++nf) {
#pragma unroll
            for (int mf = 0; mf < 4; ++mf) {
                acc[mf][nf] = __builtin_amdgcn_mfma_f32_16x16x32_f16(ah[mf], bh[nf], acc[mf][nf], 0, 0, 0);
                acc[mf][nf] = __builtin_amdgcn_mfma_f32_16x16x32_f16(ah[mf], bl[nf], acc[mf][nf], 0, 0, 0);
                acc[mf][nf] = __builtin_amdgcn_mfma_f32_16x16x32_f16(al[mf], bh[nf], acc[mf][nf], 0, 0, 0);
            }
        }
        __syncthreads();                        // barrier #2: reads done
    }

#pragma unroll
    for (int mf = 0; mf < 4; ++mf) {
        int r0 = tm0 + wr + mf * 16 + ko * 4;
#pragma unroll
        for (int nf = 0; nf < 4; ++nf) {
            int c = tn0 + wc + nf * 16 + lr;
            float bsv = bias ? bias[c] : 0.f;
#pragma unroll
            for (int r = 0; r < 4; ++r) {
                float* cp = C + (size_t)(r0 + r) * ldc + c;
                float t = acc[mf][nf][r] + bsv;
                if (ACC) t += *cp;
                if (RELU) t = fmaxf(t, 0.f);
                *cp = t;
            }
        }
    }
}

// ===========================================================================
// FUSED f16-2 adj-GEMM (round-17 form, proven): Out[z] = adj @ X[z] with X
// read directly as fp32 row-major, transposed+split2 in-kernel via LDS.
// ===========================================================================
__global__ __launch_bounds__(256)
void gemm_ak2f(int K, const half_t* __restrict__ Ah, const half_t* __restrict__ Al,
               const float* __restrict__ X, int ldx,
               float* __restrict__ C, int ldc, long long sC)
{
    __shared__ half_t Bsh[128][40], Bsl[128][40];

    const int z = blockIdx.z;
    C += sC * z;
    const long long zoff = (long long)z * NNODE;
    const int tid  = threadIdx.x;
    const int tn0  = blockIdx.x * 128;
    const int tm0  = blockIdx.y * 128;
    const int lane = tid & 63;
    const int w    = tid >> 6;
    const int wr   = (w >> 1) * 64, wc = (w & 1) * 64;
    const int lr   = lane & 15, ko = lane >> 4;

    const int sc  = tid & 127;          // staging col 0..127
    const int skh = (tid >> 7) * 16;    // staging k-half 0/16

    f32x4 acc[4][4];
#pragma unroll
    for (int i = 0; i < 4; ++i)
#pragma unroll
        for (int j = 0; j < 4; ++j) acc[i][j] = (f32x4){0.f, 0.f, 0.f, 0.f};

    size_t aoff[4];
#pragma unroll
    for (int mf = 0; mf < 4; ++mf)
        aoff[mf] = (size_t)(tm0 + wr + mf * 16 + lr) * NNODE + ko * 8;

    const float* xP = X + (size_t)(zoff + skh) * ldx + tn0 + sc;

    for (int kb = 0; kb < K; kb += 32) {
        {
            float v[16];
#pragma unroll
            for (int i = 0; i < 16; ++i)
                v[i] = xP[(size_t)(kb + i) * ldx];
            half_t th[16], tl[16];
#pragma unroll
            for (int i = 0; i < 16; ++i)
                split2(v[i], th[i], tl[i]);
            *(f16x8*)&Bsh[sc][skh]     = *(f16x8*)&th[0];
            *(f16x8*)&Bsh[sc][skh + 8] = *(f16x8*)&th[8];
            *(f16x8*)&Bsl[sc][skh]     = *(f16x8*)&tl[0];
            *(f16x8*)&Bsl[sc][skh + 8] = *(f16x8*)&tl[8];
        }
        __syncthreads();

        f16x8 ah[4], al[4];
#pragma unroll
        for (int mf = 0; mf < 4; ++mf) {
            ah[mf] = *(const f16x8*)(Ah + aoff[mf] + kb);
            al[mf] = *(const f16x8*)(Al + aoff[mf] + kb);
        }
        f16x8 bh[4], bl[4];
#pragma unroll
        for (int nf = 0; nf < 4; ++nf) {
            int c = wc + nf * 16 + lr;
            bh[nf] = *(const f16x8*)&Bsh[c][ko * 8];
            bl[nf] = *(const f16x8*)&Bsl[c][ko * 8];
        }
#pragma unroll
        for (int nf = 0; nf < 4; ++nf) {
#pragma unroll
            for (int mf = 0; mf < 4; ++mf) {
                acc[mf][nf] = __builtin_amdgcn_mfma_f32_16x16x32_f16(ah[mf], bh[nf], acc[mf][nf], 0, 0, 0);
                acc[mf][nf] = __builtin_amdgcn_mfma_f32_16x16x32_f16(ah[mf], bl[nf], acc[mf][nf], 0, 0, 0);
                acc[mf][nf] = __builtin_amdgcn_mfma_f32_16x16x32_f16(al[mf], bh[nf], acc[mf][nf], 0, 0, 0);
            }
        }
        __syncthreads();
    }

#pragma unroll
    for (int mf = 0; mf < 4; ++mf) {
        int r0 = tm0 + wr + mf * 16 + ko * 4;
#pragma unroll
        for (int nf = 0; nf < 4; ++nf) {
            int c = tn0 + wc + nf * 16 + lr;
#pragma unroll
            for (int r = 0; r < 4; ++r)
                C[(size_t)(r0 + r) * ldc + c] = acc[mf][nf][r];
        }
    }
}

// W [K][N] fp32 -> WT [N][K] f16 2-term
__global__ __launch_bounds__(256)
void wsplit2_k(const float* __restrict__ W, int K, int N,
               half_t* __restrict__ Th, half_t* __restrict__ Tl)
{
    __shared__ float tile[32][33];
    const int k0 = blockIdx.x * 32, n0 = blockIdx.y * 32;
    const int t = threadIdx.x;
    {
        int kr = t >> 3, nc = (t & 7) * 4;
        float4 v = *(const float4*)(W + (size_t)(k0 + kr) * N + n0 + nc);
        tile[kr][nc + 0] = v.x; tile[kr][nc + 1] = v.y;
        tile[kr][nc + 2] = v.z; tile[kr][nc + 3] = v.w;
    }
    __syncthreads();
    {
        int nr = t >> 3, kc = (t & 7) * 4;
        f16x4 h, l;
#pragma unroll
        for (int j = 0; j < 4; ++j) {
            half_t hh, ll;
            split2(tile[kc + j][nr], hh, ll);
            h[j] = hh; l[j] = ll;
        }
        size_t o = (size_t)(n0 + nr) * K + k0 + kc;
        *(f16x4*)(Th + o) = h;
        *(f16x4*)(Tl + o) = l;
    }
}

__global__ void asplit2_k(const float* __restrict__ A,
                          half_t* __restrict__ Ah, half_t* __restrict__ Al, int n)
{
    int i = blockIdx.x * blockDim.x + threadIdx.x;
    if (i < n) {
        half_t h, l;
        split2(A[i], h, l);
        Ah[i] = h; Al[i] = l;
    }
}

// ===========================================================================
// fp32 tiled GEMM (BM=128, BN=64, BK=16) — the round-5-validated arithmetic.
// Used for the ENTIRE pre-bn6 chain (error-amplifying region) + C=64 stages.
// ===========================================================================
template<bool RELU, bool ACC>
__global__ __launch_bounds__(256)
void gemm_k(int M, int N, int K,
            const float* __restrict__ A, int lda, long long sA,
            const float* __restrict__ B, int ldb, long long sB,
            float* __restrict__ C, int ldc, long long sC)
{
    constexpr int BM = 128, BN_ = 64, BK = 16, TM = 8, TN = 4;
    constexpr int TX = BN_ / TN;
    __shared__ float As[BK][BM + 4];
    __shared__ float Bs[BK][BN_ + 4];
    const int bz = blockIdx.z;
    A += sA * bz; B += sB * bz; C += sC * bz;
    const int tn0 = blockIdx.x * BN_, tm0 = blockIdx.y * BM;
    const int tid = threadIdx.x;
    const int tx = tid % TX, ty = tid / TX;
    float acc[TM][TN];
#pragma unroll
    for (int i = 0; i < TM; ++i)
#pragma unroll
        for (int j = 0; j < TN; ++j) acc[i][j] = 0.f;
    const int arow = tid >> 2, akq = tid & 3;
    const int bcq = tid % 16, bkr = tid / 16;
    for (int k0 = 0; k0 < K; k0 += BK) {
#pragma unroll
        for (int i = 0; i < 2; ++i) {
            int row = arow + i * 64;
            float4 a = *(const float4*)(A + (size_t)(tm0 + row) * lda + k0 + akq * 4);
            As[akq * 4 + 0][row] = a.x; As[akq * 4 + 1][row] = a.y;
            As[akq * 4 + 2][row] = a.z; As[akq * 4 + 3][row] = a.w;
        }
        {
            float4 b4 = *(const float4*)(B + (size_t)(k0 + bkr) * ldb + tn0 + bcq * 4);
            *(float4*)&Bs[bkr][bcq * 4] = b4;
        }
        __syncthreads();
#pragma unroll
        for (int k = 0; k < BK; ++k) {
            float av[TM], bv[TN];
#pragma unroll
            for (int i = 0; i < TM; ++i) av[i] = As[k][ty * TM + i];
#pragma unroll
            for (int j = 0; j < TN; ++j) bv[j] = Bs[k][tx * TN + j];
#pragma unroll
            for (int i = 0; i < TM; ++i)
#pragma unroll
                for (int j = 0; j < TN; ++j)
                    acc[i][j] = fmaf(av[i], bv[j], acc[i][j]);
        }
        __syncthreads();
    }
#pragma unroll
    for (int i = 0; i < TM; ++i) {
        size_t r = (size_t)tm0 + ty * TM + i;
        int c = tn0 + tx * TN;
        float t0 = acc[i][0], t1 = acc[i][1], t2 = acc[i][2], t3 = acc[i][3];
        float* cp = C + r * ldc + c;
        if (ACC) {
            float4 p = *(const float4*)cp;
            t0 += p.x; t1 += p.y; t2 += p.z; t3 += p.w;
        }
        if (RELU) {
            t0 = fmaxf(t0, 0.f); t1 = fmaxf(t1, 0.f);
            t2 = fmaxf(t2, 0.f); t3 = fmaxf(t3, 0.f);
        }
        float4 v; v.x = t0; v.y = t1; v.z = t2; v.w = t3;
        *(float4*)cp = v;
    }
}

// skip_1 = x (x) W_fst, into SS cols 512..575 (ld 576)
__global__ void s1_k(const float* __restrict__ x, const float* __restrict__ Wfst,
                     float* __restrict__ dst)
{
    int idx = blockIdx.x * blockDim.x + threadIdx.x;
    int r = idx >> 4, c4 = idx & 15;
    float xv = x[r];
    float4 wv = *(const float4*)(Wfst + c4 * 4);
    float4 o; o.x = xv * wv.x; o.y = xv * wv.y; o.z = xv * wv.z; o.w = xv * wv.w;
    *(float4*)(dst + (size_t)r * 576 + c4 * 4) = o;
}

// Per-sample BN over nodes (256 ch), fp64 stats. grid=(nb,4), blk=256.
__global__ __launch_bounds__(256)
void bn_k(const float* __restrict__ src, int lds_, float* __restrict__ dst, int ldd,
          const float* __restrict__ g, const float* __restrict__ bt)
{
    const int b = blockIdx.x, c0 = blockIdx.y * 64;
    const int cl = threadIdx.x & 63, ph = threadIdx.x >> 6;
    const int c = c0 + cl;
    const float* Sb = src + (size_t)b * NNODE * lds_;
    float* Db = dst + (size_t)b * NNODE * ldd;
    double sum = 0.0, sq = 0.0;
    for (int n = ph; n < NNODE; n += 4) {
        double v = (double)Sb[(size_t)n * lds_ + c];
        sum += v; sq += v * v;
    }
    __shared__ double ssum[4][64], ssq[4][64];
    __shared__ float sscale[64], sshift[64];
    ssum[ph][cl] = sum; ssq[ph][cl] = sq;
    __syncthreads();
    if (ph == 0) {
        double s = ssum[0][cl] + ssum[1][cl] + ssum[2][cl] + ssum[3][cl];
        double q = ssq[0][cl] + ssq[1][cl] + ssq[2][cl] + ssq[3][cl];
        double m = s * (1.0 / NNODE);
        double var = q * (1.0 / NNODE) - m * m;
        double sc = (double)g[c] / sqrt(var + 1e-5);
        sscale[cl] = (float)sc;
        sshift[cl] = (float)((double)bt[c] - m * sc);
    }
    __syncthreads();
    float sc = sscale[cl], sh = sshift[cl];
    for (int n = ph; n < NNODE; n += 4)
        Db[(size_t)n * ldd + c] = fmaf(Sb[(size_t)n * lds_ + c], sc, sh);
}

__global__ __launch_bounds__(256)
void head_k(const float* __restrict__ H, const float* __restrict__ Wff2,
            const float* __restrict__ bff2, const float* __restrict__ Wfin,
            float* __restrict__ out)
{
    __shared__ float wsm[128];
    __shared__ float red[256];
    const int b = blockIdx.x, n = threadIdx.x;
    if (n < 128) wsm[n] = Wff2[n];
    __syncthreads();
    const float* h = H + ((size_t)b * NNODE + n) * 128;
    float dot = 0.f;
#pragma unroll
    for (int k = 0; k < 128; k += 4) {
        float4 hv = *(const float4*)(h + k);
        dot = fmaf(hv.x, wsm[k + 0], dot); dot = fmaf(hv.y, wsm[k + 1], dot);
        dot = fmaf(hv.z, wsm[k + 2], dot); dot = fmaf(hv.w, wsm[k + 3], dot);
    }
    float logit = (dot + bff2[0]) * Wfin[0];
    red[n] = logit; __syncthreads();
    for (int s = 128; s > 0; s >>= 1) {
        if (n < s) red[n] = fmaxf(red[n], red[n + s]);
        __syncthreads();
    }
    float mx = red[0]; __syncthreads();
    float e = expf(logit - mx);
    red[n] = e; __syncthreads();
    for (int s = 128; s > 0; s >>= 1) {
        if (n < s) red[n] += red[n + s];
        __syncthreads();
    }
    out[(size_t)b * NNODE + n] = e / red[0];
}

__global__ void zero_k(float* p, int n)
{
    int i = blockIdx.x * blockDim.x + threadIdx.x;
    if (i < n) p[i] = 0.f;
}

// ---------------------------------------------------------------------------
static inline void g(bool relu, bool acc, int M, int N, int K,
    const float* A, int lda, long long sA,
    const float* B, int ldb, long long sB,
    float* C, int ldc, long long sC, int nb, hipStream_t s)
{
    dim3 grid(N / 64, M / 128, nb), blk(256);
    if ( relu &&  acc) gemm_k<true,  true ><<<grid, blk, 0, s>>>(M,N,K,A,lda,sA,B,ldb,sB,C,ldc,sC);
    if ( relu && !acc) gemm_k<true,  false><<<grid, blk, 0, s>>>(M,N,K,A,lda,sA,B,ldb,sB,C,ldc,sC);
    if (!relu &&  acc) gemm_k<false, true ><<<grid, blk, 0, s>>>(M,N,K,A,lda,sA,B,ldb,sB,C,ldc,sC);
    if (!relu && !acc) gemm_k<false, false><<<grid, blk, 0, s>>>(M,N,K,A,lda,sA,B,ldb,sB,C,ldc,sC);
}

static inline void wk2(bool relu, bool acc, int M, int N, int K,
                       const float* A, int lda,
                       const half_t* Bh, const half_t* Bl, int ldb,
                       float* C, int ldc, const float* bias, hipStream_t s)
{
    dim3 grid(N / 128, M / 128, 1), blk(256);
    if (relu  &&  acc) gemm_wk2<true,  true ><<<grid, blk, 0, s>>>(M, N, K, A, lda, Bh, Bl, ldb, C, ldc, bias);
    if (relu  && !acc) gemm_wk2<true,  false><<<grid, blk, 0, s>>>(M, N, K, A, lda, Bh, Bl, ldb, C, ldc, bias);
    if (!relu &&  acc) gemm_wk2<false, true ><<<grid, blk, 0, s>>>(M, N, K, A, lda, Bh, Bl, ldb, C, ldc, bias);
    if (!relu && !acc) gemm_wk2<false, false><<<grid, blk, 0, s>>>(M, N, K, A, lda, Bh, Bl, ldb, C, ldc, bias);
}

struct Ctx {
    const half_t *ajh, *ajl;       // f16-2 adj
    int nb;
    hipStream_t s;
};

// fused adj-GEMM: Out[z] = adj @ X[z], X fp32 row-major (ld = ldx)
static inline void ak2(const Ctx& cx, int Cch, const float* X, int ldx,
                       float* Cout, int ldc, long long sC)
{
    gemm_ak2f<<<dim3(Cch / 128, NNODE / 128, cx.nb), 256, 0, cx.s>>>(
        NNODE, cx.ajh, cx.ajl, X, ldx, Cout, ldc, sC);
}

struct Weights {
    const float *adj, *W_fst, *W_snd, *W_thrd, *W_thrdb, *W_frth, *W_ffth;
    const float *bn6_g, *bn6_b, *W_svth, *bn8_g, *bn8_b, *W_nnth, *W_tnth;
    const float *W_lvnth, *bn12_g, *bn12_b, *W_ff1, *b_ff1, *W_ff2, *b_ff2, *W_final;
};
struct WT2 { half_t *h, *l; };

static void run_chunk(const float* x, float* out, float* ws, int nb,
                      const Weights& W, const WT2* V, const Ctx& cx0,
                      hipStream_t stream)
{
    const int RSc = nb * NNODE;
    const size_t CH = (size_t)RSc;
    // 1856-channel arena (243.3 MB @ nb=128 — empirically fits, round 3):
    float* SS = ws;                  // [S3|S2|S1] ld 576
    float* S3 = SS;
    float* S2 = SS + 256;
    float* S1 = SS + 512;
    float* U  = ws + 576 * CH;       // 1024-wide; packed Q slots early
    float* Q0 = U;
    float* Q1 = U + 256 * CH;
    float* Q2 = U + 512 * CH;
    float* Q3 = U + 768 * CH;
    float* R  = ws + 1600 * CH;      // 256-wide scratch

    Ctx cx = cx0; cx.nb = nb; cx.s = stream;
    const float* adj = W.adj;
    const long long SN = (long long)NNODE;
    const long long S576 = SN * 576, S256 = SN * 256, S1024 = SN * 1024,
                    S128 = SN * 128, S64 = SN * 64;

    // ======== pre-bn6: fp32 VALU (round-5-validated arithmetic) ========
    s1_k<<<RSc / 16, 256, 0, stream>>>(x, W.W_fst, S1);
    g(0,0, NNODE,64,NNODE, adj,NNODE,0, S1,576,S576, Q0,256,S256, nb, stream);
    g(1,0, RSc,64,64, Q0,256,0, W.W_snd,64,0, Q1,64,0, 1, stream);
    g(0,0, NNODE,64,NNODE, adj,NNODE,0, Q1,64,S64, Q0+64,256,S256, nb, stream);
    g(1,0, RSc,128,128, Q0,256,0, W.W_thrd,128,0, Q2,128,0, 1, stream);
    g(0,0, NNODE,128,NNODE, adj,NNODE,0, Q2,128,S128, Q0+128,256,S256, nb, stream);
    g(1,0, RSc,256,256, Q0,256,0, W.W_thrdb,256,0, Q1,256,0, 1, stream);
    g(0,0, NNODE,256,NNODE, adj,NNODE,0, Q1,256,S256, Q2,256,S256, nb, stream);
    g(1,0, RSc,256,256, Q2,256,0, W.W_frth,256,0, Q3,256,0, 1, stream);
    g(0,0, RSc,256,64,  S1,576,0, W.W_ffth,          256,0, S2,576,0, 1, stream);
    g(0,1, RSc,256,256, Q3,256,0, W.W_ffth + 64*256, 256,0, S2,576,0, 1, stream);
    bn_k<<<dim3(nb, 4), 256, 0, stream>>>(S2, 576, S2, 576, W.bn6_g, W.bn6_b);

    // ======== post-bn6: f16-2 MFMA (bounded values) ========
    // 11. A5 = adj@S2 -> R
    ak2(cx, 256, S2, 576, R, 256, S256);
    // 12. T5 = relu(A5 @ W_svth) -> U+512 (ld 1024)
    wk2(1, 0, RSc, 256, 256, R, 256, V[0].h, V[0].l, 256, U + 512, 1024, 0, stream);
    // 13. bn8: B2 -> R ; B5 in place
    bn_k<<<dim3(nb, 4), 256, 0, stream>>>(S2, 576, R, 256, W.bn8_g, W.bn8_b);
    bn_k<<<dim3(nb, 4), 256, 0, stream>>>(U + 512, 1024, U + 512, 1024,
                                          W.bn8_g + 256, W.bn8_b + 256);
    // 14. A6a = adj@B2 -> U ; A6b = adj@B5 -> U+256
    ak2(cx, 256, R, 256, U, 1024, S1024);
    ak2(cx, 256, U + 512, 1024, U + 256, 1024, S1024);
    // 15a/16a. T6a = relu([A6a|A6b]@W_nnth[:,0:256]) -> R ; A7ta -> U+512
    wk2(1, 0, RSc, 256, 512, U, 1024, V[1].h, V[1].l, 512, R, 256, 0, stream);
    ak2(cx, 256, R, 256, U + 512, 1024, S1024);
    // 15b/16b. T6b -> R ; A7tb -> U+768
    wk2(1, 0, RSc, 256, 512, U, 1024,
        V[1].h + (size_t)256 * 512, V[1].l + (size_t)256 * 512, 512, R, 256, 0, stream);
    ak2(cx, 256, R, 256, U + 768, 1024, S1024);
    // 17. quarters (round-12 proven form): Gt_j = relu(U @ Wtnth[:,j*256..])
    //     -> R ; S3 (+)= Gt_j @ W_lvnth[j*256:(j+1)*256]
    for (int j = 0; j < 4; ++j) {
        wk2(1, 0, RSc, 256, 1024, U, 1024,
            V[2].h + (size_t)j * 256 * 1024, V[2].l + (size_t)j * 256 * 1024, 1024,
            R, 256, 0, stream);
        wk2(0, j > 0, RSc, 256, 256, R, 256,
            V[3].h + (size_t)j * 256, V[3].l + (size_t)j * 256, 1280,
            S3, 576, 0, stream);
    }
    // 18. S3 += S2 @ W_lvnth[1024:1280] ; bn12
    wk2(0, 1, RSc, 256, 256, S2, 576,
        V[3].h + 1024, V[3].l + 1024, 1280, S3, 576, 0, stream);
    bn_k<<<dim3(nb, 4), 256, 0, stream>>>(S3, 576, S3, 576, W.bn12_g, W.bn12_b);
    // 19. H = relu(SS @ W_ff1 + b_ff1) -> U (ld 128)
    wk2(1, 0, RSc, 128, 576, SS, 576, V[4].h, V[4].l, 576, U, 128, W.b_ff1, stream);
    // 20. head + softmax
    head_k<<<nb, 256, 0, stream>>>(U, W.W_ff2, W.b_ff2, W.W_final, out);
}

extern "C" void kernel_launch(void* const* d_in, const int* in_sizes, int n_in,
                              void* d_out, int out_size, void* d_ws, size_t ws_size,
                              hipStream_t stream)
{
    const float* x = (const float*)d_in[0];
    Weights W;
    W.adj = (const float*)d_in[1];   W.W_fst  = (const float*)d_in[2];
    W.W_snd = (const float*)d_in[3]; W.W_thrd = (const float*)d_in[4];
    W.W_thrdb = (const float*)d_in[5]; W.W_frth = (const float*)d_in[6];
    W.W_ffth = (const float*)d_in[7]; W.bn6_g = (const float*)d_in[8];
    W.bn6_b = (const float*)d_in[9];  W.W_svth = (const float*)d_in[10];
    W.bn8_g = (const float*)d_in[11]; W.bn8_b = (const float*)d_in[12];
    W.W_nnth = (const float*)d_in[13]; W.W_tnth = (const float*)d_in[14];
    W.W_lvnth = (const float*)d_in[15]; W.bn12_g = (const float*)d_in[16];
    W.bn12_b = (const float*)d_in[17]; W.W_ff1 = (const float*)d_in[18];
    W.b_ff1 = (const float*)d_in[19]; W.W_ff2 = (const float*)d_in[20];
    W.b_ff2 = (const float*)d_in[21]; W.W_final = (const float*)d_in[22];
    float* out = (float*)d_out;

    // f16-2 split weights (post-bn6): W_svth, W_nnth, W_tnth, W_lvnth, W_ff1
    const size_t szs[5] = {65536, 262144, 1048576, 327680, 73728};
    const size_t ADJSZ = 65536;
    size_t tot_halves = 2 * ADJSZ;
    for (int i = 0; i < 5; ++i) tot_halves += 2 * szs[i];
    const size_t split_bytes = tot_halves * 2;

    // arena = 1856 fp32 channels (576 SS + 1024 U + 256 R)
    int nb = NBATCH;
    while (nb > 0 && (size_t)1856 * nb * NNODE * 4 + split_bytes > ws_size) nb -= 32;
    if (nb <= 0) {
        zero_k<<<(out_size + 255) / 256, 256, 0, stream>>>(out, out_size);
        return;
    }

    float* ws = (float*)d_ws;
    half_t* hb = (half_t*)(ws + (size_t)1856 * nb * NNODE);
    WT2 V[5];
    size_t off = 0;
    for (int i = 0; i < 5; ++i) {
        V[i].h = hb + off; off += szs[i];
        V[i].l = hb + off; off += szs[i];
    }
    half_t* ajh = hb + off; off += ADJSZ;
    half_t* ajl = hb + off; off += ADJSZ;

    // one-time weight transpose+split (f16 2-term), post-bn6 weights only
    const float* wp[5] = {W.W_svth, W.W_nnth, W.W_tnth, W.W_lvnth, W.W_ff1};
    const int wkk[5] = {256, 512, 1024, 1280, 576};
    const int wnn[5] = {256, 512, 1024, 256, 128};
    for (int i = 0; i < 5; ++i)
        wsplit2_k<<<dim3(wkk[i] / 32, wnn[i] / 32), 256, 0, stream>>>(
            wp[i], wkk[i], wnn[i], V[i].h, V[i].l);
    asplit2_k<<<256, 256, 0, stream>>>(W.adj, ajh, ajl, 65536);

    Ctx cx0; cx0.ajh = ajh; cx0.ajl = ajl; cx0.nb = 0; cx0.s = stream;

    for (int b0 = 0; b0 < NBATCH; b0 += nb) {
        int nbc = (NBATCH - b0 < nb) ? (NBATCH - b0) : nb;
        run_chunk(x + (size_t)b0 * NNODE, out + (size_t)b0 * NNODE,
                  ws, nbc, W, V, cx0, stream);
    }
}

// Round 19
// 2353.617 us; speedup vs baseline: 1.4123x; 1.0166x over previous
//
#include <hip/hip_runtime.h>
#include <math.h>

#define NBATCH 256
#define NNODE 256
#define FCLAMP 60000.0f   // tripwire; post-bn6 values are ~1e3 max

typedef float f32x4 __attribute__((ext_vector_type(4)));
typedef _Float16 half_t;
typedef half_t f16x8 __attribute__((ext_vector_type(8)));
typedef half_t f16x4 __attribute__((ext_vector_type(4)));

// f16 2-term split: v = h + l + O(2^-22 * v); range-safe for |v| < 60000.
__device__ __forceinline__ void split2(float v, half_t& h, half_t& l)
{
    v = fminf(fmaxf(v, -FCLAMP), FCLAMP);
    half_t hh = (half_t)v;
    h = hh;
    l = (half_t)(v - (float)hh);
}

// ===========================================================================
// f16 2-term split GEMM, LDS-staged + T14 async-STAGE + T1 XCD swizzle
// (round-16/17/18 form, unchanged). Block 128x128, 4 waves (2x2), BK=32.
// 3 MFMA per product; fp32 accum -> bit-identical output vs rounds 12-18.
// ===========================================================================
template<bool RELU, bool ACC>
__global__ __launch_bounds__(256)
void gemm_wk2(int M, int N, int K,
              const float* __restrict__ A, int lda,
              const half_t* __restrict__ Bh, const half_t* __restrict__ Bl, int ldb,
              float* __restrict__ C, int ldc,
              const float* __restrict__ bias)
{
    __shared__ half_t Ash[128][40], Asl[128][40];
    __shared__ half_t Bsh[128][40], Bsl[128][40];

    // ---- T1: bijective XCD swizzle (m204) ----
    const int nwg  = gridDim.x * gridDim.y;
    const int orig = blockIdx.y * gridDim.x + blockIdx.x;
    const int q = nwg >> 3, r8 = nwg & 7;
    const int xcd = orig & 7, pos = orig >> 3;
    const int wgid = (xcd < r8 ? xcd * (q + 1) : r8 * (q + 1) + (xcd - r8) * q) + pos;
    const int bx = wgid % gridDim.x;
    const int by = wgid / gridDim.x;

    const int tid  = threadIdx.x;
    const int tn0  = bx * 128;
    const int tm0  = by * 128;
    const int lane = tid & 63;
    const int w    = tid >> 6;
    const int wr   = (w >> 1) * 64, wc = (w & 1) * 64;
    const int lr   = lane & 15, ko = lane >> 4;

    const int srow = tid >> 1;          // staging row 0..127
    const int skh  = (tid & 1) * 16;    // staging k-half 0/16

    f32x4 acc[4][4];
#pragma unroll
    for (int i = 0; i < 4; ++i)
#pragma unroll
        for (int j = 0; j < 4; ++j) acc[i][j] = (f32x4){0.f, 0.f, 0.f, 0.f};

    const float*  aP  = A  + (size_t)(tm0 + srow) * lda + skh;
    const half_t* bhP = Bh + (size_t)(tn0 + srow) * ldb + skh;
    const half_t* blP = Bl + (size_t)(tn0 + srow) * ldb + skh;

    // staged-tile registers (tile kb), preloaded before the loop
    float4 ra0, ra1, ra2, ra3;
    f16x8  rbh0, rbh1, rbl0, rbl1;
    {
        const float4* ap = (const float4*)aP;
        ra0 = ap[0]; ra1 = ap[1]; ra2 = ap[2]; ra3 = ap[3];
        const f16x8* ph = (const f16x8*)bhP;
        const f16x8* pl = (const f16x8*)blP;
        rbh0 = ph[0]; rbh1 = ph[1]; rbl0 = pl[0]; rbl1 = pl[1];
    }

    for (int kb = 0; kb < K; kb += 32) {
        // ---- write phase: split2 staged A regs, write A+B tiles to LDS ----
        {
            float vv[16] = {ra0.x, ra0.y, ra0.z, ra0.w, ra1.x, ra1.y, ra1.z, ra1.w,
                            ra2.x, ra2.y, ra2.z, ra2.w, ra3.x, ra3.y, ra3.z, ra3.w};
            half_t th[16], tl[16];
#pragma unroll
            for (int j = 0; j < 16; ++j)
                split2(vv[j], th[j], tl[j]);
            *(f16x8*)&Ash[srow][skh]     = *(f16x8*)&th[0];
            *(f16x8*)&Ash[srow][skh + 8] = *(f16x8*)&th[8];
            *(f16x8*)&Asl[srow][skh]     = *(f16x8*)&tl[0];
            *(f16x8*)&Asl[srow][skh + 8] = *(f16x8*)&tl[8];
            *(f16x8*)&Bsh[srow][skh]     = rbh0;
            *(f16x8*)&Bsh[srow][skh + 8] = rbh1;
            *(f16x8*)&Bsl[srow][skh]     = rbl0;
            *(f16x8*)&Bsl[srow][skh + 8] = rbl1;
        }
        __syncthreads();                        // barrier #1: tiles visible

        // ---- issue NEXT-tile global loads: retire under the MFMA phase ----
        if (kb + 32 < K) {
            const float4* ap = (const float4*)(aP + kb + 32);
            ra0 = ap[0]; ra1 = ap[1]; ra2 = ap[2]; ra3 = ap[3];
            const f16x8* ph = (const f16x8*)(bhP + kb + 32);
            const f16x8* pl = (const f16x8*)(blP + kb + 32);
            rbh0 = ph[0]; rbh1 = ph[1]; rbl0 = pl[0]; rbl1 = pl[1];
        }

        // ---- fragment reads ----
        f16x8 ah[4], al[4], bh[4], bl[4];
#pragma unroll
        for (int mf = 0; mf < 4; ++mf) {
            int r = wr + mf * 16 + lr;
            ah[mf] = *(const f16x8*)&Ash[r][ko * 8];
            al[mf] = *(const f16x8*)&Asl[r][ko * 8];
        }
#pragma unroll
        for (int nf = 0; nf < 4; ++nf) {
            int c = wc + nf * 16 + lr;
            bh[nf] = *(const f16x8*)&Bsh[c][ko * 8];
            bl[nf] = *(const f16x8*)&Bsl[c][ko * 8];
        }
        // ---- MFMA: 3 per product (same order as rounds 12-18) ----
#pragma unroll
        for (int nf = 0; nf < 4; ++nf) {
#pragma unroll
            for (int mf = 0; mf < 4; ++mf) {
                acc[mf][nf] = __builtin_amdgcn_mfma_f32_16x16x32_f16(ah[mf], bh[nf], acc[mf][nf], 0, 0, 0);
                acc[mf][nf] = __builtin_amdgcn_mfma_f32_16x16x32_f16(ah[mf], bl[nf], acc[mf][nf], 0, 0, 0);
                acc[mf][nf] = __builtin_amdgcn_mfma_f32_16x16x32_f16(al[mf], bh[nf], acc[mf][nf], 0, 0, 0);
            }
        }
        __syncthreads();                        // barrier #2: reads done
    }

#pragma unroll
    for (int mf = 0; mf < 4; ++mf) {
        int r0 = tm0 + wr + mf * 16 + ko * 4;
#pragma unroll
        for (int nf = 0; nf < 4; ++nf) {
            int c = tn0 + wc + nf * 16 + lr;
            float bsv = bias ? bias[c] : 0.f;
#pragma unroll
            for (int r = 0; r < 4; ++r) {
                float* cp = C + (size_t)(r0 + r) * ldc + c;
                float t = acc[mf][nf][r] + bsv;
                if (ACC) t += *cp;
                if (RELU) t = fmaxf(t, 0.f);
                *cp = t;
            }
        }
    }
}

// ===========================================================================
// FUSED f16-2 adj-GEMM (round-17/18 form, proven): Out[z] = adj @ X[z] with X
// read directly as fp32 row-major, transposed+split2 in-kernel via LDS.
// ===========================================================================
__global__ __launch_bounds__(256)
void gemm_ak2f(int K, const half_t* __restrict__ Ah, const half_t* __restrict__ Al,
               const float* __restrict__ X, int ldx,
               float* __restrict__ C, int ldc, long long sC)
{
    __shared__ half_t Bsh[128][40], Bsl[128][40];

    const int z = blockIdx.z;
    C += sC * z;
    const long long zoff = (long long)z * NNODE;
    const int tid  = threadIdx.x;
    const int tn0  = blockIdx.x * 128;
    const int tm0  = blockIdx.y * 128;
    const int lane = tid & 63;
    const int w    = tid >> 6;
    const int wr   = (w >> 1) * 64, wc = (w & 1) * 64;
    const int lr   = lane & 15, ko = lane >> 4;

    const int sc  = tid & 127;          // staging col 0..127
    const int skh = (tid >> 7) * 16;    // staging k-half 0/16

    f32x4 acc[4][4];
#pragma unroll
    for (int i = 0; i < 4; ++i)
#pragma unroll
        for (int j = 0; j < 4; ++j) acc[i][j] = (f32x4){0.f, 0.f, 0.f, 0.f};

    size_t aoff[4];
#pragma unroll
    for (int mf = 0; mf < 4; ++mf)
        aoff[mf] = (size_t)(tm0 + wr + mf * 16 + lr) * NNODE + ko * 8;

    const float* xP = X + (size_t)(zoff + skh) * ldx + tn0 + sc;

    for (int kb = 0; kb < K; kb += 32) {
        {
            float v[16];
#pragma unroll
            for (int i = 0; i < 16; ++i)
                v[i] = xP[(size_t)(kb + i) * ldx];
            half_t th[16], tl[16];
#pragma unroll
            for (int i = 0; i < 16; ++i)
                split2(v[i], th[i], tl[i]);
            *(f16x8*)&Bsh[sc][skh]     = *(f16x8*)&th[0];
            *(f16x8*)&Bsh[sc][skh + 8] = *(f16x8*)&th[8];
            *(f16x8*)&Bsl[sc][skh]     = *(f16x8*)&tl[0];
            *(f16x8*)&Bsl[sc][skh + 8] = *(f16x8*)&tl[8];
        }
        __syncthreads();

        f16x8 ah[4], al[4];
#pragma unroll
        for (int mf = 0; mf < 4; ++mf) {
            ah[mf] = *(const f16x8*)(Ah + aoff[mf] + kb);
            al[mf] = *(const f16x8*)(Al + aoff[mf] + kb);
        }
        f16x8 bh[4], bl[4];
#pragma unroll
        for (int nf = 0; nf < 4; ++nf) {
            int c = wc + nf * 16 + lr;
            bh[nf] = *(const f16x8*)&Bsh[c][ko * 8];
            bl[nf] = *(const f16x8*)&Bsl[c][ko * 8];
        }
#pragma unroll
        for (int nf = 0; nf < 4; ++nf) {
#pragma unroll
            for (int mf = 0; mf < 4; ++mf) {
                acc[mf][nf] = __builtin_amdgcn_mfma_f32_16x16x32_f16(ah[mf], bh[nf], acc[mf][nf], 0, 0, 0);
                acc[mf][nf] = __builtin_amdgcn_mfma_f32_16x16x32_f16(ah[mf], bl[nf], acc[mf][nf], 0, 0, 0);
                acc[mf][nf] = __builtin_amdgcn_mfma_f32_16x16x32_f16(al[mf], bh[nf], acc[mf][nf], 0, 0, 0);
            }
        }
        __syncthreads();
    }

#pragma unroll
    for (int mf = 0; mf < 4; ++mf) {
        int r0 = tm0 + wr + mf * 16 + ko * 4;
#pragma unroll
        for (int nf = 0; nf < 4; ++nf) {
            int c = tn0 + wc + nf * 16 + lr;
#pragma unroll
            for (int r = 0; r < 4; ++r)
                C[(size_t)(r0 + r) * ldc + c] = acc[mf][nf][r];
        }
    }
}

// W [K][N] fp32 -> WT [N][K] f16 2-term
__global__ __launch_bounds__(256)
void wsplit2_k(const float* __restrict__ W, int K, int N,
               half_t* __restrict__ Th, half_t* __restrict__ Tl)
{
    __shared__ float tile[32][33];
    const int k0 = blockIdx.x * 32, n0 = blockIdx.y * 32;
    const int t = threadIdx.x;
    {
        int kr = t >> 3, nc = (t & 7) * 4;
        float4 v = *(const float4*)(W + (size_t)(k0 + kr) * N + n0 + nc);
        tile[kr][nc + 0] = v.x; tile[kr][nc + 1] = v.y;
        tile[kr][nc + 2] = v.z; tile[kr][nc + 3] = v.w;
    }
    __syncthreads();
    {
        int nr = t >> 3, kc = (t & 7) * 4;
        f16x4 h, l;
#pragma unroll
        for (int j = 0; j < 4; ++j) {
            half_t hh, ll;
            split2(tile[kc + j][nr], hh, ll);
            h[j] = hh; l[j] = ll;
        }
        size_t o = (size_t)(n0 + nr) * K + k0 + kc;
        *(f16x4*)(Th + o) = h;
        *(f16x4*)(Tl + o) = l;
    }
}

__global__ void asplit2_k(const float* __restrict__ A,
                          half_t* __restrict__ Ah, half_t* __restrict__ Al, int n)
{
    int i = blockIdx.x * blockDim.x + threadIdx.x;
    if (i < n) {
        half_t h, l;
        split2(A[i], h, l);
        Ah[i] = h; Al[i] = l;
    }
}

// ===========================================================================
// fp32 tiled GEMM (BM=128, BN=64, BK=16) — round-5-validated arithmetic
// + T14 async-STAGE (round-15 proven on wk2: global loads issued right after
// barrier #1 retire under the FMA phase instead of sitting serially between
// barriers). Same fmaf order per accumulator -> bit-identical output.
// Used for the ENTIRE pre-bn6 chain (error-amplifying region) + C=64 stages.
// ===========================================================================
template<bool RELU, bool ACC>
__global__ __launch_bounds__(256)
void gemm_k(int M, int N, int K,
            const float* __restrict__ A, int lda, long long sA,
            const float* __restrict__ B, int ldb, long long sB,
            float* __restrict__ C, int ldc, long long sC)
{
    constexpr int BM = 128, BN_ = 64, BK = 16, TM = 8, TN = 4;
    constexpr int TX = BN_ / TN;
    __shared__ float As[BK][BM + 4];
    __shared__ float Bs[BK][BN_ + 4];
    const int bz = blockIdx.z;
    A += sA * bz; B += sB * bz; C += sC * bz;
    const int tn0 = blockIdx.x * BN_, tm0 = blockIdx.y * BM;
    const int tid = threadIdx.x;
    const int tx = tid % TX, ty = tid / TX;
    float acc[TM][TN];
#pragma unroll
    for (int i = 0; i < TM; ++i)
#pragma unroll
        for (int j = 0; j < TN; ++j) acc[i][j] = 0.f;
    const int arow = tid >> 2, akq = tid & 3;
    const int bcq = tid % 16, bkr = tid / 16;

    const float* aP0 = A + (size_t)(tm0 + arow)      * lda + akq * 4;
    const float* aP1 = A + (size_t)(tm0 + arow + 64) * lda + akq * 4;
    const float* bP  = B + (size_t)bkr * ldb + tn0 + bcq * 4;

    // T14: preload tile 0 into registers
    float4 ra0, ra1, rb;
    ra0 = *(const float4*)aP0;
    ra1 = *(const float4*)aP1;
    rb  = *(const float4*)bP;

    for (int k0 = 0; k0 < K; k0 += BK) {
        // ---- write phase: staged registers -> LDS ----
        As[akq * 4 + 0][arow]      = ra0.x; As[akq * 4 + 1][arow]      = ra0.y;
        As[akq * 4 + 2][arow]      = ra0.z; As[akq * 4 + 3][arow]      = ra0.w;
        As[akq * 4 + 0][arow + 64] = ra1.x; As[akq * 4 + 1][arow + 64] = ra1.y;
        As[akq * 4 + 2][arow + 64] = ra1.z; As[akq * 4 + 3][arow + 64] = ra1.w;
        *(float4*)&Bs[bkr][bcq * 4] = rb;
        __syncthreads();                        // barrier #1: tiles visible

        // ---- issue NEXT-tile global loads: retire under the FMA phase ----
        if (k0 + BK < K) {
            ra0 = *(const float4*)(aP0 + k0 + BK);
            ra1 = *(const float4*)(aP1 + k0 + BK);
            rb  = *(const float4*)(bP + (size_t)(k0 + BK) * ldb);
        }

        // ---- FMA phase (identical order to rounds 5-18) ----
#pragma unroll
        for (int k = 0; k < BK; ++k) {
            float av[TM], bv[TN];
#pragma unroll
            for (int i = 0; i < TM; ++i) av[i] = As[k][ty * TM + i];
#pragma unroll
            for (int j = 0; j < TN; ++j) bv[j] = Bs[k][tx * TN + j];
#pragma unroll
            for (int i = 0; i < TM; ++i)
#pragma unroll
                for (int j = 0; j < TN; ++j)
                    acc[i][j] = fmaf(av[i], bv[j], acc[i][j]);
        }
        __syncthreads();                        // barrier #2: reads done
    }
#pragma unroll
    for (int i = 0; i < TM; ++i) {
        size_t r = (size_t)tm0 + ty * TM + i;
        int c = tn0 + tx * TN;
        float t0 = acc[i][0], t1 = acc[i][1], t2 = acc[i][2], t3 = acc[i][3];
        float* cp = C + r * ldc + c;
        if (ACC) {
            float4 p = *(const float4*)cp;
            t0 += p.x; t1 += p.y; t2 += p.z; t3 += p.w;
        }
        if (RELU) {
            t0 = fmaxf(t0, 0.f); t1 = fmaxf(t1, 0.f);
            t2 = fmaxf(t2, 0.f); t3 = fmaxf(t3, 0.f);
        }
        float4 v; v.x = t0; v.y = t1; v.z = t2; v.w = t3;
        *(float4*)cp = v;
    }
}

// skip_1 = x (x) W_fst, into SS cols 512..575 (ld 576)
__global__ void s1_k(const float* __restrict__ x, const float* __restrict__ Wfst,
                     float* __restrict__ dst)
{
    int idx = blockIdx.x * blockDim.x + threadIdx.x;
    int r = idx >> 4, c4 = idx & 15;
    float xv = x[r];
    float4 wv = *(const float4*)(Wfst + c4 * 4);
    float4 o; o.x = xv * wv.x; o.y = xv * wv.y; o.z = xv * wv.z; o.w = xv * wv.w;
    *(float4*)(dst + (size_t)r * 576 + c4 * 4) = o;
}

// Per-sample BN over nodes (256 ch), fp64 stats. grid=(nb,4), blk=256.
__global__ __launch_bounds__(256)
void bn_k(const float* __restrict__ src, int lds_, float* __restrict__ dst, int ldd,
          const float* __restrict__ g, const float* __restrict__ bt)
{
    const int b = blockIdx.x, c0 = blockIdx.y * 64;
    const int cl = threadIdx.x & 63, ph = threadIdx.x >> 6;
    const int c = c0 + cl;
    const float* Sb = src + (size_t)b * NNODE * lds_;
    float* Db = dst + (size_t)b * NNODE * ldd;
    double sum = 0.0, sq = 0.0;
    for (int n = ph; n < NNODE; n += 4) {
        double v = (double)Sb[(size_t)n * lds_ + c];
        sum += v; sq += v * v;
    }
    __shared__ double ssum[4][64], ssq[4][64];
    __shared__ float sscale[64], sshift[64];
    ssum[ph][cl] = sum; ssq[ph][cl] = sq;
    __syncthreads();
    if (ph == 0) {
        double s = ssum[0][cl] + ssum[1][cl] + ssum[2][cl] + ssum[3][cl];
        double q = ssq[0][cl] + ssq[1][cl] + ssq[2][cl] + ssq[3][cl];
        double m = s * (1.0 / NNODE);
        double var = q * (1.0 / NNODE) - m * m;
        double sc = (double)g[c] / sqrt(var + 1e-5);
        sscale[cl] = (float)sc;
        sshift[cl] = (float)((double)bt[c] - m * sc);
    }
    __syncthreads();
    float sc = sscale[cl], sh = sshift[cl];
    for (int n = ph; n < NNODE; n += 4)
        Db[(size_t)n * ldd + c] = fmaf(Sb[(size_t)n * lds_ + c], sc, sh);
}

__global__ __launch_bounds__(256)
void head_k(const float* __restrict__ H, const float* __restrict__ Wff2,
            const float* __restrict__ bff2, const float* __restrict__ Wfin,
            float* __restrict__ out)
{
    __shared__ float wsm[128];
    __shared__ float red[256];
    const int b = blockIdx.x, n = threadIdx.x;
    if (n < 128) wsm[n] = Wff2[n];
    __syncthreads();
    const float* h = H + ((size_t)b * NNODE + n) * 128;
    float dot = 0.f;
#pragma unroll
    for (int k = 0; k < 128; k += 4) {
        float4 hv = *(const float4*)(h + k);
        dot = fmaf(hv.x, wsm[k + 0], dot); dot = fmaf(hv.y, wsm[k + 1], dot);
        dot = fmaf(hv.z, wsm[k + 2], dot); dot = fmaf(hv.w, wsm[k + 3], dot);
    }
    float logit = (dot + bff2[0]) * Wfin[0];
    red[n] = logit; __syncthreads();
    for (int s = 128; s > 0; s >>= 1) {
        if (n < s) red[n] = fmaxf(red[n], red[n + s]);
        __syncthreads();
    }
    float mx = red[0]; __syncthreads();
    float e = expf(logit - mx);
    red[n] = e; __syncthreads();
    for (int s = 128; s > 0; s >>= 1) {
        if (n < s) red[n] += red[n + s];
        __syncthreads();
    }
    out[(size_t)b * NNODE + n] = e / red[0];
}

__global__ void zero_k(float* p, int n)
{
    int i = blockIdx.x * blockDim.x + threadIdx.x;
    if (i < n) p[i] = 0.f;
}

// ---------------------------------------------------------------------------
static inline void g(bool relu, bool acc, int M, int N, int K,
    const float* A, int lda, long long sA,
    const float* B, int ldb, long long sB,
    float* C, int ldc, long long sC, int nb, hipStream_t s)
{
    dim3 grid(N / 64, M / 128, nb), blk(256);
    if ( relu &&  acc) gemm_k<true,  true ><<<grid, blk, 0, s>>>(M,N,K,A,lda,sA,B,ldb,sB,C,ldc,sC);
    if ( relu && !acc) gemm_k<true,  false><<<grid, blk, 0, s>>>(M,N,K,A,lda,sA,B,ldb,sB,C,ldc,sC);
    if (!relu &&  acc) gemm_k<false, true ><<<grid, blk, 0, s>>>(M,N,K,A,lda,sA,B,ldb,sB,C,ldc,sC);
    if (!relu && !acc) gemm_k<false, false><<<grid, blk, 0, s>>>(M,N,K,A,lda,sA,B,ldb,sB,C,ldc,sC);
}

static inline void wk2(bool relu, bool acc, int M, int N, int K,
                       const float* A, int lda,
                       const half_t* Bh, const half_t* Bl, int ldb,
                       float* C, int ldc, const float* bias, hipStream_t s)
{
    dim3 grid(N / 128, M / 128, 1), blk(256);
    if (relu  &&  acc) gemm_wk2<true,  true ><<<grid, blk, 0, s>>>(M, N, K, A, lda, Bh, Bl, ldb, C, ldc, bias);
    if (relu  && !acc) gemm_wk2<true,  false><<<grid, blk, 0, s>>>(M, N, K, A, lda, Bh, Bl, ldb, C, ldc, bias);
    if (!relu &&  acc) gemm_wk2<false, true ><<<grid, blk, 0, s>>>(M, N, K, A, lda, Bh, Bl, ldb, C, ldc, bias);
    if (!relu && !acc) gemm_wk2<false, false><<<grid, blk, 0, s>>>(M, N, K, A, lda, Bh, Bl, ldb, C, ldc, bias);
}

struct Ctx {
    const half_t *ajh, *ajl;       // f16-2 adj
    int nb;
    hipStream_t s;
};

// fused adj-GEMM: Out[z] = adj @ X[z], X fp32 row-major (ld = ldx)
static inline void ak2(const Ctx& cx, int Cch, const float* X, int ldx,
                       float* Cout, int ldc, long long sC)
{
    gemm_ak2f<<<dim3(Cch / 128, NNODE / 128, cx.nb), 256, 0, cx.s>>>(
        NNODE, cx.ajh, cx.ajl, X, ldx, Cout, ldc, sC);
}

struct Weights {
    const float *adj, *W_fst, *W_snd, *W_thrd, *W_thrdb, *W_frth, *W_ffth;
    const float *bn6_g, *bn6_b, *W_svth, *bn8_g, *bn8_b, *W_nnth, *W_tnth;
    const float *W_lvnth, *bn12_g, *bn12_b, *W_ff1, *b_ff1, *W_ff2, *b_ff2, *W_final;
};
struct WT2 { half_t *h, *l; };

static void run_chunk(const float* x, float* out, float* ws, int nb,
                      const Weights& W, const WT2* V, const Ctx& cx0,
                      hipStream_t stream)
{
    const int RSc = nb * NNODE;
    const size_t CH = (size_t)RSc;
    // 1856-channel arena (243.3 MB @ nb=128 — empirically fits):
    float* SS = ws;                  // [S3|S2|S1] ld 576
    float* S3 = SS;
    float* S2 = SS + 256;
    float* S1 = SS + 512;
    float* U  = ws + 576 * CH;       // 1024-wide; packed Q slots early
    float* Q0 = U;
    float* Q1 = U + 256 * CH;
    float* Q2 = U + 512 * CH;
    float* Q3 = U + 768 * CH;
    float* R  = ws + 1600 * CH;      // 256-wide scratch

    Ctx cx = cx0; cx.nb = nb; cx.s = stream;
    const float* adj = W.adj;
    const long long SN = (long long)NNODE;
    const long long S576 = SN * 576, S256 = SN * 256, S1024 = SN * 1024,
                    S128 = SN * 128, S64 = SN * 64;

    // ======== pre-bn6: fp32 VALU (round-5-validated arithmetic) ========
    s1_k<<<RSc / 16, 256, 0, stream>>>(x, W.W_fst, S1);
    g(0,0, NNODE,64,NNODE, adj,NNODE,0, S1,576,S576, Q0,256,S256, nb, stream);
    g(1,0, RSc,64,64, Q0,256,0, W.W_snd,64,0, Q1,64,0, 1, stream);
    g(0,0, NNODE,64,NNODE, adj,NNODE,0, Q1,64,S64, Q0+64,256,S256, nb, stream);
    g(1,0, RSc,128,128, Q0,256,0, W.W_thrd,128,0, Q2,128,0, 1, stream);
    g(0,0, NNODE,128,NNODE, adj,NNODE,0, Q2,128,S128, Q0+128,256,S256, nb, stream);
    g(1,0, RSc,256,256, Q0,256,0, W.W_thrdb,256,0, Q1,256,0, 1, stream);
    g(0,0, NNODE,256,NNODE, adj,NNODE,0, Q1,256,S256, Q2,256,S256, nb, stream);
    g(1,0, RSc,256,256, Q2,256,0, W.W_frth,256,0, Q3,256,0, 1, stream);
    g(0,0, RSc,256,64,  S1,576,0, W.W_ffth,          256,0, S2,576,0, 1, stream);
    g(0,1, RSc,256,256, Q3,256,0, W.W_ffth + 64*256, 256,0, S2,576,0, 1, stream);
    bn_k<<<dim3(nb, 4), 256, 0, stream>>>(S2, 576, S2, 576, W.bn6_g, W.bn6_b);

    // ======== post-bn6: f16-2 MFMA (bounded values) ========
    // 11. A5 = adj@S2 -> R
    ak2(cx, 256, S2, 576, R, 256, S256);
    // 12. T5 = relu(A5 @ W_svth) -> U+512 (ld 1024)
    wk2(1, 0, RSc, 256, 256, R, 256, V[0].h, V[0].l, 256, U + 512, 1024, 0, stream);
    // 13. bn8: B2 -> R ; B5 in place
    bn_k<<<dim3(nb, 4), 256, 0, stream>>>(S2, 576, R, 256, W.bn8_g, W.bn8_b);
    bn_k<<<dim3(nb, 4), 256, 0, stream>>>(U + 512, 1024, U + 512, 1024,
                                          W.bn8_g + 256, W.bn8_b + 256);
    // 14. A6a = adj@B2 -> U ; A6b = adj@B5 -> U+256
    ak2(cx, 256, R, 256, U, 1024, S1024);
    ak2(cx, 256, U + 512, 1024, U + 256, 1024, S1024);
    // 15a/16a. T6a = relu([A6a|A6b]@W_nnth[:,0:256]) -> R ; A7ta -> U+512
    wk2(1, 0, RSc, 256, 512, U, 1024, V[1].h, V[1].l, 512, R, 256, 0, stream);
    ak2(cx, 256, R, 256, U + 512, 1024, S1024);
    // 15b/16b. T6b -> R ; A7tb -> U+768
    wk2(1, 0, RSc, 256, 512, U, 1024,
        V[1].h + (size_t)256 * 512, V[1].l + (size_t)256 * 512, 512, R, 256, 0, stream);
    ak2(cx, 256, R, 256, U + 768, 1024, S1024);
    // 17. quarters: Gt_j = relu(U @ Wtnth[:,j*256..]) -> R ;
    //     S3 (+)= Gt_j @ W_lvnth[j*256:(j+1)*256]
    for (int j = 0; j < 4; ++j) {
        wk2(1, 0, RSc, 256, 1024, U, 1024,
            V[2].h + (size_t)j * 256 * 1024, V[2].l + (size_t)j * 256 * 1024, 1024,
            R, 256, 0, stream);
        wk2(0, j > 0, RSc, 256, 256, R, 256,
            V[3].h + (size_t)j * 256, V[3].l + (size_t)j * 256, 1280,
            S3, 576, 0, stream);
    }
    // 18. S3 += S2 @ W_lvnth[1024:1280] ; bn12
    wk2(0, 1, RSc, 256, 256, S2, 576,
        V[3].h + 1024, V[3].l + 1024, 1280, S3, 576, 0, stream);
    bn_k<<<dim3(nb, 4), 256, 0, stream>>>(S3, 576, S3, 576, W.bn12_g, W.bn12_b);
    // 19. H = relu(SS @ W_ff1 + b_ff1) -> U (ld 128)
    wk2(1, 0, RSc, 128, 576, SS, 576, V[4].h, V[4].l, 576, U, 128, W.b_ff1, stream);
    // 20. head + softmax
    head_k<<<nb, 256, 0, stream>>>(U, W.W_ff2, W.b_ff2, W.W_final, out);
}

extern "C" void kernel_launch(void* const* d_in, const int* in_sizes, int n_in,
                              void* d_out, int out_size, void* d_ws, size_t ws_size,
                              hipStream_t stream)
{
    const float* x = (const float*)d_in[0];
    Weights W;
    W.adj = (const float*)d_in[1];   W.W_fst  = (const float*)d_in[2];
    W.W_snd = (const float*)d_in[3]; W.W_thrd = (const float*)d_in[4];
    W.W_thrdb = (const float*)d_in[5]; W.W_frth = (const float*)d_in[6];
    W.W_ffth = (const float*)d_in[7]; W.bn6_g = (const float*)d_in[8];
    W.bn6_b = (const float*)d_in[9];  W.W_svth = (const float*)d_in[10];
    W.bn8_g = (const float*)d_in[11]; W.bn8_b = (const float*)d_in[12];
    W.W_nnth = (const float*)d_in[13]; W.W_tnth = (const float*)d_in[14];
    W.W_lvnth = (const float*)d_in[15]; W.bn12_g = (const float*)d_in[16];
    W.bn12_b = (const float*)d_in[17]; W.W_ff1 = (const float*)d_in[18];
    W.b_ff1 = (const float*)d_in[19]; W.W_ff2 = (const float*)d_in[20];
    W.b_ff2 = (const float*)d_in[21]; W.W_final = (const float*)d_in[22];
    float* out = (float*)d_out;

    // f16-2 split weights (post-bn6): W_svth, W_nnth, W_tnth, W_lvnth, W_ff1
    const size_t szs[5] = {65536, 262144, 1048576, 327680, 73728};
    const size_t ADJSZ = 65536;
    size_t tot_halves = 2 * ADJSZ;
    for (int i = 0; i < 5; ++i) tot_halves += 2 * szs[i];
    const size_t split_bytes = tot_halves * 2;

    // arena = 1856 fp32 channels (576 SS + 1024 U + 256 R)
    int nb = NBATCH;
    while (nb > 0 && (size_t)1856 * nb * NNODE * 4 + split_bytes > ws_size) nb -= 32;
    if (nb <= 0) {
        zero_k<<<(out_size + 255) / 256, 256, 0, stream>>>(out, out_size);
        return;
    }

    float* ws = (float*)d_ws;
    half_t* hb = (half_t*)(ws + (size_t)1856 * nb * NNODE);
    WT2 V[5];
    size_t off = 0;
    for (int i = 0; i < 5; ++i) {
        V[i].h = hb + off; off += szs[i];
        V[i].l = hb + off; off += szs[i];
    }
    half_t* ajh = hb + off; off += ADJSZ;
    half_t* ajl = hb + off; off += ADJSZ;

    // one-time weight transpose+split (f16 2-term), post-bn6 weights only
    const float* wp[5] = {W.W_svth, W.W_nnth, W.W_tnth, W.W_lvnth, W.W_ff1};
    const int wkk[5] = {256, 512, 1024, 1280, 576};
    const int wnn[5] = {256, 512, 1024, 256, 128};
    for (int i = 0; i < 5; ++i)
        wsplit2_k<<<dim3(wkk[i] / 32, wnn[i] / 32), 256, 0, stream>>>(
            wp[i], wkk[i], wnn[i], V[i].h, V[i].l);
    asplit2_k<<<256, 256, 0, stream>>>(W.adj, ajh, ajl, 65536);

    Ctx cx0; cx0.ajh = ajh; cx0.ajl = ajl; cx0.nb = 0; cx0.s = stream;

    for (int b0 = 0; b0 < NBATCH; b0 += nb) {
        int nbc = (NBATCH - b0 < nb) ? (NBATCH - b0) : nb;
        run_chunk(x + (size_t)b0 * NNODE, out + (size_t)b0 * NNODE,
                  ws, nbc, W, V, cx0, stream);
    }
}